// Round 4
// baseline (1069.755 us; speedup 1.0000x reference)
//
#include <hip/hip_runtime.h>
#include <hip/hip_bf16.h>

#define N_USER 60000
#define N_ITEM 120000
#define NTOT   180000
#define NNZ_ADJ 3600000
#define NNZ_UG   960000
#define NNZ_IG  1920000

#define RSB     2048        // rows per super-bin
#define NSB_ADJ ((NTOT  + RSB - 1) / RSB)   // 88
#define NSB_UG  ((N_USER+ RSB - 1) / RSB)   // 30
#define NSB_IG  ((N_ITEM+ RSB - 1) / RSB)   // 59
#define CAPA_SB 43008       // mean 40960 + 10 sigma
#define CAPU_SB 34816
#define CAPI_SB 34816
#define CHUNK   4096

typedef __hip_bfloat16 bf16;
typedef __attribute__((ext_vector_type(8))) short bf16x8;   // one MFMA A/B fragment
typedef __attribute__((ext_vector_type(4))) float f32x4;    // one MFMA C/D fragment

// load float element i from input tensor of unknown dtype: flag=1 -> fp32, 0 -> bf16
__device__ __forceinline__ float ldf(const void* p, long i, int f) {
    return f ? ((const float*)p)[i] : __bfloat162float(((const bf16*)p)[i]);
}

// pack two fp32 -> one uint holding 2 bf16
__device__ __forceinline__ unsigned pk2(float a, float b) {
    unsigned short lo = __bfloat16_as_ushort(__float2bfloat16(a));
    unsigned short hi = __bfloat16_as_ushort(__float2bfloat16(b));
    return (unsigned)lo | ((unsigned)hi << 16);
}

// ---------------- dtype detector (adj_vals >= 0 -> bf16 words have bit15==0) ----
__global__ void k_detect(const void* __restrict__ vals, int* __restrict__ flag) {
    if (threadIdx.x == 0 && blockIdx.x == 0) {
        const unsigned short* w = (const unsigned short*)vals;
        int cnt = 0;
        for (int i = 0; i < 512; i += 2) cnt += (w[i] >> 15) & 1;
        *flag = (cnt > 16) ? 1 : 0;
    }
}

// ---------------- cast user/item emb -> ego bf16 ----------------
__global__ __launch_bounds__(256) void k_cast16(const void* __restrict__ ue,
                                                const void* __restrict__ ie,
                                                bf16* __restrict__ ego16,
                                                const int* __restrict__ flag) {
    int f = *flag;
    long i = (long)blockIdx.x * 256 + threadIdx.x;   // NTOT*64 = 11,520,000
    const long uN = (long)N_USER * 64;
    if (i < (long)NTOT * 64) {
        float v = (i < uN) ? ldf(ue, i, f) : ldf(ie, i - uN, f);
        ego16[i] = __float2bfloat16(v);
    }
}

// ================= two-level binned build =================
__global__ __launch_bounds__(256) void k_initpos(int* __restrict__ sbpos, int nsb, int cap) {
    int i = blockIdx.x * 256 + threadIdx.x;
    if (i < nsb) sbpos[i * 16] = i * cap;
}

// L1: partition edges into <=88 super-bins (2048 rows each).
// Record: {rl(11b)<<18 | col(18b), val_f32}
__global__ __launch_bounds__(256) void k_part(const int* __restrict__ rows,
                                              const int* __restrict__ cols,
                                              const void* __restrict__ vals,
                                              uint2* __restrict__ rec,
                                              int* __restrict__ sbpos,
                                              int nnz,
                                              const int* __restrict__ flag) {
    __shared__ int lcnt[96];
    __shared__ int lbase[96];
    int f = *flag;
    int t = threadIdx.x;
    int base = blockIdx.x * CHUNK;
    if (t < 96) lcnt[t] = 0;
    __syncthreads();
    for (int k = 0; k < CHUNK / 256; k++) {
        int e = base + k * 256 + t;
        if (e < nnz) atomicAdd(&lcnt[rows[e] >> 11], 1);
    }
    __syncthreads();
    if (t < 96) {
        int c = lcnt[t];
        lbase[t] = c ? atomicAdd(&sbpos[t * 16], c) : 0;
        lcnt[t] = 0;
    }
    __syncthreads();
    for (int k = 0; k < CHUNK / 256; k++) {
        int e = base + k * 256 + t;
        if (e < nnz) {
            int r = rows[e];
            int sb = r >> 11;
            int o = atomicAdd(&lcnt[sb], 1);
            unsigned meta = ((unsigned)(r & 2047) << 18) | (unsigned)cols[e];
            rec[lbase[sb] + o] = make_uint2(meta, __float_as_uint(ldf(vals, e, f)));
        }
    }
}

// L2: per-super-bin counting sort into row order; emits absolute [rstart, rend).
__global__ __launch_bounds__(1024) void k_sortsb(const uint2* __restrict__ rec,
                                                 uint2* __restrict__ rec2,
                                                 int* __restrict__ rstart,
                                                 int* __restrict__ rend,
                                                 const int* __restrict__ sbpos,
                                                 int cap, int n_rows) {
    __shared__ int cnt[RSB];
    __shared__ int pos[RSB];
    __shared__ int carry;
    int b = blockIdx.x, t = threadIdx.x;
    int s = b * cap;
    int e = sbpos[b * 16];           // final fill cursor
    cnt[t] = 0; cnt[t + 1024] = 0;
    if (t == 0) carry = 0;
    __syncthreads();
    for (int j = s + t; j < e; j += 1024)
        atomicAdd(&cnt[rec[j].x >> 18], 1);
    __syncthreads();
    for (int tile = 0; tile < 2; tile++) {
        int i = tile * 1024 + t;
        int v = cnt[i];
        pos[i] = v;
        __syncthreads();
        for (int d = 1; d < 1024; d <<= 1) {
            int w = (t >= d) ? pos[i - d] : 0;
            __syncthreads();
            if (t >= d) pos[i] += w;
            __syncthreads();
        }
        int inc = pos[i];            // inclusive within tile
        int ex  = carry + inc - v;   // exclusive global
        __syncthreads();
        pos[i] = ex;
        if (t == 1023) carry += inc;
        __syncthreads();
    }
    int row0 = b * RSB;
    for (int i = t; i < RSB; i += 1024) {
        int row = row0 + i;
        if (row < n_rows) {
            rstart[row] = s + pos[i];
            rend[row]   = s + pos[i] + cnt[i];
        }
    }
    __syncthreads();
    for (int j = s + t; j < e; j += 1024) {
        uint2 r = rec[j];
        int o = atomicAdd(&pos[r.x >> 18], 1);
        rec2[s + o] = r;
    }
}

#define ACC8(q, v)                                      \
    a[0] += (v) * __uint_as_float((q).x << 16);         \
    a[1] += (v) * __uint_as_float((q).x & 0xFFFF0000u); \
    a[2] += (v) * __uint_as_float((q).y << 16);         \
    a[3] += (v) * __uint_as_float((q).y & 0xFFFF0000u); \
    a[4] += (v) * __uint_as_float((q).z << 16);         \
    a[5] += (v) * __uint_as_float((q).z & 0xFFFF0000u); \
    a[6] += (v) * __uint_as_float((q).w << 16);         \
    a[7] += (v) * __uint_as_float((q).w & 0xFFFF0000u);

// ================= CSR SpMM, bf16 x: one row per 8-lane octet =================
// MODE 1 only now: out = bf16 S row (stride 64). Used by the MLP branches.
// Edge loop unrolled x4 with grouped loads (4 gathers in flight per wave).
template <int MODE>
__global__ __launch_bounds__(256) void k_spmm_bf(const int* __restrict__ rstart,
                                                 const int* __restrict__ rend,
                                                 const uint2* __restrict__ rec,
                                                 const bf16* __restrict__ x,
                                                 bf16* __restrict__ out,
                                                 const bf16* __restrict__ Ein,
                                                 int n_rows) {
    int row = blockIdx.x * 32 + (threadIdx.x >> 3);
    int p = threadIdx.x & 7;
    if (row >= n_rows) return;
    int s = rstart[row], e = rend[row];
    const uint4* xb = (const uint4*)x;   // 8 bf16 per uint4
    float a[8];
#pragma unroll
    for (int i = 0; i < 8; i++) a[i] = 0.0f;

    int j = s;
    for (; j + 4 <= e; j += 4) {
        uint2 r0 = rec[j];
        uint2 r1 = rec[j + 1];
        uint2 r2 = rec[j + 2];
        uint2 r3 = rec[j + 3];
        uint4 q0 = xb[(long)(r0.x & 0x3FFFF) * 8 + p];
        uint4 q1 = xb[(long)(r1.x & 0x3FFFF) * 8 + p];
        uint4 q2 = xb[(long)(r2.x & 0x3FFFF) * 8 + p];
        uint4 q3 = xb[(long)(r3.x & 0x3FFFF) * 8 + p];
        float v0 = __uint_as_float(r0.y);
        float v1 = __uint_as_float(r1.y);
        float v2 = __uint_as_float(r2.y);
        float v3 = __uint_as_float(r3.y);
        ACC8(q0, v0)
        ACC8(q1, v1)
        ACC8(q2, v2)
        ACC8(q3, v3)
    }
    for (; j < e; j++) {
        uint2 r = rec[j];
        uint4 q = xb[(long)(r.x & 0x3FFFF) * 8 + p];
        float v = __uint_as_float(r.y);
        ACC8(q, v)
    }

    *(uint4*)(out + (long)row * 64 + p * 8) =
        make_uint4(pk2(a[0], a[1]), pk2(a[2], a[3]),
                   pk2(a[4], a[5]), pk2(a[6], a[7]));
}

// ---------------- Y[M,64] = act(X16[M,64] @ W[64,64] + b) -> bf16 --------------
// MFMA: mfma_f32_16x16x32_bf16, weights split bf16 hi+lo for fp32-like accuracy.
template <int ACT>
__global__ __launch_bounds__(256) void k_gemm64(const bf16* __restrict__ X,
                                                const void* __restrict__ W,
                                                const void* __restrict__ b,
                                                bf16* __restrict__ Y, int M,
                                                const int* __restrict__ flag) {
    __shared__ bf16 WtH[64][72];
    __shared__ bf16 WtL[64][72];
    __shared__ float bl[64];
    int f = *flag;
    int tid = threadIdx.x;
    for (int idx = tid; idx < 4096; idx += 256) {
        int n = idx >> 6, kk = idx & 63;
        float v = ldf(W, (long)kk * 64 + n, f);
        bf16 h = __float2bfloat16(v);
        WtH[n][kk] = h;
        WtL[n][kk] = __float2bfloat16(v - __bfloat162float(h));
    }
    if (tid < 64) bl[tid] = ldf(b, tid, f);
    __syncthreads();

    int l  = tid & 63;
    int lr = l & 15;      // A row / D col within tile
    int lk = l >> 4;      // k sub-block / D row group

    bf16x8 bh[2][4], bb[2][4];
#pragma unroll
    for (int kt = 0; kt < 2; kt++)
#pragma unroll
        for (int ct = 0; ct < 4; ct++) {
            int n  = ct * 16 + lr;
            int ko = kt * 32 + lk * 8;
            bh[kt][ct] = *(const bf16x8*)&WtH[n][ko];
            bb[kt][ct] = *(const bf16x8*)&WtL[n][ko];
        }

    int nt  = M >> 4;                       // M is a multiple of 16
    int wid = blockIdx.x * 4 + (tid >> 6);
    int nw  = gridDim.x * 4;

    for (int t = wid; t < nt; t += nw) {
        const bf16* Ap = X + (long)(t * 16 + lr) * 64 + lk * 8;
        bf16x8 a[2];
#pragma unroll
        for (int kt = 0; kt < 2; kt++) a[kt] = *(const bf16x8*)(Ap + kt * 32);

        f32x4 acc[4];
#pragma unroll
        for (int ct = 0; ct < 4; ct++) {
            float bv = bl[ct * 16 + lr];
            acc[ct] = (f32x4){bv, bv, bv, bv};
        }
#pragma unroll
        for (int kt = 0; kt < 2; kt++)
#pragma unroll
            for (int ct = 0; ct < 4; ct++) {
                acc[ct] = __builtin_amdgcn_mfma_f32_16x16x32_bf16(a[kt], bh[kt][ct], acc[ct], 0, 0, 0);
                acc[ct] = __builtin_amdgcn_mfma_f32_16x16x32_bf16(a[kt], bb[kt][ct], acc[ct], 0, 0, 0);
            }

#pragma unroll
        for (int r = 0; r < 4; r++) {
            float v0 = acc[0][r], v1 = acc[1][r], v2 = acc[2][r], v3 = acc[3][r];
            if (ACT == 2) {
                v0 = fmaxf(v0, 0.0f); v1 = fmaxf(v1, 0.0f);
                v2 = fmaxf(v2, 0.0f); v3 = fmaxf(v3, 0.0f);
            } else {
                v0 = (v0 > 0.0f) ? v0 : (expf(v0) - 1.0f);
                v1 = (v1 > 0.0f) ? v1 : (expf(v1) - 1.0f);
                v2 = (v2 > 0.0f) ? v2 : (expf(v2) - 1.0f);
                v3 = (v3 > 0.0f) ? v3 : (expf(v3) - 1.0f);
            }
            long ob = (long)(t * 16 + lk * 4 + r) * 64 + lr;
            Y[ob]      = __float2bfloat16(v0);
            Y[ob + 16] = __float2bfloat16(v1);
            Y[ob + 32] = __float2bfloat16(v2);
            Y[ob + 48] = __float2bfloat16(v3);
        }
    }
}

// ============ FUSED NGCF layer: SpMM -> LDS [S|P] tile -> MFMA -> l2norm ======
// Eliminates the 47 MB SP write + 23 MB SP read per layer (round-3 theory:
// spmm at random-gather fabric ceiling, only byte-elimination pays).
// Block = 256 threads = 64 rows. Phase 1: gather loop (verbatim spmm<2> math)
// writes S|P into LDS tile (stride 136 bf16, same bank pattern as Wt tables).
// Phase 2: 4 waves x one 16-row MFMA tile each (verbatim k_layer math, A-frags
// from LDS). ego ping-pongs between buffers (no in-place WAR). Rounding points
// identical to the split version -> bit-identical output.
__global__ __launch_bounds__(256) void k_fused(const int* __restrict__ rstart,
                                               const int* __restrict__ rend,
                                               const uint2* __restrict__ rec,
                                               const bf16* __restrict__ Ein,
                                               bf16* __restrict__ Eout,
                                               const void* __restrict__ Wgc,
                                               const void* __restrict__ bgc,
                                               const void* __restrict__ Wbi,
                                               const void* __restrict__ bbi,
                                               long woff, long boff,
                                               bf16* __restrict__ nm, int M,
                                               const int* __restrict__ flag) {
    __shared__ bf16 WtH[64][136];
    __shared__ bf16 WtL[64][136];
    __shared__ bf16 SPt[64][136];     // 64 rows x [S8|P8]x8 interleaved
    __shared__ float bl[64];
    int f = *flag;
    int tid = threadIdx.x;
    int bid = blockIdx.x;

    // Wcat[16g+j] = W1[8g+j] (j<8), Wcat[16g+8+j] = W2[8g+j] -- matches SP interleave
    for (int idx = tid; idx < 8192; idx += 256) {
        int n = idx >> 7, kk = idx & 127;
        int g = kk >> 4, j = kk & 15;
        float v = (j < 8) ? ldf(Wgc, woff + (long)(8 * g + j) * 64 + n, f)
                          : ldf(Wbi, woff + (long)(8 * g + j - 8) * 64 + n, f);
        bf16 h = __float2bfloat16(v);
        WtH[n][kk] = h;
        WtL[n][kk] = __float2bfloat16(v - __bfloat162float(h));
    }
    if (tid < 64) bl[tid] = ldf(bgc, boff + tid, f) + ldf(bbi, boff + tid, f);

    // ---- phase 1: SpMM for 64 rows (32 octets x 2 rows), S|P -> LDS ----
    {
        int p = tid & 7;
        const uint4* xb = (const uint4*)Ein;
#pragma unroll
        for (int half = 0; half < 2; half++) {
            int rl = (tid >> 3) + half * 32;
            int grow = bid * 64 + rl;
            if (grow < M) {
                int s = rstart[grow], e = rend[grow];
                float a[8];
#pragma unroll
                for (int i = 0; i < 8; i++) a[i] = 0.0f;
                int j = s;
                for (; j + 4 <= e; j += 4) {
                    uint2 r0 = rec[j];
                    uint2 r1 = rec[j + 1];
                    uint2 r2 = rec[j + 2];
                    uint2 r3 = rec[j + 3];
                    uint4 q0 = xb[(long)(r0.x & 0x3FFFF) * 8 + p];
                    uint4 q1 = xb[(long)(r1.x & 0x3FFFF) * 8 + p];
                    uint4 q2 = xb[(long)(r2.x & 0x3FFFF) * 8 + p];
                    uint4 q3 = xb[(long)(r3.x & 0x3FFFF) * 8 + p];
                    float v0 = __uint_as_float(r0.y);
                    float v1 = __uint_as_float(r1.y);
                    float v2 = __uint_as_float(r2.y);
                    float v3 = __uint_as_float(r3.y);
                    ACC8(q0, v0)
                    ACC8(q1, v1)
                    ACC8(q2, v2)
                    ACC8(q3, v3)
                }
                for (; j < e; j++) {
                    uint2 r = rec[j];
                    uint4 q = xb[(long)(r.x & 0x3FFFF) * 8 + p];
                    float v = __uint_as_float(r.y);
                    ACC8(q, v)
                }
                uint4 eq = *(const uint4*)(Ein + (long)grow * 64 + p * 8);
                float pr[8];
                pr[0] = a[0] * __uint_as_float(eq.x << 16);
                pr[1] = a[1] * __uint_as_float(eq.x & 0xFFFF0000u);
                pr[2] = a[2] * __uint_as_float(eq.y << 16);
                pr[3] = a[3] * __uint_as_float(eq.y & 0xFFFF0000u);
                pr[4] = a[4] * __uint_as_float(eq.z << 16);
                pr[5] = a[5] * __uint_as_float(eq.z & 0xFFFF0000u);
                pr[6] = a[6] * __uint_as_float(eq.w << 16);
                pr[7] = a[7] * __uint_as_float(eq.w & 0xFFFF0000u);
                bf16* ob = &SPt[rl][p * 16];
                *(uint4*)ob = make_uint4(pk2(a[0], a[1]), pk2(a[2], a[3]),
                                         pk2(a[4], a[5]), pk2(a[6], a[7]));
                *(uint4*)(ob + 8) = make_uint4(pk2(pr[0], pr[1]), pk2(pr[2], pr[3]),
                                               pk2(pr[4], pr[5]), pk2(pr[6], pr[7]));
            }
        }
    }
    __syncthreads();

    // ---- phase 2: one 16-row MFMA tile per wave ----
    {
        int w  = tid >> 6;        // wave 0..3 -> local rows [16w, 16w+16)
        int l  = tid & 63;
        int lr = l & 15;
        int lk = l >> 4;
        int rbase = bid * 64 + w * 16;

        f32x4 acc[4];
#pragma unroll
        for (int ct = 0; ct < 4; ct++) {
            float bv = bl[ct * 16 + lr];
            acc[ct] = (f32x4){bv, bv, bv, bv};
        }
#pragma unroll
        for (int kt = 0; kt < 4; kt++) {
            bf16x8 av = *(const bf16x8*)&SPt[w * 16 + lr][kt * 32 + lk * 8];
#pragma unroll
            for (int ct = 0; ct < 4; ct++) {
                bf16x8 bh = *(const bf16x8*)&WtH[ct * 16 + lr][kt * 32 + lk * 8];
                bf16x8 bb = *(const bf16x8*)&WtL[ct * 16 + lr][kt * 32 + lk * 8];
                acc[ct] = __builtin_amdgcn_mfma_f32_16x16x32_bf16(av, bh, acc[ct], 0, 0, 0);
                acc[ct] = __builtin_amdgcn_mfma_f32_16x16x32_bf16(av, bb, acc[ct], 0, 0, 0);
            }
        }

#pragma unroll
        for (int r = 0; r < 4; r++) {
            float v0 = acc[0][r], v1 = acc[1][r], v2 = acc[2][r], v3 = acc[3][r];
            v0 = (v0 > 0.0f) ? v0 : 0.2f * v0;
            v1 = (v1 > 0.0f) ? v1 : 0.2f * v1;
            v2 = (v2 > 0.0f) ? v2 : 0.2f * v2;
            v3 = (v3 > 0.0f) ? v3 : 0.2f * v3;
            float ss = v0 * v0 + v1 * v1 + v2 * v2 + v3 * v3;
            ss += __shfl_xor(ss, 1, 64);    // reduce over the 16-lane column group
            ss += __shfl_xor(ss, 2, 64);
            ss += __shfl_xor(ss, 4, 64);
            ss += __shfl_xor(ss, 8, 64);
            float sc2 = 1.0f / fmaxf(sqrtf(ss), 1e-12f);
            int grow = rbase + lk * 4 + r;
            if (grow < M) {
                long ob = (long)grow * 64 + lr;
                Eout[ob]      = __float2bfloat16(v0);
                Eout[ob + 16] = __float2bfloat16(v1);
                Eout[ob + 32] = __float2bfloat16(v2);
                Eout[ob + 48] = __float2bfloat16(v3);
                nm[ob]        = __float2bfloat16(v0 * sc2);
                nm[ob + 16]   = __float2bfloat16(v1 * sc2);
                nm[ob + 32]   = __float2bfloat16(v2 * sc2);
                nm[ob + 48]   = __float2bfloat16(v3 * sc2);
            }
        }
    }
}

// ---------------- final gather into output ----------------
__global__ __launch_bounds__(64) void k_gather(const int* __restrict__ users,
                                               const int* __restrict__ pos,
                                               const int* __restrict__ neg,
                                               const void* __restrict__ ue,
                                               const void* __restrict__ ie,
                                               const bf16* __restrict__ n1,
                                               const bf16* __restrict__ n2,
                                               const bf16* __restrict__ n3,
                                               const bf16* __restrict__ uh,
                                               const bf16* __restrict__ ih,
                                               void* __restrict__ out,
                                               const int* __restrict__ flag) {
    int f = *flag;
    int b = blockIdx.x;           // 0..12287: [users | pos | neg] x 4096
    int which = b >> 12;
    int s = b & 4095;
    int lane = threadIdx.x;       // 64
    long ebase, nbase;
    const void* e0;
    const bf16* hh;
    if (which == 0) {
        int r = users[s];
        e0 = ue; ebase = (long)r * 64;
        hh = uh + (long)r * 64;
        nbase = (long)r * 64;
    } else {
        int r = (which == 1) ? pos[s] : neg[s];
        e0 = ie; ebase = (long)r * 64;
        hh = ih + (long)r * 64;
        nbase = (long)(N_USER + r) * 64;
    }
    float o0 = ldf(e0, ebase + lane, f);
    float o1 = __bfloat162float(n1[nbase + lane]);
    float o2 = __bfloat162float(n2[nbase + lane]);
    float o3 = __bfloat162float(n3[nbase + lane]);
    float o4 = __bfloat162float(hh[lane]);
    long ob = (long)b * 320;
    if (f) {
        float* o = (float*)out + ob;
        o[lane] = o0; o[64 + lane] = o1; o[128 + lane] = o2;
        o[192 + lane] = o3; o[256 + lane] = o4;
    } else {
        bf16* o = (bf16*)out + ob;
        o[lane]       = __float2bfloat16(o0);
        o[64 + lane]  = __float2bfloat16(o1);
        o[128 + lane] = __float2bfloat16(o2);
        o[192 + lane] = __float2bfloat16(o3);
        o[256 + lane] = __float2bfloat16(o4);
    }
}

// host-side helper: two-level build of row-sorted packed records for one graph
static void build_graph(const int* rows, const int* cols, const void* vals,
                        int nnz, int nsb, int cap, int n_rows,
                        int* sbpos, uint2* recTmp, uint2* rec2,
                        int* rstart, int* rend,
                        const int* FLAG, hipStream_t stream) {
    k_initpos<<<1, 256, 0, stream>>>(sbpos, nsb, cap);
    k_part<<<(nnz + CHUNK - 1) / CHUNK, 256, 0, stream>>>(rows, cols, vals, recTmp, sbpos, nnz, FLAG);
    k_sortsb<<<nsb, 1024, 0, stream>>>(recTmp, rec2, rstart, rend, sbpos, cap, n_rows);
}

extern "C" void kernel_launch(void* const* d_in, const int* in_sizes, int n_in,
                              void* d_out, int out_size, void* d_ws, size_t ws_size,
                              hipStream_t stream) {
    const int* users = (const int*)d_in[0];
    const int* pos   = (const int*)d_in[1];
    const int* neg   = (const int*)d_in[2];
    const int* adj_r = (const int*)d_in[3];
    const int* adj_c = (const int*)d_in[4];
    const void* adj_v = d_in[5];
    const int* ug_r  = (const int*)d_in[6];
    const int* ug_c  = (const int*)d_in[7];
    const void* ug_v = d_in[8];
    const int* ig_r  = (const int*)d_in[9];
    const int* ig_c  = (const int*)d_in[10];
    const void* ig_v = d_in[11];
    const void* ue   = d_in[12];
    const void* ie   = d_in[13];
    const void* Wgc  = d_in[14];
    const void* bgc  = d_in[15];
    const void* Wbi  = d_in[16];
    const void* bbi  = d_in[17];
    const void* Wu0  = d_in[18];
    const void* bu0  = d_in[19];
    const void* Wu1  = d_in[20];
    const void* bu1  = d_in[21];
    const void* Wi0  = d_in[22];
    const void* bi0  = d_in[23];
    const void* Wi1  = d_in[24];
    const void* bi1  = d_in[25];

    char* ws = (char*)d_ws;
    int*   FLAG  = (int*)(ws + 0);                       // 256 B
    bf16*  egoB  = (bf16*)(ws + 256);                    // 23,040,000 (re-uses old SP slot)
    bf16*  S16T  = (bf16*)(ws + 46080256L);              // N_ITEM*64*2 = 15,360,000
    bf16*  ego16 = (bf16*)(ws + 61440256L);              // 23,040,000
    bf16*  UH    = (bf16*)(ws + 84480256L);              //  7,680,000
    bf16*  IH    = (bf16*)(ws + 92160256L);              // 15,360,000
    bf16*  NM1   = (bf16*)(ws + 107520256L);             // 23,040,000
    bf16*  NM2   = (bf16*)(ws + 130560256L);             // 23,040,000
    bf16*  NM3   = (bf16*)(ws + 153600256L);             // 23,040,000
    // T2 (bf16, <=15.36 MB) aliases NM2: dead before layer k=1 writes NM2
    bf16*  T2    = (bf16*)(ws + 130560256L);
    // recTmp aliases egoB region: builds finish before layer 0 writes egoB
    uint2* recTmp = (uint2*)(ws + 256);
    uint2* rec2A = (uint2*)(ws + 176640256L);            // 30,277,632
    uint2* rec2U = (uint2*)(ws + 206917888L);            //  8,355,840
    uint2* rec2I = (uint2*)(ws + 215273728L);            // 16,433,152
    int* rstartA = (int*)(ws + 231706880L);              //    720,000
    int* rendA   = (int*)(ws + 232426880L);              //    720,000
    int* rstartU = (int*)(ws + 233146880L);              //    240,000
    int* rendU   = (int*)(ws + 233386880L);              //    240,000
    int* rstartI = (int*)(ws + 233626880L);              //    480,000
    int* rendI   = (int*)(ws + 234106880L);              //    480,000
    int* sbpos   = (int*)(ws + 234586880L);              //      6,144
                                                         // end 234,593,024 (< 261,120,256 proven)

    k_detect<<<1, 64, 0, stream>>>(adj_v, FLAG);
    k_cast16<<<45000, 256, 0, stream>>>(ue, ie, ego16, FLAG);

    // ---- two-level build of row-sorted packed records (recTmp aliases egoB) ----
    build_graph(ug_r,  ug_c,  ug_v,  NNZ_UG,  NSB_UG,  CAPU_SB, N_USER,
                sbpos, recTmp, rec2U, rstartU, rendU, FLAG, stream);
    build_graph(ig_r,  ig_c,  ig_v,  NNZ_IG,  NSB_IG,  CAPI_SB, N_ITEM,
                sbpos, recTmp, rec2I, rstartI, rendI, FLAG, stream);
    build_graph(adj_r, adj_c, adj_v, NNZ_ADJ, NSB_ADJ, CAPA_SB, NTOT,
                sbpos, recTmp, rec2A, rstartA, rendA, FLAG, stream);

    // ---- user MLP branch (bf16 S throughout) ----
    int gu = (N_USER / 16 + 7) / 8;     // ~2 row-tiles per wave
    int gi = (N_ITEM / 16 + 7) / 8;
    k_spmm_bf<1><<<(N_USER + 31) / 32, 256, 0, stream>>>(rstartU, rendU, rec2U, ego16, S16T, nullptr, N_USER);
    k_gemm64<1><<<gu, 256, 0, stream>>>(S16T, Wu0, bu0, T2, N_USER, FLAG);
    k_spmm_bf<1><<<(N_USER + 31) / 32, 256, 0, stream>>>(rstartU, rendU, rec2U, T2, S16T, nullptr, N_USER);
    k_gemm64<2><<<gu, 256, 0, stream>>>(S16T, Wu1, bu1, UH, N_USER, FLAG);

    // ---- item MLP branch ----
    const bf16* ego16I = ego16 + (size_t)N_USER * 64;
    k_spmm_bf<1><<<(N_ITEM + 31) / 32, 256, 0, stream>>>(rstartI, rendI, rec2I, ego16I, S16T, nullptr, N_ITEM);
    k_gemm64<1><<<gi, 256, 0, stream>>>(S16T, Wi0, bi0, T2, N_ITEM, FLAG);
    k_spmm_bf<1><<<(N_ITEM + 31) / 32, 256, 0, stream>>>(rstartI, rendI, rec2I, T2, S16T, nullptr, N_ITEM);
    k_gemm64<2><<<gi, 256, 0, stream>>>(S16T, Wi1, bi1, IH, N_ITEM, FLAG);

    // ---- 3 NGCF layers: fused spmm+GEMM+l2norm, ego ping-pong (no SP round-trip) ----
    bf16* norms[3] = {NM1, NM2, NM3};
    bf16* bufs[2]  = {ego16, egoB};
    for (int k = 0; k < 3; k++) {
        k_fused<<<(NTOT + 63) / 64, 256, 0, stream>>>(rstartA, rendA, rec2A,
                                                      bufs[k & 1], bufs[(k + 1) & 1],
                                                      Wgc, bgc, Wbi, bbi,
                                                      (long)k * 4096, (long)k * 64,
                                                      norms[k], NTOT, FLAG);
    }

    // ---- output gather ----
    k_gather<<<12288, 64, 0, stream>>>(users, pos, neg, ue, ie, NM1, NM2, NM3, UH, IH,
                                       d_out, FLAG);
}

// Round 5
// 969.112 us; speedup vs baseline: 1.1038x; 1.1038x over previous
//
#include <hip/hip_runtime.h>
#include <hip/hip_bf16.h>

#define N_USER 60000
#define N_ITEM 120000
#define NTOT   180000
#define NNZ_ADJ 3600000
#define NNZ_UG   960000
#define NNZ_IG  1920000

#define RSB     2048        // rows per super-bin
#define NSB_ADJ ((NTOT  + RSB - 1) / RSB)   // 88
#define NSB_UG  ((N_USER+ RSB - 1) / RSB)   // 30
#define NSB_IG  ((N_ITEM+ RSB - 1) / RSB)   // 59
#define CAPA_SB 43008       // mean 40960 + 10 sigma
#define CAPU_SB 34816
#define CAPI_SB 34816
#define CHUNK   4096

typedef __hip_bfloat16 bf16;
typedef __attribute__((ext_vector_type(8))) short bf16x8;   // one MFMA A/B fragment
typedef __attribute__((ext_vector_type(4))) float f32x4;    // one MFMA C/D fragment

// load float element i from input tensor of unknown dtype: flag=1 -> fp32, 0 -> bf16
__device__ __forceinline__ float ldf(const void* p, long i, int f) {
    return f ? ((const float*)p)[i] : __bfloat162float(((const bf16*)p)[i]);
}

// pack two fp32 -> one uint holding 2 bf16
__device__ __forceinline__ unsigned pk2(float a, float b) {
    unsigned short lo = __bfloat16_as_ushort(__float2bfloat16(a));
    unsigned short hi = __bfloat16_as_ushort(__float2bfloat16(b));
    return (unsigned)lo | ((unsigned)hi << 16);
}

// elementwise bf16 product of two bf16x8 fragments (for P = E .* S in-register)
__device__ __forceinline__ bf16x8 mul_bf8(bf16x8 x, bf16x8 y) {
    bf16x8 r;
#pragma unroll
    for (int e = 0; e < 8; e++) {
        float xf = __uint_as_float(((unsigned)(unsigned short)x[e]) << 16);
        float yf = __uint_as_float(((unsigned)(unsigned short)y[e]) << 16);
        r[e] = (short)__bfloat16_as_ushort(__float2bfloat16(xf * yf));
    }
    return r;
}

// ---------------- dtype detector (adj_vals >= 0 -> bf16 words have bit15==0) ----
__global__ void k_detect(const void* __restrict__ vals, int* __restrict__ flag) {
    if (threadIdx.x == 0 && blockIdx.x == 0) {
        const unsigned short* w = (const unsigned short*)vals;
        int cnt = 0;
        for (int i = 0; i < 512; i += 2) cnt += (w[i] >> 15) & 1;
        *flag = (cnt > 16) ? 1 : 0;
    }
}

// ---------------- cast user/item emb -> ego bf16 ----------------
__global__ __launch_bounds__(256) void k_cast16(const void* __restrict__ ue,
                                                const void* __restrict__ ie,
                                                bf16* __restrict__ ego16,
                                                const int* __restrict__ flag) {
    int f = *flag;
    long i = (long)blockIdx.x * 256 + threadIdx.x;   // NTOT*64 = 11,520,000
    const long uN = (long)N_USER * 64;
    if (i < (long)NTOT * 64) {
        float v = (i < uN) ? ldf(ue, i, f) : ldf(ie, i - uN, f);
        ego16[i] = __float2bfloat16(v);
    }
}

// ================= two-level binned build =================
__global__ __launch_bounds__(256) void k_initpos(int* __restrict__ sbpos, int nsb, int cap) {
    int i = blockIdx.x * 256 + threadIdx.x;
    if (i < nsb) sbpos[i * 16] = i * cap;
}

// L1: partition edges into <=88 super-bins (2048 rows each).
// Record: {rl(11b)<<18 | col(18b), val_f32}
__global__ __launch_bounds__(256) void k_part(const int* __restrict__ rows,
                                              const int* __restrict__ cols,
                                              const void* __restrict__ vals,
                                              uint2* __restrict__ rec,
                                              int* __restrict__ sbpos,
                                              int nnz,
                                              const int* __restrict__ flag) {
    __shared__ int lcnt[96];
    __shared__ int lbase[96];
    int f = *flag;
    int t = threadIdx.x;
    int base = blockIdx.x * CHUNK;
    if (t < 96) lcnt[t] = 0;
    __syncthreads();
    for (int k = 0; k < CHUNK / 256; k++) {
        int e = base + k * 256 + t;
        if (e < nnz) atomicAdd(&lcnt[rows[e] >> 11], 1);
    }
    __syncthreads();
    if (t < 96) {
        int c = lcnt[t];
        lbase[t] = c ? atomicAdd(&sbpos[t * 16], c) : 0;
        lcnt[t] = 0;
    }
    __syncthreads();
    for (int k = 0; k < CHUNK / 256; k++) {
        int e = base + k * 256 + t;
        if (e < nnz) {
            int r = rows[e];
            int sb = r >> 11;
            int o = atomicAdd(&lcnt[sb], 1);
            unsigned meta = ((unsigned)(r & 2047) << 18) | (unsigned)cols[e];
            rec[lbase[sb] + o] = make_uint2(meta, __float_as_uint(ldf(vals, e, f)));
        }
    }
}

// L2: per-super-bin counting sort into row order; emits absolute [rstart, rend).
__global__ __launch_bounds__(1024) void k_sortsb(const uint2* __restrict__ rec,
                                                 uint2* __restrict__ rec2,
                                                 int* __restrict__ rstart,
                                                 int* __restrict__ rend,
                                                 const int* __restrict__ sbpos,
                                                 int cap, int n_rows) {
    __shared__ int cnt[RSB];
    __shared__ int pos[RSB];
    __shared__ int carry;
    int b = blockIdx.x, t = threadIdx.x;
    int s = b * cap;
    int e = sbpos[b * 16];           // final fill cursor
    cnt[t] = 0; cnt[t + 1024] = 0;
    if (t == 0) carry = 0;
    __syncthreads();
    for (int j = s + t; j < e; j += 1024)
        atomicAdd(&cnt[rec[j].x >> 18], 1);
    __syncthreads();
    for (int tile = 0; tile < 2; tile++) {
        int i = tile * 1024 + t;
        int v = cnt[i];
        pos[i] = v;
        __syncthreads();
        for (int d = 1; d < 1024; d <<= 1) {
            int w = (t >= d) ? pos[i - d] : 0;
            __syncthreads();
            if (t >= d) pos[i] += w;
            __syncthreads();
        }
        int inc = pos[i];            // inclusive within tile
        int ex  = carry + inc - v;   // exclusive global
        __syncthreads();
        pos[i] = ex;
        if (t == 1023) carry += inc;
        __syncthreads();
    }
    int row0 = b * RSB;
    for (int i = t; i < RSB; i += 1024) {
        int row = row0 + i;
        if (row < n_rows) {
            rstart[row] = s + pos[i];
            rend[row]   = s + pos[i] + cnt[i];
        }
    }
    __syncthreads();
    for (int j = s + t; j < e; j += 1024) {
        uint2 r = rec[j];
        int o = atomicAdd(&pos[r.x >> 18], 1);
        rec2[s + o] = r;
    }
}

#define ACC8(q, v)                                      \
    a[0] += (v) * __uint_as_float((q).x << 16);         \
    a[1] += (v) * __uint_as_float((q).x & 0xFFFF0000u); \
    a[2] += (v) * __uint_as_float((q).y << 16);         \
    a[3] += (v) * __uint_as_float((q).y & 0xFFFF0000u); \
    a[4] += (v) * __uint_as_float((q).z << 16);         \
    a[5] += (v) * __uint_as_float((q).z & 0xFFFF0000u); \
    a[6] += (v) * __uint_as_float((q).w << 16);         \
    a[7] += (v) * __uint_as_float((q).w & 0xFFFF0000u);

// ================= CSR SpMM, bf16 x: one row per 8-lane octet =================
// out = bf16 S row (stride 64). Edge loop unrolled x4 with grouped loads
// (4 gathers in flight per wave; round-3: +12% BW, near gather fabric ceiling).
// P is no longer materialized here -- k_layer forms it in-register (round-5).
__global__ __launch_bounds__(256) void k_spmm_bf(const int* __restrict__ rstart,
                                                 const int* __restrict__ rend,
                                                 const uint2* __restrict__ rec,
                                                 const bf16* __restrict__ x,
                                                 bf16* __restrict__ out,
                                                 int n_rows) {
    int row = blockIdx.x * 32 + (threadIdx.x >> 3);
    int p = threadIdx.x & 7;
    if (row >= n_rows) return;
    int s = rstart[row], e = rend[row];
    const uint4* xb = (const uint4*)x;   // 8 bf16 per uint4
    float a[8];
#pragma unroll
    for (int i = 0; i < 8; i++) a[i] = 0.0f;

    int j = s;
    for (; j + 4 <= e; j += 4) {
        uint2 r0 = rec[j];
        uint2 r1 = rec[j + 1];
        uint2 r2 = rec[j + 2];
        uint2 r3 = rec[j + 3];
        uint4 q0 = xb[(long)(r0.x & 0x3FFFF) * 8 + p];
        uint4 q1 = xb[(long)(r1.x & 0x3FFFF) * 8 + p];
        uint4 q2 = xb[(long)(r2.x & 0x3FFFF) * 8 + p];
        uint4 q3 = xb[(long)(r3.x & 0x3FFFF) * 8 + p];
        float v0 = __uint_as_float(r0.y);
        float v1 = __uint_as_float(r1.y);
        float v2 = __uint_as_float(r2.y);
        float v3 = __uint_as_float(r3.y);
        ACC8(q0, v0)
        ACC8(q1, v1)
        ACC8(q2, v2)
        ACC8(q3, v3)
    }
    for (; j < e; j++) {
        uint2 r = rec[j];
        uint4 q = xb[(long)(r.x & 0x3FFFF) * 8 + p];
        float v = __uint_as_float(r.y);
        ACC8(q, v)
    }

    *(uint4*)(out + (long)row * 64 + p * 8) =
        make_uint4(pk2(a[0], a[1]), pk2(a[2], a[3]),
                   pk2(a[4], a[5]), pk2(a[6], a[7]));
}

// ---------------- Y[M,64] = act(X16[M,64] @ W[64,64] + b) -> bf16 --------------
// MFMA: mfma_f32_16x16x32_bf16, weights split bf16 hi+lo for fp32-like accuracy.
template <int ACT>
__global__ __launch_bounds__(256) void k_gemm64(const bf16* __restrict__ X,
                                                const void* __restrict__ W,
                                                const void* __restrict__ b,
                                                bf16* __restrict__ Y, int M,
                                                const int* __restrict__ flag) {
    __shared__ bf16 WtH[64][72];
    __shared__ bf16 WtL[64][72];
    __shared__ float bl[64];
    int f = *flag;
    int tid = threadIdx.x;
    for (int idx = tid; idx < 4096; idx += 256) {
        int n = idx >> 6, kk = idx & 63;
        float v = ldf(W, (long)kk * 64 + n, f);
        bf16 h = __float2bfloat16(v);
        WtH[n][kk] = h;
        WtL[n][kk] = __float2bfloat16(v - __bfloat162float(h));
    }
    if (tid < 64) bl[tid] = ldf(b, tid, f);
    __syncthreads();

    int l  = tid & 63;
    int lr = l & 15;      // A row / D col within tile
    int lk = l >> 4;      // k sub-block / D row group

    bf16x8 bh[2][4], bb[2][4];
#pragma unroll
    for (int kt = 0; kt < 2; kt++)
#pragma unroll
        for (int ct = 0; ct < 4; ct++) {
            int n  = ct * 16 + lr;
            int ko = kt * 32 + lk * 8;
            bh[kt][ct] = *(const bf16x8*)&WtH[n][ko];
            bb[kt][ct] = *(const bf16x8*)&WtL[n][ko];
        }

    int nt  = M >> 4;                       // M is a multiple of 16
    int wid = blockIdx.x * 4 + (tid >> 6);
    int nw  = gridDim.x * 4;

    for (int t = wid; t < nt; t += nw) {
        const bf16* Ap = X + (long)(t * 16 + lr) * 64 + lk * 8;
        bf16x8 a[2];
#pragma unroll
        for (int kt = 0; kt < 2; kt++) a[kt] = *(const bf16x8*)(Ap + kt * 32);

        f32x4 acc[4];
#pragma unroll
        for (int ct = 0; ct < 4; ct++) {
            float bv = bl[ct * 16 + lr];
            acc[ct] = (f32x4){bv, bv, bv, bv};
        }
#pragma unroll
        for (int kt = 0; kt < 2; kt++)
#pragma unroll
            for (int ct = 0; ct < 4; ct++) {
                acc[ct] = __builtin_amdgcn_mfma_f32_16x16x32_bf16(a[kt], bh[kt][ct], acc[ct], 0, 0, 0);
                acc[ct] = __builtin_amdgcn_mfma_f32_16x16x32_bf16(a[kt], bb[kt][ct], acc[ct], 0, 0, 0);
            }

#pragma unroll
        for (int r = 0; r < 4; r++) {
            float v0 = acc[0][r], v1 = acc[1][r], v2 = acc[2][r], v3 = acc[3][r];
            if (ACT == 2) {
                v0 = fmaxf(v0, 0.0f); v1 = fmaxf(v1, 0.0f);
                v2 = fmaxf(v2, 0.0f); v3 = fmaxf(v3, 0.0f);
            } else {
                v0 = (v0 > 0.0f) ? v0 : (expf(v0) - 1.0f);
                v1 = (v1 > 0.0f) ? v1 : (expf(v1) - 1.0f);
                v2 = (v2 > 0.0f) ? v2 : (expf(v2) - 1.0f);
                v3 = (v3 > 0.0f) ? v3 : (expf(v3) - 1.0f);
            }
            long ob = (long)(t * 16 + lk * 4 + r) * 64 + lr;
            Y[ob]      = __float2bfloat16(v0);
            Y[ob + 16] = __float2bfloat16(v1);
            Y[ob + 32] = __float2bfloat16(v2);
            Y[ob + 48] = __float2bfloat16(v3);
        }
    }
}

// ---------------- NGCF layer: E_out = leakyrelu(S@W1 + (E.*S)@W2 + b) --------
// P = E.*S formed IN-REGISTER from the S and E rows (row-local, so no P
// round-trip through HBM: saves 23 MB write + refetch per layer). l2norm is
// NOT materialized: only the per-row scale (f32) is stored; k_gather applies
// E_k * scale for the 7% of rows it touches (saves 23 MB write per layer).
// Weights: W1/W2 transposed in LDS (B^T frag layout, +8 pad), bf16 hi+lo split.
// D frag: col = lane&15, row = 4*(lane>>4)+reg [verified mapping].
__global__ __launch_bounds__(256) void k_layer(const bf16* __restrict__ S,
                                               const bf16* __restrict__ Ein,
                                               bf16* __restrict__ Eout,
                                               const void* __restrict__ Wgc,
                                               const void* __restrict__ bgc,
                                               const void* __restrict__ Wbi,
                                               const void* __restrict__ bbi,
                                               long woff, long boff,
                                               float* __restrict__ scale, int M,
                                               const int* __restrict__ flag) {
    __shared__ bf16 W1H[64][72];
    __shared__ bf16 W1L[64][72];
    __shared__ bf16 W2H[64][72];
    __shared__ bf16 W2L[64][72];
    __shared__ float bl[64];
    int f = *flag;
    int tid = threadIdx.x;
    for (int idx = tid; idx < 4096; idx += 256) {
        int n = idx >> 6, kk = idx & 63;
        float v1 = ldf(Wgc, woff + (long)kk * 64 + n, f);
        float v2 = ldf(Wbi, woff + (long)kk * 64 + n, f);
        bf16 h1 = __float2bfloat16(v1);
        bf16 h2 = __float2bfloat16(v2);
        W1H[n][kk] = h1;
        W1L[n][kk] = __float2bfloat16(v1 - __bfloat162float(h1));
        W2H[n][kk] = h2;
        W2L[n][kk] = __float2bfloat16(v2 - __bfloat162float(h2));
    }
    if (tid < 64) bl[tid] = ldf(bgc, boff + tid, f) + ldf(bbi, boff + tid, f);
    __syncthreads();

    int l  = tid & 63;
    int lr = l & 15;
    int lk = l >> 4;

    bf16x8 w1h[2][4], w1l[2][4], w2h[2][4], w2l[2][4];
#pragma unroll
    for (int kt = 0; kt < 2; kt++)
#pragma unroll
        for (int ct = 0; ct < 4; ct++) {
            int n  = ct * 16 + lr;
            int ko = kt * 32 + lk * 8;
            w1h[kt][ct] = *(const bf16x8*)&W1H[n][ko];
            w1l[kt][ct] = *(const bf16x8*)&W1L[n][ko];
            w2h[kt][ct] = *(const bf16x8*)&W2H[n][ko];
            w2l[kt][ct] = *(const bf16x8*)&W2L[n][ko];
        }

    int nt  = M >> 4;                 // 11250 for NTOT
    int wid = blockIdx.x * 4 + (tid >> 6);
    int nw  = gridDim.x * 4;

    for (int t = wid; t < nt; t += nw) {
        long rb = (long)(t * 16 + lr) * 64 + lk * 8;
        bf16x8 sv[2], pv[2];
        sv[0] = *(const bf16x8*)(S + rb);
        sv[1] = *(const bf16x8*)(S + rb + 32);
        {
            bf16x8 e0 = *(const bf16x8*)(Ein + rb);
            bf16x8 e1 = *(const bf16x8*)(Ein + rb + 32);
            pv[0] = mul_bf8(e0, sv[0]);
            pv[1] = mul_bf8(e1, sv[1]);
        }

        f32x4 acc[4];
#pragma unroll
        for (int ct = 0; ct < 4; ct++) {
            float bv = bl[ct * 16 + lr];
            acc[ct] = (f32x4){bv, bv, bv, bv};
        }
#pragma unroll
        for (int kt = 0; kt < 2; kt++)
#pragma unroll
            for (int ct = 0; ct < 4; ct++) {
                acc[ct] = __builtin_amdgcn_mfma_f32_16x16x32_bf16(sv[kt], w1h[kt][ct], acc[ct], 0, 0, 0);
                acc[ct] = __builtin_amdgcn_mfma_f32_16x16x32_bf16(sv[kt], w1l[kt][ct], acc[ct], 0, 0, 0);
                acc[ct] = __builtin_amdgcn_mfma_f32_16x16x32_bf16(pv[kt], w2h[kt][ct], acc[ct], 0, 0, 0);
                acc[ct] = __builtin_amdgcn_mfma_f32_16x16x32_bf16(pv[kt], w2l[kt][ct], acc[ct], 0, 0, 0);
            }

#pragma unroll
        for (int r = 0; r < 4; r++) {
            float v0 = acc[0][r], v1 = acc[1][r], v2 = acc[2][r], v3 = acc[3][r];
            v0 = (v0 > 0.0f) ? v0 : 0.2f * v0;
            v1 = (v1 > 0.0f) ? v1 : 0.2f * v1;
            v2 = (v2 > 0.0f) ? v2 : 0.2f * v2;
            v3 = (v3 > 0.0f) ? v3 : 0.2f * v3;
            float ss = v0 * v0 + v1 * v1 + v2 * v2 + v3 * v3;
            ss += __shfl_xor(ss, 1, 64);    // reduce over the 16-lane column group
            ss += __shfl_xor(ss, 2, 64);
            ss += __shfl_xor(ss, 4, 64);
            ss += __shfl_xor(ss, 8, 64);
            float sc2 = 1.0f / fmaxf(sqrtf(ss), 1e-12f);
            int grow = t * 16 + lk * 4 + r;
            long ob = (long)grow * 64 + lr;
            Eout[ob]      = __float2bfloat16(v0);
            Eout[ob + 16] = __float2bfloat16(v1);
            Eout[ob + 32] = __float2bfloat16(v2);
            Eout[ob + 48] = __float2bfloat16(v3);
            if (lr == 0) scale[grow] = sc2;
        }
    }
}

// ---------------- final gather into output ----------------
// nm_k[row] reconstructed as E_k[row] * scale_k[row] (norms not materialized).
__global__ __launch_bounds__(64) void k_gather(const int* __restrict__ users,
                                               const int* __restrict__ pos,
                                               const int* __restrict__ neg,
                                               const void* __restrict__ ue,
                                               const void* __restrict__ ie,
                                               const bf16* __restrict__ E1,
                                               const bf16* __restrict__ E2,
                                               const bf16* __restrict__ E3,
                                               const float* __restrict__ s1,
                                               const float* __restrict__ s2,
                                               const float* __restrict__ s3,
                                               const bf16* __restrict__ uh,
                                               const bf16* __restrict__ ih,
                                               void* __restrict__ out,
                                               const int* __restrict__ flag) {
    int f = *flag;
    int b = blockIdx.x;           // 0..12287: [users | pos | neg] x 4096
    int which = b >> 12;
    int s = b & 4095;
    int lane = threadIdx.x;       // 64
    long ebase, nrow;
    const void* e0;
    const bf16* hh;
    if (which == 0) {
        int r = users[s];
        e0 = ue; ebase = (long)r * 64;
        hh = uh + (long)r * 64;
        nrow = (long)r;
    } else {
        int r = (which == 1) ? pos[s] : neg[s];
        e0 = ie; ebase = (long)r * 64;
        hh = ih + (long)r * 64;
        nrow = (long)(N_USER + r);
    }
    long nbase = nrow * 64;
    float o0 = ldf(e0, ebase + lane, f);
    float o1 = __bfloat162float(E1[nbase + lane]) * s1[nrow];
    float o2 = __bfloat162float(E2[nbase + lane]) * s2[nrow];
    float o3 = __bfloat162float(E3[nbase + lane]) * s3[nrow];
    float o4 = __bfloat162float(hh[lane]);
    long ob = (long)b * 320;
    if (f) {
        float* o = (float*)out + ob;
        o[lane] = o0; o[64 + lane] = o1; o[128 + lane] = o2;
        o[192 + lane] = o3; o[256 + lane] = o4;
    } else {
        bf16* o = (bf16*)out + ob;
        o[lane]       = __float2bfloat16(o0);
        o[64 + lane]  = __float2bfloat16(o1);
        o[128 + lane] = __float2bfloat16(o2);
        o[192 + lane] = __float2bfloat16(o3);
        o[256 + lane] = __float2bfloat16(o4);
    }
}

// host-side helper: two-level build of row-sorted packed records for one graph
static void build_graph(const int* rows, const int* cols, const void* vals,
                        int nnz, int nsb, int cap, int n_rows,
                        int* sbpos, uint2* recTmp, uint2* rec2,
                        int* rstart, int* rend,
                        const int* FLAG, hipStream_t stream) {
    k_initpos<<<1, 256, 0, stream>>>(sbpos, nsb, cap);
    k_part<<<(nnz + CHUNK - 1) / CHUNK, 256, 0, stream>>>(rows, cols, vals, recTmp, sbpos, nnz, FLAG);
    k_sortsb<<<nsb, 1024, 0, stream>>>(recTmp, rec2, rstart, rend, sbpos, cap, n_rows);
}

extern "C" void kernel_launch(void* const* d_in, const int* in_sizes, int n_in,
                              void* d_out, int out_size, void* d_ws, size_t ws_size,
                              hipStream_t stream) {
    const int* users = (const int*)d_in[0];
    const int* pos   = (const int*)d_in[1];
    const int* neg   = (const int*)d_in[2];
    const int* adj_r = (const int*)d_in[3];
    const int* adj_c = (const int*)d_in[4];
    const void* adj_v = d_in[5];
    const int* ug_r  = (const int*)d_in[6];
    const int* ug_c  = (const int*)d_in[7];
    const void* ug_v = d_in[8];
    const int* ig_r  = (const int*)d_in[9];
    const int* ig_c  = (const int*)d_in[10];
    const void* ig_v = d_in[11];
    const void* ue   = d_in[12];
    const void* ie   = d_in[13];
    const void* Wgc  = d_in[14];
    const void* bgc  = d_in[15];
    const void* Wbi  = d_in[16];
    const void* bbi  = d_in[17];
    const void* Wu0  = d_in[18];
    const void* bu0  = d_in[19];
    const void* Wu1  = d_in[20];
    const void* bu1  = d_in[21];
    const void* Wi0  = d_in[22];
    const void* bi0  = d_in[23];
    const void* Wi1  = d_in[24];
    const void* bi1  = d_in[25];

    char* ws = (char*)d_ws;
    int*   FLAG  = (int*)(ws + 0);                       // 256 B
    bf16*  S16A  = (bf16*)(ws + 256);                    // NTOT*64*2 = 23,040,000 (adj S)
    bf16*  S16T  = (bf16*)(ws + 46080256L);              // N_ITEM*64*2 = 15,360,000
    bf16*  ego16 = (bf16*)(ws + 61440256L);              // E0, 23,040,000
    bf16*  UH    = (bf16*)(ws + 84480256L);              //  7,680,000
    bf16*  IH    = (bf16*)(ws + 92160256L);              // 15,360,000
    bf16*  E1    = (bf16*)(ws + 107520256L);             // 23,040,000
    bf16*  E2    = (bf16*)(ws + 130560256L);             // 23,040,000
    bf16*  E3    = (bf16*)(ws + 153600256L);             // 23,040,000
    // T2 (bf16, <=15.36 MB) aliases E2: dead before layer k=1 writes E2
    bf16*  T2    = (bf16*)(ws + 130560256L);
    // recTmp aliases S16A (+slack to 46 MB): builds finish before layer 0 writes S16A
    uint2* recTmp = (uint2*)(ws + 256);                  // 30,277,632 max
    uint2* rec2A = (uint2*)(ws + 176640256L);            // 30,277,632
    uint2* rec2U = (uint2*)(ws + 206917888L);            //  8,355,840
    uint2* rec2I = (uint2*)(ws + 215273728L);            // 16,433,152
    int* rstartA = (int*)(ws + 231706880L);              //    720,000
    int* rendA   = (int*)(ws + 232426880L);              //    720,000
    int* rstartU = (int*)(ws + 233146880L);              //    240,000
    int* rendU   = (int*)(ws + 233386880L);              //    240,000
    int* rstartI = (int*)(ws + 233626880L);              //    480,000
    int* rendI   = (int*)(ws + 234106880L);              //    480,000
    int* sbpos   = (int*)(ws + 234586880L);              //      6,144
    float* SC1   = (float*)(ws + 234600192L);            //    720,000
    float* SC2   = (float*)(ws + 235320192L);            //    720,000
    float* SC3   = (float*)(ws + 236040192L);            //    720,000
                                                         // end 236,760,192 (< 261,120,256 proven)

    k_detect<<<1, 64, 0, stream>>>(adj_v, FLAG);
    k_cast16<<<45000, 256, 0, stream>>>(ue, ie, ego16, FLAG);

    // ---- two-level build of row-sorted packed records (recTmp aliases S16A) ----
    build_graph(ug_r,  ug_c,  ug_v,  NNZ_UG,  NSB_UG,  CAPU_SB, N_USER,
                sbpos, recTmp, rec2U, rstartU, rendU, FLAG, stream);
    build_graph(ig_r,  ig_c,  ig_v,  NNZ_IG,  NSB_IG,  CAPI_SB, N_ITEM,
                sbpos, recTmp, rec2I, rstartI, rendI, FLAG, stream);
    build_graph(adj_r, adj_c, adj_v, NNZ_ADJ, NSB_ADJ, CAPA_SB, NTOT,
                sbpos, recTmp, rec2A, rstartA, rendA, FLAG, stream);

    // ---- user MLP branch (bf16 S throughout) ----
    int gu = (N_USER / 16 + 7) / 8;     // ~2 row-tiles per wave
    int gi = (N_ITEM / 16 + 7) / 8;
    k_spmm_bf<<<(N_USER + 31) / 32, 256, 0, stream>>>(rstartU, rendU, rec2U, ego16, S16T, N_USER);
    k_gemm64<1><<<gu, 256, 0, stream>>>(S16T, Wu0, bu0, T2, N_USER, FLAG);
    k_spmm_bf<<<(N_USER + 31) / 32, 256, 0, stream>>>(rstartU, rendU, rec2U, T2, S16T, N_USER);
    k_gemm64<2><<<gu, 256, 0, stream>>>(S16T, Wu1, bu1, UH, N_USER, FLAG);

    // ---- item MLP branch ----
    const bf16* ego16I = ego16 + (size_t)N_USER * 64;
    k_spmm_bf<<<(N_ITEM + 31) / 32, 256, 0, stream>>>(rstartI, rendI, rec2I, ego16I, S16T, N_ITEM);
    k_gemm64<1><<<gi, 256, 0, stream>>>(S16T, Wi0, bi0, T2, N_ITEM, FLAG);
    k_spmm_bf<<<(N_ITEM + 31) / 32, 256, 0, stream>>>(rstartI, rendI, rec2I, T2, S16T, N_ITEM);
    k_gemm64<2><<<gi, 256, 0, stream>>>(S16T, Wi1, bi1, IH, N_ITEM, FLAG);

    // ---- 3 NGCF layers: S-only spmm; layer forms P in-register, stores E_k + scale ----
    bf16* Ebuf[4]  = {ego16, E1, E2, E3};
    float* SCs[3]  = {SC1, SC2, SC3};
    for (int k = 0; k < 3; k++) {
        k_spmm_bf<<<(NTOT + 31) / 32, 256, 0, stream>>>(rstartA, rendA, rec2A, Ebuf[k], S16A, NTOT);
        k_layer<<<704, 256, 0, stream>>>(S16A, Ebuf[k], Ebuf[k + 1],
                                         Wgc, bgc, Wbi, bbi,
                                         (long)k * 4096, (long)k * 64,
                                         SCs[k], NTOT, FLAG);
    }

    // ---- output gather ----
    k_gather<<<12288, 64, 0, stream>>>(users, pos, neg, ue, ie, E1, E2, E3,
                                       SC1, SC2, SC3, UH, IH, d_out, FLAG);
}

// Round 7
// 838.447 us; speedup vs baseline: 1.2759x; 1.1558x over previous
//
#include <hip/hip_runtime.h>
#include <hip/hip_bf16.h>

#define N_USER 60000
#define N_ITEM 120000
#define NTOT   180000
#define NNZ_ADJ 3600000
#define NNZ_UG   960000
#define NNZ_IG  1920000

#define RSB     2048        // rows per super-bin
#define NSB_ADJ ((NTOT  + RSB - 1) / RSB)   // 88
#define NSB_UG  ((N_USER+ RSB - 1) / RSB)   // 30
#define NSB_IG  ((N_ITEM+ RSB - 1) / RSB)   // 59
#define CAPA_SB 43008       // mean 40960 + 10 sigma
#define CAPU_SB 34816
#define CAPI_SB 34816
#define CHUNK   4096
#define PB_U ((NNZ_UG  + CHUNK - 1) / CHUNK)   // 235
#define PB_I ((NNZ_IG  + CHUNK - 1) / CHUNK)   // 469
#define PB_A ((NNZ_ADJ + CHUNK - 1) / CHUNK)   // 879

typedef __hip_bfloat16 bf16;
typedef __attribute__((ext_vector_type(8))) short bf16x8;   // one MFMA A/B fragment
typedef __attribute__((ext_vector_type(4))) float f32x4;    // one MFMA C/D fragment

// load float element i from input tensor of unknown dtype: flag=1 -> fp32, 0 -> bf16
__device__ __forceinline__ float ldf(const void* p, long i, int f) {
    return f ? ((const float*)p)[i] : __bfloat162float(((const bf16*)p)[i]);
}

// pack two fp32 -> one uint holding 2 bf16
__device__ __forceinline__ unsigned pk2(float a, float b) {
    unsigned short lo = __bfloat16_as_ushort(__float2bfloat16(a));
    unsigned short hi = __bfloat16_as_ushort(__float2bfloat16(b));
    return (unsigned)lo | ((unsigned)hi << 16);
}

// elementwise bf16 product of two bf16x8 fragments (for P = E .* S in-register)
__device__ __forceinline__ bf16x8 mul_bf8(bf16x8 x, bf16x8 y) {
    bf16x8 r;
#pragma unroll
    for (int e = 0; e < 8; e++) {
        float xf = __uint_as_float(((unsigned)(unsigned short)x[e]) << 16);
        float yf = __uint_as_float(((unsigned)(unsigned short)y[e]) << 16);
        r[e] = (short)__bfloat16_as_ushort(__float2bfloat16(xf * yf));
    }
    return r;
}

// ---------------- dtype detector (adj_vals >= 0 -> bf16 words have bit15==0) ----
__global__ void k_detect(const void* __restrict__ vals, int* __restrict__ flag) {
    if (threadIdx.x == 0 && blockIdx.x == 0) {
        const unsigned short* w = (const unsigned short*)vals;
        int cnt = 0;
        for (int i = 0; i < 512; i += 2) cnt += (w[i] >> 15) & 1;
        *flag = (cnt > 16) ? 1 : 0;
    }
}

// ---------------- cast user/item emb -> ego bf16 ----------------
__global__ __launch_bounds__(256) void k_cast16(const void* __restrict__ ue,
                                                const void* __restrict__ ie,
                                                bf16* __restrict__ ego16,
                                                const int* __restrict__ flag) {
    int f = *flag;
    long i = (long)blockIdx.x * 256 + threadIdx.x;   // NTOT*64 = 11,520,000
    const long uN = (long)N_USER * 64;
    if (i < (long)NTOT * 64) {
        float v = (i < uN) ? ldf(ue, i, f) : ldf(ie, i - uN, f);
        ego16[i] = __float2bfloat16(v);
    }
}

// ================= merged two-level binned build (round-6: the 3 sequential
// build pipelines had 30/59/88-block launches on 256 CUs -> latency-additive;
// merged launches run all graphs' blocks concurrently, per-block code identical) =================
__global__ void k_initpos3(int* __restrict__ sbU, int* __restrict__ sbI,
                           int* __restrict__ sbA) {
    int i = threadIdx.x;
    if (i < NSB_UG)  sbU[i * 16] = i * CAPU_SB;
    if (i < NSB_IG)  sbI[i * 16] = i * CAPI_SB;
    if (i < NSB_ADJ) sbA[i * 16] = i * CAPA_SB;
}

// L1: partition edges into super-bins (2048 rows each), all 3 graphs in one grid.
// Record: {rl(11b)<<18 | col(18b), val_f32}
__global__ __launch_bounds__(256) void k_part3(const int* __restrict__ rU, const int* __restrict__ cU, const void* __restrict__ vU,
                                               const int* __restrict__ rI, const int* __restrict__ cI, const void* __restrict__ vI,
                                               const int* __restrict__ rA, const int* __restrict__ cA, const void* __restrict__ vA,
                                               uint2* __restrict__ recU, uint2* __restrict__ recI, uint2* __restrict__ recA,
                                               int* __restrict__ sbU, int* __restrict__ sbI, int* __restrict__ sbA,
                                               const int* __restrict__ flag) {
    __shared__ int lcnt[96];
    __shared__ int lbase[96];
    int f = *flag;
    int t = threadIdx.x;
    int b = blockIdx.x;
    const int *rows, *cols; const void* vals; uint2* rec; int* sbpos; int nnz, base;
    if (b < PB_U)             { rows = rU; cols = cU; vals = vU; rec = recU; sbpos = sbU; nnz = NNZ_UG;  base = b * CHUNK; }
    else if (b < PB_U + PB_I) { rows = rI; cols = cI; vals = vI; rec = recI; sbpos = sbI; nnz = NNZ_IG;  base = (b - PB_U) * CHUNK; }
    else                      { rows = rA; cols = cA; vals = vA; rec = recA; sbpos = sbA; nnz = NNZ_ADJ; base = (b - PB_U - PB_I) * CHUNK; }

    if (t < 96) lcnt[t] = 0;
    __syncthreads();
    for (int k = 0; k < CHUNK / 256; k++) {
        int e = base + k * 256 + t;
        if (e < nnz) atomicAdd(&lcnt[rows[e] >> 11], 1);
    }
    __syncthreads();
    if (t < 96) {
        int c = lcnt[t];
        lbase[t] = c ? atomicAdd(&sbpos[t * 16], c) : 0;
        lcnt[t] = 0;
    }
    __syncthreads();
    for (int k = 0; k < CHUNK / 256; k++) {
        int e = base + k * 256 + t;
        if (e < nnz) {
            int r = rows[e];
            int sb = r >> 11;
            int o = atomicAdd(&lcnt[sb], 1);
            unsigned meta = ((unsigned)(r & 2047) << 18) | (unsigned)cols[e];
            rec[lbase[sb] + o] = make_uint2(meta, __float_as_uint(ldf(vals, e, f)));
        }
    }
}

// L2: per-super-bin counting sort into row order, all 3 graphs in one grid
// (30+59+88 = 177 blocks, 2 blocks/CU -> fully concurrent).
__global__ __launch_bounds__(1024) void k_sortsb3(
        const uint2* __restrict__ recU, uint2* __restrict__ rec2U, int* __restrict__ rstartU, int* __restrict__ rendU, const int* __restrict__ sbU,
        const uint2* __restrict__ recI, uint2* __restrict__ rec2I, int* __restrict__ rstartI, int* __restrict__ rendI, const int* __restrict__ sbI,
        const uint2* __restrict__ recA, uint2* __restrict__ rec2A, int* __restrict__ rstartA, int* __restrict__ rendA, const int* __restrict__ sbA) {
    __shared__ int cnt[RSB];
    __shared__ int pos[RSB];
    __shared__ int carry;
    int b = blockIdx.x, t = threadIdx.x;
    const uint2* rec; uint2* rec2; int* rstart; int* rend; const int* sbpos;
    int cap, n_rows, lb;
    if (b < NSB_UG) {
        lb = b; rec = recU; rec2 = rec2U; rstart = rstartU; rend = rendU;
        sbpos = sbU; cap = CAPU_SB; n_rows = N_USER;
    } else if (b < NSB_UG + NSB_IG) {
        lb = b - NSB_UG; rec = recI; rec2 = rec2I; rstart = rstartI; rend = rendI;
        sbpos = sbI; cap = CAPI_SB; n_rows = N_ITEM;
    } else {
        lb = b - NSB_UG - NSB_IG; rec = recA; rec2 = rec2A; rstart = rstartA; rend = rendA;
        sbpos = sbA; cap = CAPA_SB; n_rows = NTOT;
    }
    int s = lb * cap;
    int e = sbpos[lb * 16];          // final fill cursor
    cnt[t] = 0; cnt[t + 1024] = 0;
    if (t == 0) carry = 0;
    __syncthreads();
    for (int j = s + t; j < e; j += 1024)
        atomicAdd(&cnt[rec[j].x >> 18], 1);
    __syncthreads();
    for (int tile = 0; tile < 2; tile++) {
        int i = tile * 1024 + t;
        int v = cnt[i];
        pos[i] = v;
        __syncthreads();
        for (int d = 1; d < 1024; d <<= 1) {
            int w = (t >= d) ? pos[i - d] : 0;
            __syncthreads();
            if (t >= d) pos[i] += w;
            __syncthreads();
        }
        int inc = pos[i];            // inclusive within tile
        int ex  = carry + inc - v;   // exclusive global
        __syncthreads();
        pos[i] = ex;
        if (t == 1023) carry += inc;
        __syncthreads();
    }
    int row0 = lb * RSB;
    for (int i = t; i < RSB; i += 1024) {
        int row = row0 + i;
        if (row < n_rows) {
            rstart[row] = s + pos[i];
            rend[row]   = s + pos[i] + cnt[i];
        }
    }
    __syncthreads();
    for (int j = s + t; j < e; j += 1024) {
        uint2 r = rec[j];
        int o = atomicAdd(&pos[r.x >> 18], 1);
        rec2[s + o] = r;
    }
}

#define ACC8(q, v)                                      \
    a[0] += (v) * __uint_as_float((q).x << 16);         \
    a[1] += (v) * __uint_as_float((q).x & 0xFFFF0000u); \
    a[2] += (v) * __uint_as_float((q).y << 16);         \
    a[3] += (v) * __uint_as_float((q).y & 0xFFFF0000u); \
    a[4] += (v) * __uint_as_float((q).z << 16);         \
    a[5] += (v) * __uint_as_float((q).z & 0xFFFF0000u); \
    a[6] += (v) * __uint_as_float((q).w << 16);         \
    a[7] += (v) * __uint_as_float((q).w & 0xFFFF0000u);

// ================= CSR SpMM row body, bf16 x: one row per 8-lane octet =========
// Edge loop unrolled x4 with grouped loads (4 gathers in flight per wave).
__device__ __forceinline__ void spmm_row(int row, int p,
                                         const int* __restrict__ rstart,
                                         const int* __restrict__ rend,
                                         const uint2* __restrict__ rec,
                                         const bf16* __restrict__ x,
                                         bf16* __restrict__ out) {
    int s = rstart[row], e = rend[row];
    const uint4* xb = (const uint4*)x;   // 8 bf16 per uint4
    float a[8];
#pragma unroll
    for (int i = 0; i < 8; i++) a[i] = 0.0f;

    int j = s;
    for (; j + 4 <= e; j += 4) {
        uint2 r0 = rec[j];
        uint2 r1 = rec[j + 1];
        uint2 r2 = rec[j + 2];
        uint2 r3 = rec[j + 3];
        uint4 q0 = xb[(long)(r0.x & 0x3FFFF) * 8 + p];
        uint4 q1 = xb[(long)(r1.x & 0x3FFFF) * 8 + p];
        uint4 q2 = xb[(long)(r2.x & 0x3FFFF) * 8 + p];
        uint4 q3 = xb[(long)(r3.x & 0x3FFFF) * 8 + p];
        float v0 = __uint_as_float(r0.y);
        float v1 = __uint_as_float(r1.y);
        float v2 = __uint_as_float(r2.y);
        float v3 = __uint_as_float(r3.y);
        ACC8(q0, v0)
        ACC8(q1, v1)
        ACC8(q2, v2)
        ACC8(q3, v3)
    }
    for (; j < e; j++) {
        uint2 r = rec[j];
        uint4 q = xb[(long)(r.x & 0x3FFFF) * 8 + p];
        float v = __uint_as_float(r.y);
        ACC8(q, v)
    }

    *(uint4*)(out + (long)row * 64 + p * 8) =
        make_uint4(pk2(a[0], a[1]), pk2(a[2], a[3]),
                   pk2(a[4], a[5]), pk2(a[6], a[7]));
}

// single-segment spmm (adjacency layer loop)
__global__ __launch_bounds__(256) void k_spmm_bf(const int* __restrict__ rstart,
                                                 const int* __restrict__ rend,
                                                 const uint2* __restrict__ rec,
                                                 const bf16* __restrict__ x,
                                                 bf16* __restrict__ out,
                                                 int n_rows) {
    int row = blockIdx.x * 32 + (threadIdx.x >> 3);
    int p = threadIdx.x & 7;
    if (row >= n_rows) return;
    spmm_row(row, p, rstart, rend, rec, x, out);
}

// two-segment spmm (user+item MLP stages merged into one launch)
__global__ __launch_bounds__(256) void k_spmm2(
        const int* __restrict__ rs0, const int* __restrict__ re0, const uint2* __restrict__ rc0,
        const bf16* __restrict__ x0, bf16* __restrict__ o0, int n0, int nb0,
        const int* __restrict__ rs1, const int* __restrict__ re1, const uint2* __restrict__ rc1,
        const bf16* __restrict__ x1, bf16* __restrict__ o1, int n1) {
    int b = blockIdx.x;
    int p = threadIdx.x & 7;
    int rl = threadIdx.x >> 3;
    if (b < nb0) {
        int row = b * 32 + rl;
        if (row < n0) spmm_row(row, p, rs0, re0, rc0, x0, o0);
    } else {
        int row = (b - nb0) * 32 + rl;
        if (row < n1) spmm_row(row, p, rs1, re1, rc1, x1, o1);
    }
}

// ---------------- two-segment Y = act(X16 @ W + b) -> bf16 (MFMA) --------------
// User and item branches share the stage; blocks route by range. Per-segment
// grid-stride identical to the separate launches -> bit-identical output.
// Weights split bf16 hi+lo for fp32-like accuracy (weight error ~2^-17).
// A frag: row = lane&15, k = 8*(lane>>4)+e. D frag: col = lane&15,
// row = 4*(lane>>4)+reg [verified mapping].
template <int ACT>
__global__ __launch_bounds__(256) void k_gemm2(
        const bf16* __restrict__ X0, const void* __restrict__ W0, const void* __restrict__ b0,
        bf16* __restrict__ Y0, int M0, int nb0,
        const bf16* __restrict__ X1, const void* __restrict__ W1, const void* __restrict__ b1,
        bf16* __restrict__ Y1, int M1,
        const int* __restrict__ flag) {
    __shared__ bf16 WtH[64][72];
    __shared__ bf16 WtL[64][72];
    __shared__ float bl[64];
    int f = *flag;
    int tid = threadIdx.x;
    int bId = blockIdx.x;
    const bf16* X; const void* W; const void* bb; bf16* Y; int M, sb, nbseg;
    if (bId < nb0) { X = X0; W = W0; bb = b0; Y = Y0; M = M0; sb = bId; nbseg = nb0; }
    else { X = X1; W = W1; bb = b1; Y = Y1; M = M1; sb = bId - nb0; nbseg = gridDim.x - nb0; }

    for (int idx = tid; idx < 4096; idx += 256) {
        int n = idx >> 6, kk = idx & 63;
        float v = ldf(W, (long)kk * 64 + n, f);
        bf16 h = __float2bfloat16(v);
        WtH[n][kk] = h;
        WtL[n][kk] = __float2bfloat16(v - __bfloat162float(h));
    }
    if (tid < 64) bl[tid] = ldf(bb, tid, f);
    __syncthreads();

    int l  = tid & 63;
    int lr = l & 15;      // A row / D col within tile
    int lk = l >> 4;      // k sub-block / D row group

    bf16x8 bh[2][4], bbf[2][4];
#pragma unroll
    for (int kt = 0; kt < 2; kt++)
#pragma unroll
        for (int ct = 0; ct < 4; ct++) {
            int n  = ct * 16 + lr;
            int ko = kt * 32 + lk * 8;
            bh[kt][ct]  = *(const bf16x8*)&WtH[n][ko];
            bbf[kt][ct] = *(const bf16x8*)&WtL[n][ko];
        }

    int nt  = M >> 4;                       // M is a multiple of 16
    int wid = sb * 4 + (tid >> 6);
    int nw  = nbseg * 4;

    for (int t = wid; t < nt; t += nw) {
        const bf16* Ap = X + (long)(t * 16 + lr) * 64 + lk * 8;
        bf16x8 a[2];
#pragma unroll
        for (int kt = 0; kt < 2; kt++) a[kt] = *(const bf16x8*)(Ap + kt * 32);

        f32x4 acc[4];
#pragma unroll
        for (int ct = 0; ct < 4; ct++) {
            float bv = bl[ct * 16 + lr];
            acc[ct] = (f32x4){bv, bv, bv, bv};
        }
#pragma unroll
        for (int kt = 0; kt < 2; kt++)
#pragma unroll
            for (int ct = 0; ct < 4; ct++) {
                acc[ct] = __builtin_amdgcn_mfma_f32_16x16x32_bf16(a[kt], bh[kt][ct], acc[ct], 0, 0, 0);
                acc[ct] = __builtin_amdgcn_mfma_f32_16x16x32_bf16(a[kt], bbf[kt][ct], acc[ct], 0, 0, 0);
            }

#pragma unroll
        for (int r = 0; r < 4; r++) {
            float v0 = acc[0][r], v1 = acc[1][r], v2 = acc[2][r], v3 = acc[3][r];
            if (ACT == 2) {
                v0 = fmaxf(v0, 0.0f); v1 = fmaxf(v1, 0.0f);
                v2 = fmaxf(v2, 0.0f); v3 = fmaxf(v3, 0.0f);
            } else {
                v0 = (v0 > 0.0f) ? v0 : (expf(v0) - 1.0f);
                v1 = (v1 > 0.0f) ? v1 : (expf(v1) - 1.0f);
                v2 = (v2 > 0.0f) ? v2 : (expf(v2) - 1.0f);
                v3 = (v3 > 0.0f) ? v3 : (expf(v3) - 1.0f);
            }
            long ob = (long)(t * 16 + lk * 4 + r) * 64 + lr;
            Y[ob]      = __float2bfloat16(v0);
            Y[ob + 16] = __float2bfloat16(v1);
            Y[ob + 32] = __float2bfloat16(v2);
            Y[ob + 48] = __float2bfloat16(v3);
        }
    }
}

// ---------------- NGCF layer: E_out = leakyrelu(S@W1 + (E.*S)@W2 + b) --------
// P = E.*S formed IN-REGISTER (row-local). Only the per-row l2 scale (f32) is
// stored; k_gather applies E_k * scale. W1/W2 in LDS (B^T layout, +8 pad),
// bf16 hi+lo split.
__global__ __launch_bounds__(256) void k_layer(const bf16* __restrict__ S,
                                               const bf16* __restrict__ Ein,
                                               bf16* __restrict__ Eout,
                                               const void* __restrict__ Wgc,
                                               const void* __restrict__ bgc,
                                               const void* __restrict__ Wbi,
                                               const void* __restrict__ bbi,
                                               long woff, long boff,
                                               float* __restrict__ scale, int M,
                                               const int* __restrict__ flag) {
    __shared__ bf16 W1H[64][72];
    __shared__ bf16 W1L[64][72];
    __shared__ bf16 W2H[64][72];
    __shared__ bf16 W2L[64][72];
    __shared__ float bl[64];
    int f = *flag;
    int tid = threadIdx.x;
    for (int idx = tid; idx < 4096; idx += 256) {
        int n = idx >> 6, kk = idx & 63;
        float v1 = ldf(Wgc, woff + (long)kk * 64 + n, f);
        float v2 = ldf(Wbi, woff + (long)kk * 64 + n, f);
        bf16 h1 = __float2bfloat16(v1);
        bf16 h2 = __float2bfloat16(v2);
        W1H[n][kk] = h1;
        W1L[n][kk] = __float2bfloat16(v1 - __bfloat162float(h1));
        W2H[n][kk] = h2;
        W2L[n][kk] = __float2bfloat16(v2 - __bfloat162float(h2));
    }
    if (tid < 64) bl[tid] = ldf(bgc, boff + tid, f) + ldf(bbi, boff + tid, f);
    __syncthreads();

    int l  = tid & 63;
    int lr = l & 15;
    int lk = l >> 4;

    bf16x8 w1h[2][4], w1l[2][4], w2h[2][4], w2l[2][4];
#pragma unroll
    for (int kt = 0; kt < 2; kt++)
#pragma unroll
        for (int ct = 0; ct < 4; ct++) {
            int n  = ct * 16 + lr;
            int ko = kt * 32 + lk * 8;
            w1h[kt][ct] = *(const bf16x8*)&W1H[n][ko];
            w1l[kt][ct] = *(const bf16x8*)&W1L[n][ko];
            w2h[kt][ct] = *(const bf16x8*)&W2H[n][ko];
            w2l[kt][ct] = *(const bf16x8*)&W2L[n][ko];
        }

    int nt  = M >> 4;                 // 11250 for NTOT
    int wid = blockIdx.x * 4 + (tid >> 6);
    int nw  = gridDim.x * 4;

    for (int t = wid; t < nt; t += nw) {
        long rb = (long)(t * 16 + lr) * 64 + lk * 8;
        bf16x8 sv[2], pv[2];
        sv[0] = *(const bf16x8*)(S + rb);
        sv[1] = *(const bf16x8*)(S + rb + 32);
        {
            bf16x8 e0 = *(const bf16x8*)(Ein + rb);
            bf16x8 e1 = *(const bf16x8*)(Ein + rb + 32);
            pv[0] = mul_bf8(e0, sv[0]);
            pv[1] = mul_bf8(e1, sv[1]);
        }

        f32x4 acc[4];
#pragma unroll
        for (int ct = 0; ct < 4; ct++) {
            float bv = bl[ct * 16 + lr];
            acc[ct] = (f32x4){bv, bv, bv, bv};
        }
#pragma unroll
        for (int kt = 0; kt < 2; kt++)
#pragma unroll
            for (int ct = 0; ct < 4; ct++) {
                acc[ct] = __builtin_amdgcn_mfma_f32_16x16x32_bf16(sv[kt], w1h[kt][ct], acc[ct], 0, 0, 0);
                acc[ct] = __builtin_amdgcn_mfma_f32_16x16x32_bf16(sv[kt], w1l[kt][ct], acc[ct], 0, 0, 0);
                acc[ct] = __builtin_amdgcn_mfma_f32_16x16x32_bf16(pv[kt], w2h[kt][ct], acc[ct], 0, 0, 0);
                acc[ct] = __builtin_amdgcn_mfma_f32_16x16x32_bf16(pv[kt], w2l[kt][ct], acc[ct], 0, 0, 0);
            }

#pragma unroll
        for (int r = 0; r < 4; r++) {
            float v0 = acc[0][r], v1 = acc[1][r], v2 = acc[2][r], v3 = acc[3][r];
            v0 = (v0 > 0.0f) ? v0 : 0.2f * v0;
            v1 = (v1 > 0.0f) ? v1 : 0.2f * v1;
            v2 = (v2 > 0.0f) ? v2 : 0.2f * v2;
            v3 = (v3 > 0.0f) ? v3 : 0.2f * v3;
            float ss = v0 * v0 + v1 * v1 + v2 * v2 + v3 * v3;
            ss += __shfl_xor(ss, 1, 64);    // reduce over the 16-lane column group
            ss += __shfl_xor(ss, 2, 64);
            ss += __shfl_xor(ss, 4, 64);
            ss += __shfl_xor(ss, 8, 64);
            float sc2 = 1.0f / fmaxf(sqrtf(ss), 1e-12f);
            int grow = t * 16 + lk * 4 + r;
            long ob = (long)grow * 64 + lr;
            Eout[ob]      = __float2bfloat16(v0);
            Eout[ob + 16] = __float2bfloat16(v1);
            Eout[ob + 32] = __float2bfloat16(v2);
            Eout[ob + 48] = __float2bfloat16(v3);
            if (lr == 0) scale[grow] = sc2;
        }
    }
}

// ---------------- final gather into output ----------------
// nm_k[row] reconstructed as E_k[row] * scale_k[row] (norms not materialized).
__global__ __launch_bounds__(64) void k_gather(const int* __restrict__ users,
                                               const int* __restrict__ pos,
                                               const int* __restrict__ neg,
                                               const void* __restrict__ ue,
                                               const void* __restrict__ ie,
                                               const bf16* __restrict__ E1,
                                               const bf16* __restrict__ E2,
                                               const bf16* __restrict__ E3,
                                               const float* __restrict__ s1,
                                               const float* __restrict__ s2,
                                               const float* __restrict__ s3,
                                               const bf16* __restrict__ uh,
                                               const bf16* __restrict__ ih,
                                               void* __restrict__ out,
                                               const int* __restrict__ flag) {
    int f = *flag;
    int b = blockIdx.x;           // 0..12287: [users | pos | neg] x 4096
    int which = b >> 12;
    int s = b & 4095;
    int lane = threadIdx.x;       // 64
    long ebase, nrow;
    const void* e0;
    const bf16* hh;
    if (which == 0) {
        int r = users[s];
        e0 = ue; ebase = (long)r * 64;
        hh = uh + (long)r * 64;
        nrow = (long)r;
    } else {
        int r = (which == 1) ? pos[s] : neg[s];
        e0 = ie; ebase = (long)r * 64;
        hh = ih + (long)r * 64;
        nrow = (long)(N_USER + r);
    }
    long nbase = nrow * 64;
    float o0 = ldf(e0, ebase + lane, f);
    float o1 = __bfloat162float(E1[nbase + lane]) * s1[nrow];
    float o2 = __bfloat162float(E2[nbase + lane]) * s2[nrow];
    float o3 = __bfloat162float(E3[nbase + lane]) * s3[nrow];
    float o4 = __bfloat162float(hh[lane]);
    long ob = (long)b * 320;
    if (f) {
        float* o = (float*)out + ob;
        o[lane] = o0; o[64 + lane] = o1; o[128 + lane] = o2;
        o[192 + lane] = o3; o[256 + lane] = o4;
    } else {
        bf16* o = (bf16*)out + ob;
        o[lane]       = __float2bfloat16(o0);
        o[64 + lane]  = __float2bfloat16(o1);
        o[128 + lane] = __float2bfloat16(o2);
        o[192 + lane] = __float2bfloat16(o3);
        o[256 + lane] = __float2bfloat16(o4);
    }
}

extern "C" void kernel_launch(void* const* d_in, const int* in_sizes, int n_in,
                              void* d_out, int out_size, void* d_ws, size_t ws_size,
                              hipStream_t stream) {
    const int* users = (const int*)d_in[0];
    const int* pos   = (const int*)d_in[1];
    const int* neg   = (const int*)d_in[2];
    const int* adj_r = (const int*)d_in[3];
    const int* adj_c = (const int*)d_in[4];
    const void* adj_v = d_in[5];
    const int* ug_r  = (const int*)d_in[6];
    const int* ug_c  = (const int*)d_in[7];
    const void* ug_v = d_in[8];
    const int* ig_r  = (const int*)d_in[9];
    const int* ig_c  = (const int*)d_in[10];
    const void* ig_v = d_in[11];
    const void* ue   = d_in[12];
    const void* ie   = d_in[13];
    const void* Wgc  = d_in[14];
    const void* bgc  = d_in[15];
    const void* Wbi  = d_in[16];
    const void* bbi  = d_in[17];
    const void* Wu0  = d_in[18];
    const void* bu0  = d_in[19];
    const void* Wu1  = d_in[20];
    const void* bu1  = d_in[21];
    const void* Wi0  = d_in[22];
    const void* bi0  = d_in[23];
    const void* Wi1  = d_in[24];
    const void* bi1  = d_in[25];

    char* ws = (char*)d_ws;
    int*   FLAG  = (int*)(ws + 0);                       // 256 B
    bf16*  S16A  = (bf16*)(ws + 256);                    // 23,040,000 (adj S, layer phase)
    // recTmpA aliases [256, 30,277,888): dead before S16A first written (layer phase)
    uint2* recTmpA = (uint2*)(ws + 256);                 // 30,277,632
    bf16*  SU    = (bf16*)(ws + 30277888L);              //  7,680,000 (user S, MLP) - after recTmpA
    bf16*  SI    = (bf16*)(ws + 46080256L);              // 15,360,000 (item S, MLP)
    bf16*  ego16 = (bf16*)(ws + 61440256L);              // E0, 23,040,000
    bf16*  UH    = (bf16*)(ws + 84480256L);              //  7,680,000
    bf16*  IH    = (bf16*)(ws + 92160256L);              // 15,360,000
    bf16*  E1    = (bf16*)(ws + 107520256L);             // 23,040,000
    bf16*  E2    = (bf16*)(ws + 130560256L);             // 23,040,000
    bf16*  E3    = (bf16*)(ws + 153600256L);             // 23,040,000
    // recTmpU aliases E2 head (dead before MLP writes TI); TI aliases E2 head;
    // TU aliases E2 tail. All dead before layer k=1 writes E2.
    uint2* recTmpU = (uint2*)(ws + 130560256L);          //  8,355,840
    bf16*  TI    = (bf16*)(ws + 130560256L);             // 15,360,000
    bf16*  TU    = (bf16*)(ws + 145920256L);             //  7,680,000 (ends 153,600,256)
    // recTmpI aliases E3 head: dead before layer k=2 writes E3
    uint2* recTmpI = (uint2*)(ws + 153600256L);          // 16,433,152
    uint2* rec2A = (uint2*)(ws + 176640256L);            // 30,277,632
    uint2* rec2U = (uint2*)(ws + 206917888L);            //  8,355,840
    uint2* rec2I = (uint2*)(ws + 215273728L);            // 16,433,152
    int* rstartA = (int*)(ws + 231706880L);              //    720,000
    int* rendA   = (int*)(ws + 232426880L);              //    720,000
    int* rstartU = (int*)(ws + 233146880L);              //    240,000
    int* rendU   = (int*)(ws + 233386880L);              //    240,000
    int* rstartI = (int*)(ws + 233626880L);              //    480,000
    int* rendI   = (int*)(ws + 234106880L);              //    480,000
    int* sbposU  = (int*)(ws + 234586880L);              //      1,920 (pad to 2,048)
    int* sbposI  = (int*)(ws + 234588928L);              //      3,776 (pad to 2,048x? -> 4,096)
    int* sbposA  = (int*)(ws + 234593024L);              //      5,632
    float* SC1   = (float*)(ws + 234600192L);            //    720,000
    float* SC2   = (float*)(ws + 235320192L);            //    720,000
    float* SC3   = (float*)(ws + 236040192L);            //    720,000
                                                         // end 236,760,192 (< 261,120,256 proven)

    k_detect<<<1, 64, 0, stream>>>(adj_v, FLAG);
    k_cast16<<<45000, 256, 0, stream>>>(ue, ie, ego16, FLAG);

    // ---- merged two-level build: 3 launches for all three graphs ----
    k_initpos3<<<1, 256, 0, stream>>>(sbposU, sbposI, sbposA);
    k_part3<<<PB_U + PB_I + PB_A, 256, 0, stream>>>(ug_r, ug_c, ug_v,
                                                    ig_r, ig_c, ig_v,
                                                    adj_r, adj_c, adj_v,
                                                    recTmpU, recTmpI, recTmpA,
                                                    sbposU, sbposI, sbposA, FLAG);
    k_sortsb3<<<NSB_UG + NSB_IG + NSB_ADJ, 1024, 0, stream>>>(
        recTmpU, rec2U, rstartU, rendU, sbposU,
        recTmpI, rec2I, rstartI, rendI, sbposI,
        recTmpA, rec2A, rstartA, rendA, sbposA);

    // ---- user+item MLP branches, stage-merged (2 spmm + 2 gemm launches) ----
    const bf16* ego16I = ego16 + (size_t)N_USER * 64;
    int nbU = (N_USER + 31) / 32;       // 1875
    int nbI = (N_ITEM + 31) / 32;       // 3750
    int gu = (N_USER / 16 + 7) / 8;     // 469 (~2 row-tiles per wave)
    int gi = (N_ITEM / 16 + 7) / 8;     // 938
    k_spmm2<<<nbU + nbI, 256, 0, stream>>>(rstartU, rendU, rec2U, ego16,  SU, N_USER, nbU,
                                           rstartI, rendI, rec2I, ego16I, SI, N_ITEM);
    k_gemm2<1><<<gu + gi, 256, 0, stream>>>(SU, Wu0, bu0, TU, N_USER, gu,
                                            SI, Wi0, bi0, TI, N_ITEM, FLAG);
    k_spmm2<<<nbU + nbI, 256, 0, stream>>>(rstartU, rendU, rec2U, TU, SU, N_USER, nbU,
                                           rstartI, rendI, rec2I, TI, SI, N_ITEM);
    k_gemm2<2><<<gu + gi, 256, 0, stream>>>(SU, Wu1, bu1, UH, N_USER, gu,
                                            SI, Wi1, bi1, IH, N_ITEM, FLAG);

    // ---- 3 NGCF layers: S-only spmm; layer forms P in-register, stores E_k + scale ----
    bf16* Ebuf[4]  = {ego16, E1, E2, E3};
    float* SCs[3]  = {SC1, SC2, SC3};
    for (int k = 0; k < 3; k++) {
        k_spmm_bf<<<(NTOT + 31) / 32, 256, 0, stream>>>(rstartA, rendA, rec2A, Ebuf[k], S16A, NTOT);
        k_layer<<<704, 256, 0, stream>>>(S16A, Ebuf[k], Ebuf[k + 1],
                                         Wgc, bgc, Wbi, bbi,
                                         (long)k * 4096, (long)k * 64,
                                         SCs[k], NTOT, FLAG);
    }

    // ---- output gather ----
    k_gather<<<12288, 64, 0, stream>>>(users, pos, neg, ue, ie, E1, E2, E3,
                                       SC1, SC2, SC3, UH, IH, d_out, FLAG);
}

// Round 8
// 818.797 us; speedup vs baseline: 1.3065x; 1.0240x over previous
//
#include <hip/hip_runtime.h>
#include <hip/hip_bf16.h>

#define N_USER 60000
#define N_ITEM 120000
#define NTOT   180000
#define NNZ_ADJ 3600000
#define NNZ_UG   960000
#define NNZ_IG  1920000

#define RSB     2048        // rows per super-bin
#define NSB_ADJ ((NTOT  + RSB - 1) / RSB)   // 88
#define NSB_UG  ((N_USER+ RSB - 1) / RSB)   // 30
#define NSB_IG  ((N_ITEM+ RSB - 1) / RSB)   // 59
#define CAPA_SB 43008       // mean 40960 + 10 sigma
#define CAPU_SB 34816
#define CAPI_SB 34816
#define CHUNK   4096
#define PB_U ((NNZ_UG  + CHUNK - 1) / CHUNK)   // 235
#define PB_I ((NNZ_IG  + CHUNK - 1) / CHUNK)   // 469
#define PB_A ((NNZ_ADJ + CHUNK - 1) / CHUNK)   // 879

typedef __hip_bfloat16 bf16;
typedef __attribute__((ext_vector_type(8))) short bf16x8;   // one MFMA A/B fragment
typedef __attribute__((ext_vector_type(4))) float f32x4;    // one MFMA C/D fragment

// load float element i from input tensor of unknown dtype: flag=1 -> fp32, 0 -> bf16
__device__ __forceinline__ float ldf(const void* p, long i, int f) {
    return f ? ((const float*)p)[i] : __bfloat162float(((const bf16*)p)[i]);
}

// pack two fp32 -> one uint holding 2 bf16
__device__ __forceinline__ unsigned pk2(float a, float b) {
    unsigned short lo = __bfloat16_as_ushort(__float2bfloat16(a));
    unsigned short hi = __bfloat16_as_ushort(__float2bfloat16(b));
    return (unsigned)lo | ((unsigned)hi << 16);
}

// elementwise bf16 product of two bf16x8 fragments (for P = E .* S in-register)
__device__ __forceinline__ bf16x8 mul_bf8(bf16x8 x, bf16x8 y) {
    bf16x8 r;
#pragma unroll
    for (int e = 0; e < 8; e++) {
        float xf = __uint_as_float(((unsigned)(unsigned short)x[e]) << 16);
        float yf = __uint_as_float(((unsigned)(unsigned short)y[e]) << 16);
        r[e] = (short)__bfloat16_as_ushort(__float2bfloat16(xf * yf));
    }
    return r;
}

// ---------------- dtype detector (adj_vals >= 0 -> bf16 words have bit15==0) ----
__global__ void k_detect(const void* __restrict__ vals, int* __restrict__ flag) {
    if (threadIdx.x == 0 && blockIdx.x == 0) {
        const unsigned short* w = (const unsigned short*)vals;
        int cnt = 0;
        for (int i = 0; i < 512; i += 2) cnt += (w[i] >> 15) & 1;
        *flag = (cnt > 16) ? 1 : 0;
    }
}

// ---------------- cast user/item emb -> ego bf16 ----------------
__global__ __launch_bounds__(256) void k_cast16(const void* __restrict__ ue,
                                                const void* __restrict__ ie,
                                                bf16* __restrict__ ego16,
                                                const int* __restrict__ flag) {
    int f = *flag;
    long i = (long)blockIdx.x * 256 + threadIdx.x;   // NTOT*64 = 11,520,000
    const long uN = (long)N_USER * 64;
    if (i < (long)NTOT * 64) {
        float v = (i < uN) ? ldf(ue, i, f) : ldf(ie, i - uN, f);
        ego16[i] = __float2bfloat16(v);
    }
}

// ================= merged two-level binned build =================
__global__ void k_initpos3(int* __restrict__ sbU, int* __restrict__ sbI,
                           int* __restrict__ sbA) {
    int i = threadIdx.x;
    if (i < NSB_UG)  sbU[i * 16] = i * CAPU_SB;
    if (i < NSB_IG)  sbI[i * 16] = i * CAPI_SB;
    if (i < NSB_ADJ) sbA[i * 16] = i * CAPA_SB;
}

// L1: partition edges into super-bins (2048 rows each), all 3 graphs in one grid.
// Record: {rl(11b)<<18 | col(18b), val_f32}
// Round-8: both passes unrolled x4 with grouped loads (round-7 counters:
// VALUBusy 2.6%, hbm 18%, one dependent chain per thread -> latency-bound).
__global__ __launch_bounds__(256) void k_part3(const int* __restrict__ rU, const int* __restrict__ cU, const void* __restrict__ vU,
                                               const int* __restrict__ rI, const int* __restrict__ cI, const void* __restrict__ vI,
                                               const int* __restrict__ rA, const int* __restrict__ cA, const void* __restrict__ vA,
                                               uint2* __restrict__ recU, uint2* __restrict__ recI, uint2* __restrict__ recA,
                                               int* __restrict__ sbU, int* __restrict__ sbI, int* __restrict__ sbA,
                                               const int* __restrict__ flag) {
    __shared__ int lcnt[96];
    __shared__ int lbase[96];
    int f = *flag;
    int t = threadIdx.x;
    int b = blockIdx.x;
    const int *rows, *cols; const void* vals; uint2* rec; int* sbpos; int nnz, base;
    if (b < PB_U)             { rows = rU; cols = cU; vals = vU; rec = recU; sbpos = sbU; nnz = NNZ_UG;  base = b * CHUNK; }
    else if (b < PB_U + PB_I) { rows = rI; cols = cI; vals = vI; rec = recI; sbpos = sbI; nnz = NNZ_IG;  base = (b - PB_U) * CHUNK; }
    else                      { rows = rA; cols = cA; vals = vA; rec = recA; sbpos = sbA; nnz = NNZ_ADJ; base = (b - PB_U - PB_I) * CHUNK; }

    if (t < 96) lcnt[t] = 0;
    __syncthreads();
#pragma unroll
    for (int k = 0; k < CHUNK / 256; k += 4) {
        int e0 = base + k * 256 + t;
        int e1 = e0 + 256, e2 = e0 + 512, e3 = e0 + 768;
        int s0 = (e0 < nnz) ? (rows[e0] >> 11) : -1;
        int s1 = (e1 < nnz) ? (rows[e1] >> 11) : -1;
        int s2 = (e2 < nnz) ? (rows[e2] >> 11) : -1;
        int s3 = (e3 < nnz) ? (rows[e3] >> 11) : -1;
        if (s0 >= 0) atomicAdd(&lcnt[s0], 1);
        if (s1 >= 0) atomicAdd(&lcnt[s1], 1);
        if (s2 >= 0) atomicAdd(&lcnt[s2], 1);
        if (s3 >= 0) atomicAdd(&lcnt[s3], 1);
    }
    __syncthreads();
    if (t < 96) {
        int c = lcnt[t];
        lbase[t] = c ? atomicAdd(&sbpos[t * 16], c) : 0;
        lcnt[t] = 0;
    }
    __syncthreads();
#pragma unroll
    for (int k = 0; k < CHUNK / 256; k += 4) {
        int e0 = base + k * 256 + t;
        int e1 = e0 + 256, e2 = e0 + 512, e3 = e0 + 768;
        bool g0 = e0 < nnz, g1 = e1 < nnz, g2 = e2 < nnz, g3 = e3 < nnz;
        int r0 = g0 ? rows[e0] : 0;
        int r1 = g1 ? rows[e1] : 0;
        int r2 = g2 ? rows[e2] : 0;
        int r3 = g3 ? rows[e3] : 0;
        int c0 = g0 ? cols[e0] : 0;
        int c1 = g1 ? cols[e1] : 0;
        int c2 = g2 ? cols[e2] : 0;
        int c3 = g3 ? cols[e3] : 0;
        float v0 = g0 ? ldf(vals, e0, f) : 0.0f;
        float v1 = g1 ? ldf(vals, e1, f) : 0.0f;
        float v2 = g2 ? ldf(vals, e2, f) : 0.0f;
        float v3 = g3 ? ldf(vals, e3, f) : 0.0f;
        if (g0) { int sb = r0 >> 11; int o = atomicAdd(&lcnt[sb], 1);
                  rec[lbase[sb] + o] = make_uint2(((unsigned)(r0 & 2047) << 18) | (unsigned)c0, __float_as_uint(v0)); }
        if (g1) { int sb = r1 >> 11; int o = atomicAdd(&lcnt[sb], 1);
                  rec[lbase[sb] + o] = make_uint2(((unsigned)(r1 & 2047) << 18) | (unsigned)c1, __float_as_uint(v1)); }
        if (g2) { int sb = r2 >> 11; int o = atomicAdd(&lcnt[sb], 1);
                  rec[lbase[sb] + o] = make_uint2(((unsigned)(r2 & 2047) << 18) | (unsigned)c2, __float_as_uint(v2)); }
        if (g3) { int sb = r3 >> 11; int o = atomicAdd(&lcnt[sb], 1);
                  rec[lbase[sb] + o] = make_uint2(((unsigned)(r3 & 2047) << 18) | (unsigned)c3, __float_as_uint(v3)); }
    }
}

// L2: per-super-bin counting sort into row order, all 3 graphs in one grid.
// Round-8: Hillis-Steele 2-tile scan (~44 block barriers) replaced by a
// wave-shuffle scan (pair per thread, 6-step shfl_up, 16 wave sums, add-back:
// 4 barriers); count/scatter passes unrolled x4 with grouped loads.
__global__ __launch_bounds__(1024) void k_sortsb3(
        const uint2* __restrict__ recU, uint2* __restrict__ rec2U, int* __restrict__ rstartU, int* __restrict__ rendU, const int* __restrict__ sbU,
        const uint2* __restrict__ recI, uint2* __restrict__ rec2I, int* __restrict__ rstartI, int* __restrict__ rendI, const int* __restrict__ sbI,
        const uint2* __restrict__ recA, uint2* __restrict__ rec2A, int* __restrict__ rstartA, int* __restrict__ rendA, const int* __restrict__ sbA) {
    __shared__ int cnt[RSB];
    __shared__ int pos[RSB];
    __shared__ int wsum[16];
    int b = blockIdx.x, t = threadIdx.x;
    const uint2* rec; uint2* rec2; int* rstart; int* rend; const int* sbpos;
    int cap, n_rows, lb;
    if (b < NSB_UG) {
        lb = b; rec = recU; rec2 = rec2U; rstart = rstartU; rend = rendU;
        sbpos = sbU; cap = CAPU_SB; n_rows = N_USER;
    } else if (b < NSB_UG + NSB_IG) {
        lb = b - NSB_UG; rec = recI; rec2 = rec2I; rstart = rstartI; rend = rendI;
        sbpos = sbI; cap = CAPI_SB; n_rows = N_ITEM;
    } else {
        lb = b - NSB_UG - NSB_IG; rec = recA; rec2 = rec2A; rstart = rstartA; rend = rendA;
        sbpos = sbA; cap = CAPA_SB; n_rows = NTOT;
    }
    int s = lb * cap;
    int e = sbpos[lb * 16];          // final fill cursor
    cnt[t] = 0; cnt[t + 1024] = 0;
    __syncthreads();
    // ---- count pass, x4 unrolled (stride 1024) ----
    int j = s + t;
    for (; j + 3072 < e; j += 4096) {
        uint2 r0 = rec[j];
        uint2 r1 = rec[j + 1024];
        uint2 r2 = rec[j + 2048];
        uint2 r3 = rec[j + 3072];
        atomicAdd(&cnt[r0.x >> 18], 1);
        atomicAdd(&cnt[r1.x >> 18], 1);
        atomicAdd(&cnt[r2.x >> 18], 1);
        atomicAdd(&cnt[r3.x >> 18], 1);
    }
    for (; j < e; j += 1024)
        atomicAdd(&cnt[rec[j].x >> 18], 1);
    __syncthreads();
    // ---- wave-shuffle exclusive scan over 2048 counts (pair per thread) ----
    int a  = cnt[2 * t];
    int bb = cnt[2 * t + 1];
    int ps = a + bb;                 // pair sum
    int incl = ps;                   // inclusive scan of pair sums within wave
    int lane = t & 63;
#pragma unroll
    for (int d = 1; d < 64; d <<= 1) {
        int v = __shfl_up(incl, d, 64);
        if (lane >= d) incl += v;
    }
    int wv = t >> 6;                 // wave id 0..15
    if (lane == 63) wsum[wv] = incl;
    __syncthreads();
    if (t < 16) {
        int v  = wsum[t];
        int iv = v;
#pragma unroll
        for (int d = 1; d < 16; d <<= 1) {
            int w = __shfl_up(iv, d, 64);
            if (t >= d) iv += w;
        }
        wsum[t] = iv - v;            // exclusive wave offset
    }
    __syncthreads();
    int ex0 = wsum[wv] + (incl - ps);    // exclusive prefix of element 2t
    pos[2 * t]     = ex0;
    pos[2 * t + 1] = ex0 + a;
    int row0 = lb * RSB;
    {
        int ra = row0 + 2 * t;
        if (ra < n_rows) { rstart[ra] = s + ex0;      rend[ra] = s + ex0 + a; }
        int rb = ra + 1;
        if (rb < n_rows) { rstart[rb] = s + ex0 + a;  rend[rb] = s + ex0 + a + bb; }
    }
    __syncthreads();
    // ---- scatter pass, x4 unrolled ----
    j = s + t;
    for (; j + 3072 < e; j += 4096) {
        uint2 r0 = rec[j];
        uint2 r1 = rec[j + 1024];
        uint2 r2 = rec[j + 2048];
        uint2 r3 = rec[j + 3072];
        int o0 = atomicAdd(&pos[r0.x >> 18], 1);
        int o1 = atomicAdd(&pos[r1.x >> 18], 1);
        int o2 = atomicAdd(&pos[r2.x >> 18], 1);
        int o3 = atomicAdd(&pos[r3.x >> 18], 1);
        rec2[s + o0] = r0;
        rec2[s + o1] = r1;
        rec2[s + o2] = r2;
        rec2[s + o3] = r3;
    }
    for (; j < e; j += 1024) {
        uint2 r = rec[j];
        int o = atomicAdd(&pos[r.x >> 18], 1);
        rec2[s + o] = r;
    }
}

#define ACC8(q, v)                                      \
    a[0] += (v) * __uint_as_float((q).x << 16);         \
    a[1] += (v) * __uint_as_float((q).x & 0xFFFF0000u); \
    a[2] += (v) * __uint_as_float((q).y << 16);         \
    a[3] += (v) * __uint_as_float((q).y & 0xFFFF0000u); \
    a[4] += (v) * __uint_as_float((q).z << 16);         \
    a[5] += (v) * __uint_as_float((q).z & 0xFFFF0000u); \
    a[6] += (v) * __uint_as_float((q).w << 16);         \
    a[7] += (v) * __uint_as_float((q).w & 0xFFFF0000u);

// ================= CSR SpMM row body, bf16 x: one row per 8-lane octet =========
// Edge loop unrolled x4 with grouped loads (4 gathers in flight per wave).
__device__ __forceinline__ void spmm_row(int row, int p,
                                         const int* __restrict__ rstart,
                                         const int* __restrict__ rend,
                                         const uint2* __restrict__ rec,
                                         const bf16* __restrict__ x,
                                         bf16* __restrict__ out) {
    int s = rstart[row], e = rend[row];
    const uint4* xb = (const uint4*)x;   // 8 bf16 per uint4
    float a[8];
#pragma unroll
    for (int i = 0; i < 8; i++) a[i] = 0.0f;

    int j = s;
    for (; j + 4 <= e; j += 4) {
        uint2 r0 = rec[j];
        uint2 r1 = rec[j + 1];
        uint2 r2 = rec[j + 2];
        uint2 r3 = rec[j + 3];
        uint4 q0 = xb[(long)(r0.x & 0x3FFFF) * 8 + p];
        uint4 q1 = xb[(long)(r1.x & 0x3FFFF) * 8 + p];
        uint4 q2 = xb[(long)(r2.x & 0x3FFFF) * 8 + p];
        uint4 q3 = xb[(long)(r3.x & 0x3FFFF) * 8 + p];
        float v0 = __uint_as_float(r0.y);
        float v1 = __uint_as_float(r1.y);
        float v2 = __uint_as_float(r2.y);
        float v3 = __uint_as_float(r3.y);
        ACC8(q0, v0)
        ACC8(q1, v1)
        ACC8(q2, v2)
        ACC8(q3, v3)
    }
    for (; j < e; j++) {
        uint2 r = rec[j];
        uint4 q = xb[(long)(r.x & 0x3FFFF) * 8 + p];
        float v = __uint_as_float(r.y);
        ACC8(q, v)
    }

    *(uint4*)(out + (long)row * 64 + p * 8) =
        make_uint4(pk2(a[0], a[1]), pk2(a[2], a[3]),
                   pk2(a[4], a[5]), pk2(a[6], a[7]));
}

// single-segment spmm (adjacency layer loop)
__global__ __launch_bounds__(256) void k_spmm_bf(const int* __restrict__ rstart,
                                                 const int* __restrict__ rend,
                                                 const uint2* __restrict__ rec,
                                                 const bf16* __restrict__ x,
                                                 bf16* __restrict__ out,
                                                 int n_rows) {
    int row = blockIdx.x * 32 + (threadIdx.x >> 3);
    int p = threadIdx.x & 7;
    if (row >= n_rows) return;
    spmm_row(row, p, rstart, rend, rec, x, out);
}

// two-segment spmm (user+item MLP stages merged into one launch)
__global__ __launch_bounds__(256) void k_spmm2(
        const int* __restrict__ rs0, const int* __restrict__ re0, const uint2* __restrict__ rc0,
        const bf16* __restrict__ x0, bf16* __restrict__ o0, int n0, int nb0,
        const int* __restrict__ rs1, const int* __restrict__ re1, const uint2* __restrict__ rc1,
        const bf16* __restrict__ x1, bf16* __restrict__ o1, int n1) {
    int b = blockIdx.x;
    int p = threadIdx.x & 7;
    int rl = threadIdx.x >> 3;
    if (b < nb0) {
        int row = b * 32 + rl;
        if (row < n0) spmm_row(row, p, rs0, re0, rc0, x0, o0);
    } else {
        int row = (b - nb0) * 32 + rl;
        if (row < n1) spmm_row(row, p, rs1, re1, rc1, x1, o1);
    }
}

// ---------------- two-segment Y = act(X16 @ W + b) -> bf16 (MFMA) --------------
template <int ACT>
__global__ __launch_bounds__(256) void k_gemm2(
        const bf16* __restrict__ X0, const void* __restrict__ W0, const void* __restrict__ b0,
        bf16* __restrict__ Y0, int M0, int nb0,
        const bf16* __restrict__ X1, const void* __restrict__ W1, const void* __restrict__ b1,
        bf16* __restrict__ Y1, int M1,
        const int* __restrict__ flag) {
    __shared__ bf16 WtH[64][72];
    __shared__ bf16 WtL[64][72];
    __shared__ float bl[64];
    int f = *flag;
    int tid = threadIdx.x;
    int bId = blockIdx.x;
    const bf16* X; const void* W; const void* bb; bf16* Y; int M, sb, nbseg;
    if (bId < nb0) { X = X0; W = W0; bb = b0; Y = Y0; M = M0; sb = bId; nbseg = nb0; }
    else { X = X1; W = W1; bb = b1; Y = Y1; M = M1; sb = bId - nb0; nbseg = gridDim.x - nb0; }

    for (int idx = tid; idx < 4096; idx += 256) {
        int n = idx >> 6, kk = idx & 63;
        float v = ldf(W, (long)kk * 64 + n, f);
        bf16 h = __float2bfloat16(v);
        WtH[n][kk] = h;
        WtL[n][kk] = __float2bfloat16(v - __bfloat162float(h));
    }
    if (tid < 64) bl[tid] = ldf(bb, tid, f);
    __syncthreads();

    int l  = tid & 63;
    int lr = l & 15;      // A row / D col within tile
    int lk = l >> 4;      // k sub-block / D row group

    bf16x8 bh[2][4], bbf[2][4];
#pragma unroll
    for (int kt = 0; kt < 2; kt++)
#pragma unroll
        for (int ct = 0; ct < 4; ct++) {
            int n  = ct * 16 + lr;
            int ko = kt * 32 + lk * 8;
            bh[kt][ct]  = *(const bf16x8*)&WtH[n][ko];
            bbf[kt][ct] = *(const bf16x8*)&WtL[n][ko];
        }

    int nt  = M >> 4;                       // M is a multiple of 16
    int wid = sb * 4 + (tid >> 6);
    int nw  = nbseg * 4;

    for (int t = wid; t < nt; t += nw) {
        const bf16* Ap = X + (long)(t * 16 + lr) * 64 + lk * 8;
        bf16x8 a[2];
#pragma unroll
        for (int kt = 0; kt < 2; kt++) a[kt] = *(const bf16x8*)(Ap + kt * 32);

        f32x4 acc[4];
#pragma unroll
        for (int ct = 0; ct < 4; ct++) {
            float bv = bl[ct * 16 + lr];
            acc[ct] = (f32x4){bv, bv, bv, bv};
        }
#pragma unroll
        for (int kt = 0; kt < 2; kt++)
#pragma unroll
            for (int ct = 0; ct < 4; ct++) {
                acc[ct] = __builtin_amdgcn_mfma_f32_16x16x32_bf16(a[kt], bh[kt][ct], acc[ct], 0, 0, 0);
                acc[ct] = __builtin_amdgcn_mfma_f32_16x16x32_bf16(a[kt], bbf[kt][ct], acc[ct], 0, 0, 0);
            }

#pragma unroll
        for (int r = 0; r < 4; r++) {
            float v0 = acc[0][r], v1 = acc[1][r], v2 = acc[2][r], v3 = acc[3][r];
            if (ACT == 2) {
                v0 = fmaxf(v0, 0.0f); v1 = fmaxf(v1, 0.0f);
                v2 = fmaxf(v2, 0.0f); v3 = fmaxf(v3, 0.0f);
            } else {
                v0 = (v0 > 0.0f) ? v0 : (expf(v0) - 1.0f);
                v1 = (v1 > 0.0f) ? v1 : (expf(v1) - 1.0f);
                v2 = (v2 > 0.0f) ? v2 : (expf(v2) - 1.0f);
                v3 = (v3 > 0.0f) ? v3 : (expf(v3) - 1.0f);
            }
            long ob = (long)(t * 16 + lk * 4 + r) * 64 + lr;
            Y[ob]      = __float2bfloat16(v0);
            Y[ob + 16] = __float2bfloat16(v1);
            Y[ob + 32] = __float2bfloat16(v2);
            Y[ob + 48] = __float2bfloat16(v3);
        }
    }
}

// ---------------- NGCF layer: E_out = leakyrelu(S@W1 + (E.*S)@W2 + b) --------
// P = E.*S formed IN-REGISTER (row-local). Only the per-row l2 scale (f32) is
// stored; k_gather applies E_k * scale. W1/W2 in LDS (B^T layout, +8 pad),
// bf16 hi+lo split.
__global__ __launch_bounds__(256) void k_layer(const bf16* __restrict__ S,
                                               const bf16* __restrict__ Ein,
                                               bf16* __restrict__ Eout,
                                               const void* __restrict__ Wgc,
                                               const void* __restrict__ bgc,
                                               const void* __restrict__ Wbi,
                                               const void* __restrict__ bbi,
                                               long woff, long boff,
                                               float* __restrict__ scale, int M,
                                               const int* __restrict__ flag) {
    __shared__ bf16 W1H[64][72];
    __shared__ bf16 W1L[64][72];
    __shared__ bf16 W2H[64][72];
    __shared__ bf16 W2L[64][72];
    __shared__ float bl[64];
    int f = *flag;
    int tid = threadIdx.x;
    for (int idx = tid; idx < 4096; idx += 256) {
        int n = idx >> 6, kk = idx & 63;
        float v1 = ldf(Wgc, woff + (long)kk * 64 + n, f);
        float v2 = ldf(Wbi, woff + (long)kk * 64 + n, f);
        bf16 h1 = __float2bfloat16(v1);
        bf16 h2 = __float2bfloat16(v2);
        W1H[n][kk] = h1;
        W1L[n][kk] = __float2bfloat16(v1 - __bfloat162float(h1));
        W2H[n][kk] = h2;
        W2L[n][kk] = __float2bfloat16(v2 - __bfloat162float(h2));
    }
    if (tid < 64) bl[tid] = ldf(bgc, boff + tid, f) + ldf(bbi, boff + tid, f);
    __syncthreads();

    int l  = tid & 63;
    int lr = l & 15;
    int lk = l >> 4;

    bf16x8 w1h[2][4], w1l[2][4], w2h[2][4], w2l[2][4];
#pragma unroll
    for (int kt = 0; kt < 2; kt++)
#pragma unroll
        for (int ct = 0; ct < 4; ct++) {
            int n  = ct * 16 + lr;
            int ko = kt * 32 + lk * 8;
            w1h[kt][ct] = *(const bf16x8*)&W1H[n][ko];
            w1l[kt][ct] = *(const bf16x8*)&W1L[n][ko];
            w2h[kt][ct] = *(const bf16x8*)&W2H[n][ko];
            w2l[kt][ct] = *(const bf16x8*)&W2L[n][ko];
        }

    int nt  = M >> 4;                 // 11250 for NTOT
    int wid = blockIdx.x * 4 + (tid >> 6);
    int nw  = gridDim.x * 4;

    for (int t = wid; t < nt; t += nw) {
        long rb = (long)(t * 16 + lr) * 64 + lk * 8;
        bf16x8 sv[2], pv[2];
        sv[0] = *(const bf16x8*)(S + rb);
        sv[1] = *(const bf16x8*)(S + rb + 32);
        {
            bf16x8 e0 = *(const bf16x8*)(Ein + rb);
            bf16x8 e1 = *(const bf16x8*)(Ein + rb + 32);
            pv[0] = mul_bf8(e0, sv[0]);
            pv[1] = mul_bf8(e1, sv[1]);
        }

        f32x4 acc[4];
#pragma unroll
        for (int ct = 0; ct < 4; ct++) {
            float bv = bl[ct * 16 + lr];
            acc[ct] = (f32x4){bv, bv, bv, bv};
        }
#pragma unroll
        for (int kt = 0; kt < 2; kt++)
#pragma unroll
            for (int ct = 0; ct < 4; ct++) {
                acc[ct] = __builtin_amdgcn_mfma_f32_16x16x32_bf16(sv[kt], w1h[kt][ct], acc[ct], 0, 0, 0);
                acc[ct] = __builtin_amdgcn_mfma_f32_16x16x32_bf16(sv[kt], w1l[kt][ct], acc[ct], 0, 0, 0);
                acc[ct] = __builtin_amdgcn_mfma_f32_16x16x32_bf16(pv[kt], w2h[kt][ct], acc[ct], 0, 0, 0);
                acc[ct] = __builtin_amdgcn_mfma_f32_16x16x32_bf16(pv[kt], w2l[kt][ct], acc[ct], 0, 0, 0);
            }

#pragma unroll
        for (int r = 0; r < 4; r++) {
            float v0 = acc[0][r], v1 = acc[1][r], v2 = acc[2][r], v3 = acc[3][r];
            v0 = (v0 > 0.0f) ? v0 : 0.2f * v0;
            v1 = (v1 > 0.0f) ? v1 : 0.2f * v1;
            v2 = (v2 > 0.0f) ? v2 : 0.2f * v2;
            v3 = (v3 > 0.0f) ? v3 : 0.2f * v3;
            float ss = v0 * v0 + v1 * v1 + v2 * v2 + v3 * v3;
            ss += __shfl_xor(ss, 1, 64);    // reduce over the 16-lane column group
            ss += __shfl_xor(ss, 2, 64);
            ss += __shfl_xor(ss, 4, 64);
            ss += __shfl_xor(ss, 8, 64);
            float sc2 = 1.0f / fmaxf(sqrtf(ss), 1e-12f);
            int grow = t * 16 + lk * 4 + r;
            long ob = (long)grow * 64 + lr;
            Eout[ob]      = __float2bfloat16(v0);
            Eout[ob + 16] = __float2bfloat16(v1);
            Eout[ob + 32] = __float2bfloat16(v2);
            Eout[ob + 48] = __float2bfloat16(v3);
            if (lr == 0) scale[grow] = sc2;
        }
    }
}

// ---------------- final gather into output ----------------
// nm_k[row] reconstructed as E_k[row] * scale_k[row] (norms not materialized).
__global__ __launch_bounds__(64) void k_gather(const int* __restrict__ users,
                                               const int* __restrict__ pos,
                                               const int* __restrict__ neg,
                                               const void* __restrict__ ue,
                                               const void* __restrict__ ie,
                                               const bf16* __restrict__ E1,
                                               const bf16* __restrict__ E2,
                                               const bf16* __restrict__ E3,
                                               const float* __restrict__ s1,
                                               const float* __restrict__ s2,
                                               const float* __restrict__ s3,
                                               const bf16* __restrict__ uh,
                                               const bf16* __restrict__ ih,
                                               void* __restrict__ out,
                                               const int* __restrict__ flag) {
    int f = *flag;
    int b = blockIdx.x;           // 0..12287: [users | pos | neg] x 4096
    int which = b >> 12;
    int s = b & 4095;
    int lane = threadIdx.x;       // 64
    long ebase, nrow;
    const void* e0;
    const bf16* hh;
    if (which == 0) {
        int r = users[s];
        e0 = ue; ebase = (long)r * 64;
        hh = uh + (long)r * 64;
        nrow = (long)r;
    } else {
        int r = (which == 1) ? pos[s] : neg[s];
        e0 = ie; ebase = (long)r * 64;
        hh = ih + (long)r * 64;
        nrow = (long)(N_USER + r);
    }
    long nbase = nrow * 64;
    float o0 = ldf(e0, ebase + lane, f);
    float o1 = __bfloat162float(E1[nbase + lane]) * s1[nrow];
    float o2 = __bfloat162float(E2[nbase + lane]) * s2[nrow];
    float o3 = __bfloat162float(E3[nbase + lane]) * s3[nrow];
    float o4 = __bfloat162float(hh[lane]);
    long ob = (long)b * 320;
    if (f) {
        float* o = (float*)out + ob;
        o[lane] = o0; o[64 + lane] = o1; o[128 + lane] = o2;
        o[192 + lane] = o3; o[256 + lane] = o4;
    } else {
        bf16* o = (bf16*)out + ob;
        o[lane]       = __float2bfloat16(o0);
        o[64 + lane]  = __float2bfloat16(o1);
        o[128 + lane] = __float2bfloat16(o2);
        o[192 + lane] = __float2bfloat16(o3);
        o[256 + lane] = __float2bfloat16(o4);
    }
}

extern "C" void kernel_launch(void* const* d_in, const int* in_sizes, int n_in,
                              void* d_out, int out_size, void* d_ws, size_t ws_size,
                              hipStream_t stream) {
    const int* users = (const int*)d_in[0];
    const int* pos   = (const int*)d_in[1];
    const int* neg   = (const int*)d_in[2];
    const int* adj_r = (const int*)d_in[3];
    const int* adj_c = (const int*)d_in[4];
    const void* adj_v = d_in[5];
    const int* ug_r  = (const int*)d_in[6];
    const int* ug_c  = (const int*)d_in[7];
    const void* ug_v = d_in[8];
    const int* ig_r  = (const int*)d_in[9];
    const int* ig_c  = (const int*)d_in[10];
    const void* ig_v = d_in[11];
    const void* ue   = d_in[12];
    const void* ie   = d_in[13];
    const void* Wgc  = d_in[14];
    const void* bgc  = d_in[15];
    const void* Wbi  = d_in[16];
    const void* bbi  = d_in[17];
    const void* Wu0  = d_in[18];
    const void* bu0  = d_in[19];
    const void* Wu1  = d_in[20];
    const void* bu1  = d_in[21];
    const void* Wi0  = d_in[22];
    const void* bi0  = d_in[23];
    const void* Wi1  = d_in[24];
    const void* bi1  = d_in[25];

    char* ws = (char*)d_ws;
    int*   FLAG  = (int*)(ws + 0);                       // 256 B
    bf16*  S16A  = (bf16*)(ws + 256);                    // 23,040,000 (adj S, layer phase)
    // recTmpA aliases [256, 30,277,888): dead before S16A first written (layer phase)
    uint2* recTmpA = (uint2*)(ws + 256);                 // 30,277,632
    bf16*  SU    = (bf16*)(ws + 30277888L);              //  7,680,000 (user S, MLP) - after recTmpA
    bf16*  SI    = (bf16*)(ws + 46080256L);              // 15,360,000 (item S, MLP)
    bf16*  ego16 = (bf16*)(ws + 61440256L);              // E0, 23,040,000
    bf16*  UH    = (bf16*)(ws + 84480256L);              //  7,680,000
    bf16*  IH    = (bf16*)(ws + 92160256L);              // 15,360,000
    bf16*  E1    = (bf16*)(ws + 107520256L);             // 23,040,000
    bf16*  E2    = (bf16*)(ws + 130560256L);             // 23,040,000
    bf16*  E3    = (bf16*)(ws + 153600256L);             // 23,040,000
    // recTmpU aliases E2 head (dead before MLP writes TI); TI aliases E2 head;
    // TU aliases E2 tail. All dead before layer k=1 writes E2.
    uint2* recTmpU = (uint2*)(ws + 130560256L);          //  8,355,840
    bf16*  TI    = (bf16*)(ws + 130560256L);             // 15,360,000
    bf16*  TU    = (bf16*)(ws + 145920256L);             //  7,680,000 (ends 153,600,256)
    // recTmpI aliases E3 head: dead before layer k=2 writes E3
    uint2* recTmpI = (uint2*)(ws + 153600256L);          // 16,433,152
    uint2* rec2A = (uint2*)(ws + 176640256L);            // 30,277,632
    uint2* rec2U = (uint2*)(ws + 206917888L);            //  8,355,840
    uint2* rec2I = (uint2*)(ws + 215273728L);            // 16,433,152
    int* rstartA = (int*)(ws + 231706880L);              //    720,000
    int* rendA   = (int*)(ws + 232426880L);              //    720,000
    int* rstartU = (int*)(ws + 233146880L);              //    240,000
    int* rendU   = (int*)(ws + 233386880L);              //    240,000
    int* rstartI = (int*)(ws + 233626880L);              //    480,000
    int* rendI   = (int*)(ws + 234106880L);              //    480,000
    int* sbposU  = (int*)(ws + 234586880L);              //      1,920 (pad to 2,048)
    int* sbposI  = (int*)(ws + 234588928L);              //      3,776 (pad to 4,096)
    int* sbposA  = (int*)(ws + 234593024L);              //      5,632
    float* SC1   = (float*)(ws + 234600192L);            //    720,000
    float* SC2   = (float*)(ws + 235320192L);            //    720,000
    float* SC3   = (float*)(ws + 236040192L);            //    720,000
                                                         // end 236,760,192 (< 261,120,256 proven)

    k_detect<<<1, 64, 0, stream>>>(adj_v, FLAG);
    k_cast16<<<45000, 256, 0, stream>>>(ue, ie, ego16, FLAG);

    // ---- merged two-level build: 3 launches for all three graphs ----
    k_initpos3<<<1, 256, 0, stream>>>(sbposU, sbposI, sbposA);
    k_part3<<<PB_U + PB_I + PB_A, 256, 0, stream>>>(ug_r, ug_c, ug_v,
                                                    ig_r, ig_c, ig_v,
                                                    adj_r, adj_c, adj_v,
                                                    recTmpU, recTmpI, recTmpA,
                                                    sbposU, sbposI, sbposA, FLAG);
    k_sortsb3<<<NSB_UG + NSB_IG + NSB_ADJ, 1024, 0, stream>>>(
        recTmpU, rec2U, rstartU, rendU, sbposU,
        recTmpI, rec2I, rstartI, rendI, sbposI,
        recTmpA, rec2A, rstartA, rendA, sbposA);

    // ---- user+item MLP branches, stage-merged (2 spmm + 2 gemm launches) ----
    const bf16* ego16I = ego16 + (size_t)N_USER * 64;
    int nbU = (N_USER + 31) / 32;       // 1875
    int nbI = (N_ITEM + 31) / 32;       // 3750
    int gu = (N_USER / 16 + 7) / 8;     // 469 (~2 row-tiles per wave)
    int gi = (N_ITEM / 16 + 7) / 8;     // 938
    k_spmm2<<<nbU + nbI, 256, 0, stream>>>(rstartU, rendU, rec2U, ego16,  SU, N_USER, nbU,
                                           rstartI, rendI, rec2I, ego16I, SI, N_ITEM);
    k_gemm2<1><<<gu + gi, 256, 0, stream>>>(SU, Wu0, bu0, TU, N_USER, gu,
                                            SI, Wi0, bi0, TI, N_ITEM, FLAG);
    k_spmm2<<<nbU + nbI, 256, 0, stream>>>(rstartU, rendU, rec2U, TU, SU, N_USER, nbU,
                                           rstartI, rendI, rec2I, TI, SI, N_ITEM);
    k_gemm2<2><<<gu + gi, 256, 0, stream>>>(SU, Wu1, bu1, UH, N_USER, gu,
                                            SI, Wi1, bi1, IH, N_ITEM, FLAG);

    // ---- 3 NGCF layers: S-only spmm; layer forms P in-register, stores E_k + scale ----
    bf16* Ebuf[4]  = {ego16, E1, E2, E3};
    float* SCs[3]  = {SC1, SC2, SC3};
    for (int k = 0; k < 3; k++) {
        k_spmm_bf<<<(NTOT + 31) / 32, 256, 0, stream>>>(rstartA, rendA, rec2A, Ebuf[k], S16A, NTOT);
        k_layer<<<704, 256, 0, stream>>>(S16A, Ebuf[k], Ebuf[k + 1],
                                         Wgc, bgc, Wbi, bbi,
                                         (long)k * 4096, (long)k * 64,
                                         SCs[k], NTOT, FLAG);
    }

    // ---- output gather ----
    k_gather<<<12288, 64, 0, stream>>>(users, pos, neg, ue, ie, E1, E2, E3,
                                       SC1, SC2, SC3, UH, IH, d_out, FLAG);
}

// Round 10
// 765.898 us; speedup vs baseline: 1.3967x; 1.0691x over previous
//
#include <hip/hip_runtime.h>
#include <hip/hip_bf16.h>

#define N_USER 60000
#define N_ITEM 120000
#define NTOT   180000
#define NNZ_ADJ 3600000
#define NNZ_UG   960000
#define NNZ_IG  1920000

#define RSB     2048        // rows per super-bin
#define NSB_ADJ ((NTOT  + RSB - 1) / RSB)   // 88
#define NSB_UG  ((N_USER+ RSB - 1) / RSB)   // 30
#define NSB_IG  ((N_ITEM+ RSB - 1) / RSB)   // 59
#define CAPA_SB 43008       // mean 40960 + 10 sigma
#define CAPU_SB 34816
#define CAPI_SB 34816
#define CHUNK   4096
#define PB_U ((NNZ_UG  + CHUNK - 1) / CHUNK)   // 235
#define PB_I ((NNZ_IG  + CHUNK - 1) / CHUNK)   // 469
#define PB_A ((NNZ_ADJ + CHUNK - 1) / CHUNK)   // 879

typedef __hip_bfloat16 bf16;
typedef __attribute__((ext_vector_type(8))) short bf16x8;   // one MFMA A/B fragment
typedef __attribute__((ext_vector_type(4))) float f32x4;    // one MFMA C/D fragment

// load float element i from input tensor of unknown dtype: flag=1 -> fp32, 0 -> bf16
__device__ __forceinline__ float ldf(const void* p, long i, int f) {
    return f ? ((const float*)p)[i] : __bfloat162float(((const bf16*)p)[i]);
}

// pack two fp32 -> one uint holding 2 bf16
__device__ __forceinline__ unsigned pk2(float a, float b) {
    unsigned short lo = __bfloat16_as_ushort(__float2bfloat16(a));
    unsigned short hi = __bfloat16_as_ushort(__float2bfloat16(b));
    return (unsigned)lo | ((unsigned)hi << 16);
}

// elementwise bf16 product of two bf16x8 fragments (for P = E .* S in-register)
__device__ __forceinline__ bf16x8 mul_bf8(bf16x8 x, bf16x8 y) {
    bf16x8 r;
#pragma unroll
    for (int e = 0; e < 8; e++) {
        float xf = __uint_as_float(((unsigned)(unsigned short)x[e]) << 16);
        float yf = __uint_as_float(((unsigned)(unsigned short)y[e]) << 16);
        r[e] = (short)__bfloat16_as_ushort(__float2bfloat16(xf * yf));
    }
    return r;
}

// ---------------- dtype detector (adj_vals >= 0 -> bf16 words have bit15==0) ----
__global__ void k_detect(const void* __restrict__ vals, int* __restrict__ flag) {
    if (threadIdx.x == 0 && blockIdx.x == 0) {
        const unsigned short* w = (const unsigned short*)vals;
        int cnt = 0;
        for (int i = 0; i < 512; i += 2) cnt += (w[i] >> 15) & 1;
        *flag = (cnt > 16) ? 1 : 0;
    }
}

// ---------------- cast user/item emb -> ego bf16 ----------------
__global__ __launch_bounds__(256) void k_cast16(const void* __restrict__ ue,
                                                const void* __restrict__ ie,
                                                bf16* __restrict__ ego16,
                                                const int* __restrict__ flag) {
    int f = *flag;
    long i = (long)blockIdx.x * 256 + threadIdx.x;   // NTOT*64 = 11,520,000
    const long uN = (long)N_USER * 64;
    if (i < (long)NTOT * 64) {
        float v = (i < uN) ? ldf(ue, i, f) : ldf(ie, i - uN, f);
        ego16[i] = __float2bfloat16(v);
    }
}

// ================= merged two-level binned build =================
__global__ void k_initpos3(int* __restrict__ sbU, int* __restrict__ sbI,
                           int* __restrict__ sbA) {
    int i = threadIdx.x;
    if (i < NSB_UG)  sbU[i * 16] = i * CAPU_SB;
    if (i < NSB_IG)  sbI[i * 16] = i * CAPI_SB;
    if (i < NSB_ADJ) sbA[i * 16] = i * CAPA_SB;
}

// L1: partition edges into super-bins, all 3 graphs in one grid.
// Round-9: LDS-staged block-local counting sort + coalesced flush
// (round-8 counters: 102 us at 1.3 TB/s, scatter-write bound -- 8B stores to
// ~96 streams = partial-line RMW at L2, plus double-read of inputs).
// Each thread holds 16 consecutive edges in registers (vector loads, read once);
// records are bin-sorted into a 32 KB LDS stage, then flushed linearly so
// global writes are ~43-record contiguous runs per bin. Within-bin order
// changes only (already nondeterministic across blocks).
__global__ __launch_bounds__(256) void k_part3(const int* __restrict__ rU, const int* __restrict__ cU, const void* __restrict__ vU,
                                               const int* __restrict__ rI, const int* __restrict__ cI, const void* __restrict__ vI,
                                               const int* __restrict__ rA, const int* __restrict__ cA, const void* __restrict__ vA,
                                               uint2* __restrict__ recU, uint2* __restrict__ recI, uint2* __restrict__ recA,
                                               int* __restrict__ sbU, int* __restrict__ sbI, int* __restrict__ sbA,
                                               const int* __restrict__ flag) {
    __shared__ int lcnt[96];
    __shared__ int lstart[96];       // LDS stage base per bin (exclusive scan)
    __shared__ int lpos[96];         // running cursor for scatter
    __shared__ int lbase[96];        // global base per bin
    __shared__ int wtmp;             // cross-wave scan carry
    __shared__ uint2 stage[CHUNK];   // 32 KB bin-sorted records
    __shared__ unsigned char sbin[CHUNK];  // bin of each stage slot

    int f = *flag;
    int t = threadIdx.x;
    int b = blockIdx.x;
    const int *rows, *cols; const void* vals; uint2* rec; int* sbpos; int nnz, base;
    if (b < PB_U)             { rows = rU; cols = cU; vals = vU; rec = recU; sbpos = sbU; nnz = NNZ_UG;  base = b * CHUNK; }
    else if (b < PB_U + PB_I) { rows = rI; cols = cI; vals = vI; rec = recI; sbpos = sbI; nnz = NNZ_IG;  base = (b - PB_U) * CHUNK; }
    else                      { rows = rA; cols = cA; vals = vA; rec = recA; sbpos = sbA; nnz = NNZ_ADJ; base = (b - PB_U - PB_I) * CHUNK; }

    if (t < 96) lcnt[t] = 0;

    // ---- load 16 consecutive edges per thread into registers (read once) ----
    int base16 = base + t * 16;
    int rr[16], cc[16];
    float vv[16];
    if (base + CHUNK <= nnz) {           // full block: vectorized, unguarded
#pragma unroll
        for (int k = 0; k < 4; k++) {
            int4 r4 = *(const int4*)(rows + base16 + 4 * k);
            int4 c4 = *(const int4*)(cols + base16 + 4 * k);
            rr[4 * k + 0] = r4.x; rr[4 * k + 1] = r4.y; rr[4 * k + 2] = r4.z; rr[4 * k + 3] = r4.w;
            cc[4 * k + 0] = c4.x; cc[4 * k + 1] = c4.y; cc[4 * k + 2] = c4.z; cc[4 * k + 3] = c4.w;
        }
        if (f) {
#pragma unroll
            for (int k = 0; k < 4; k++) {
                float4 v4 = *(const float4*)((const float*)vals + base16 + 4 * k);
                vv[4 * k + 0] = v4.x; vv[4 * k + 1] = v4.y; vv[4 * k + 2] = v4.z; vv[4 * k + 3] = v4.w;
            }
        } else {
            const unsigned short* vb = (const unsigned short*)vals;
#pragma unroll
            for (int h = 0; h < 2; h++) {
                uint4 q = *(const uint4*)(vb + base16 + 8 * h);
                vv[8 * h + 0] = __uint_as_float(q.x << 16);
                vv[8 * h + 1] = __uint_as_float(q.x & 0xFFFF0000u);
                vv[8 * h + 2] = __uint_as_float(q.y << 16);
                vv[8 * h + 3] = __uint_as_float(q.y & 0xFFFF0000u);
                vv[8 * h + 4] = __uint_as_float(q.z << 16);
                vv[8 * h + 5] = __uint_as_float(q.z & 0xFFFF0000u);
                vv[8 * h + 6] = __uint_as_float(q.w << 16);
                vv[8 * h + 7] = __uint_as_float(q.w & 0xFFFF0000u);
            }
        }
    } else {                             // tail block: guarded scalar
#pragma unroll
        for (int k = 0; k < 16; k++) {
            int e = base16 + k;
            if (e < nnz) { rr[k] = rows[e]; cc[k] = cols[e]; vv[k] = ldf(vals, e, f); }
            else         { rr[k] = -1; cc[k] = 0; vv[k] = 0.0f; }
        }
    }
    __syncthreads();

    // ---- count pass (registers -> LDS counters) ----
#pragma unroll
    for (int k = 0; k < 16; k++)
        if (rr[k] >= 0) atomicAdd(&lcnt[rr[k] >> 11], 1);
    __syncthreads();

    // ---- 2-wave shfl exclusive scan over 96 bin counts ----
    int v = (t < 96) ? lcnt[t] : 0;
    int incl = v;
    {
        int lane = t & 63;
#pragma unroll
        for (int d = 1; d < 64; d <<= 1) {
            int w = __shfl_up(incl, d, 64);
            if (lane >= d) incl += w;
        }
    }
    if (t == 63) wtmp = incl;            // total of bins 0..63
    __syncthreads();
    if (t >= 64 && t < 96) incl += wtmp;
    if (t < 96) {
        int ex = incl - v;
        lstart[t] = ex;
        lpos[t]   = ex;
        lbase[t]  = v ? atomicAdd(&sbpos[t * 16], v) : 0;
    }
    __syncthreads();

    // ---- scatter into LDS stage (bin-sorted within block) ----
#pragma unroll
    for (int k = 0; k < 16; k++) {
        if (rr[k] >= 0) {
            int sb = rr[k] >> 11;
            int o = atomicAdd(&lpos[sb], 1);
            stage[o] = make_uint2(((unsigned)(rr[k] & 2047) << 18) | (unsigned)cc[k],
                                  __float_as_uint(vv[k]));
            sbin[o] = (unsigned char)sb;
        }
    }
    __syncthreads();

    // ---- coalesced flush: linear LDS -> contiguous per-bin global runs ----
    int total = lstart[95] + lcnt[95];
    for (int i = t; i < total; i += 256) {
        int sb = sbin[i];
        rec[lbase[sb] + (i - lstart[sb])] = stage[i];
    }
}

// L2: per-super-bin counting sort into row order, all 3 graphs in one grid.
// Wave-shuffle scan (4 barriers); count/scatter passes unrolled x4.
__global__ __launch_bounds__(1024) void k_sortsb3(
        const uint2* __restrict__ recU, uint2* __restrict__ rec2U, int* __restrict__ rstartU, int* __restrict__ rendU, const int* __restrict__ sbU,
        const uint2* __restrict__ recI, uint2* __restrict__ rec2I, int* __restrict__ rstartI, int* __restrict__ rendI, const int* __restrict__ sbI,
        const uint2* __restrict__ recA, uint2* __restrict__ rec2A, int* __restrict__ rstartA, int* __restrict__ rendA, const int* __restrict__ sbA) {
    __shared__ int cnt[RSB];
    __shared__ int pos[RSB];
    __shared__ int wsum[16];
    int b = blockIdx.x, t = threadIdx.x;
    const uint2* rec; uint2* rec2; int* rstart; int* rend; const int* sbpos;
    int cap, n_rows, lb;
    if (b < NSB_UG) {
        lb = b; rec = recU; rec2 = rec2U; rstart = rstartU; rend = rendU;
        sbpos = sbU; cap = CAPU_SB; n_rows = N_USER;
    } else if (b < NSB_UG + NSB_IG) {
        lb = b - NSB_UG; rec = recI; rec2 = rec2I; rstart = rstartI; rend = rendI;
        sbpos = sbI; cap = CAPI_SB; n_rows = N_ITEM;
    } else {
        lb = b - NSB_UG - NSB_IG; rec = recA; rec2 = rec2A; rstart = rstartA; rend = rendA;
        sbpos = sbA; cap = CAPA_SB; n_rows = NTOT;
    }
    int s = lb * cap;
    int e = sbpos[lb * 16];          // final fill cursor
    cnt[t] = 0; cnt[t + 1024] = 0;
    __syncthreads();
    // ---- count pass, x4 unrolled (stride 1024) ----
    int j = s + t;
    for (; j + 3072 < e; j += 4096) {
        uint2 r0 = rec[j];
        uint2 r1 = rec[j + 1024];
        uint2 r2 = rec[j + 2048];
        uint2 r3 = rec[j + 3072];
        atomicAdd(&cnt[r0.x >> 18], 1);
        atomicAdd(&cnt[r1.x >> 18], 1);
        atomicAdd(&cnt[r2.x >> 18], 1);
        atomicAdd(&cnt[r3.x >> 18], 1);
    }
    for (; j < e; j += 1024)
        atomicAdd(&cnt[rec[j].x >> 18], 1);
    __syncthreads();
    // ---- wave-shuffle exclusive scan over 2048 counts (pair per thread) ----
    int a  = cnt[2 * t];
    int bb = cnt[2 * t + 1];
    int ps = a + bb;                 // pair sum
    int incl = ps;                   // inclusive scan of pair sums within wave
    int lane = t & 63;
#pragma unroll
    for (int d = 1; d < 64; d <<= 1) {
        int v = __shfl_up(incl, d, 64);
        if (lane >= d) incl += v;
    }
    int wv = t >> 6;                 // wave id 0..15
    if (lane == 63) wsum[wv] = incl;
    __syncthreads();
    if (t < 16) {
        int v  = wsum[t];
        int iv = v;
#pragma unroll
        for (int d = 1; d < 16; d <<= 1) {
            int w = __shfl_up(iv, d, 64);
            if (t >= d) iv += w;
        }
        wsum[t] = iv - v;            // exclusive wave offset
    }
    __syncthreads();
    int ex0 = wsum[wv] + (incl - ps);    // exclusive prefix of element 2t
    pos[2 * t]     = ex0;
    pos[2 * t + 1] = ex0 + a;
    int row0 = lb * RSB;
    {
        int ra = row0 + 2 * t;
        if (ra < n_rows) { rstart[ra] = s + ex0;      rend[ra] = s + ex0 + a; }
        int rb = ra + 1;
        if (rb < n_rows) { rstart[rb] = s + ex0 + a;  rend[rb] = s + ex0 + a + bb; }
    }
    __syncthreads();
    // ---- scatter pass, x4 unrolled ----
    j = s + t;
    for (; j + 3072 < e; j += 4096) {
        uint2 r0 = rec[j];
        uint2 r1 = rec[j + 1024];
        uint2 r2 = rec[j + 2048];
        uint2 r3 = rec[j + 3072];
        int o0 = atomicAdd(&pos[r0.x >> 18], 1);
        int o1 = atomicAdd(&pos[r1.x >> 18], 1);
        int o2 = atomicAdd(&pos[r2.x >> 18], 1);
        int o3 = atomicAdd(&pos[r3.x >> 18], 1);
        rec2[s + o0] = r0;
        rec2[s + o1] = r1;
        rec2[s + o2] = r2;
        rec2[s + o3] = r3;
    }
    for (; j < e; j += 1024) {
        uint2 r = rec[j];
        int o = atomicAdd(&pos[r.x >> 18], 1);
        rec2[s + o] = r;
    }
}

#define ACC8(q, v)                                      \
    a[0] += (v) * __uint_as_float((q).x << 16);         \
    a[1] += (v) * __uint_as_float((q).x & 0xFFFF0000u); \
    a[2] += (v) * __uint_as_float((q).y << 16);         \
    a[3] += (v) * __uint_as_float((q).y & 0xFFFF0000u); \
    a[4] += (v) * __uint_as_float((q).z << 16);         \
    a[5] += (v) * __uint_as_float((q).z & 0xFFFF0000u); \
    a[6] += (v) * __uint_as_float((q).w << 16);         \
    a[7] += (v) * __uint_as_float((q).w & 0xFFFF0000u);

// ================= CSR SpMM row body, bf16 x: one row per 8-lane octet =========
// Edge loop unrolled x4 with grouped loads (4 gathers in flight per wave).
__device__ __forceinline__ void spmm_row(int row, int p,
                                         const int* __restrict__ rstart,
                                         const int* __restrict__ rend,
                                         const uint2* __restrict__ rec,
                                         const bf16* __restrict__ x,
                                         bf16* __restrict__ out) {
    int s = rstart[row], e = rend[row];
    const uint4* xb = (const uint4*)x;   // 8 bf16 per uint4
    float a[8];
#pragma unroll
    for (int i = 0; i < 8; i++) a[i] = 0.0f;

    int j = s;
    for (; j + 4 <= e; j += 4) {
        uint2 r0 = rec[j];
        uint2 r1 = rec[j + 1];
        uint2 r2 = rec[j + 2];
        uint2 r3 = rec[j + 3];
        uint4 q0 = xb[(long)(r0.x & 0x3FFFF) * 8 + p];
        uint4 q1 = xb[(long)(r1.x & 0x3FFFF) * 8 + p];
        uint4 q2 = xb[(long)(r2.x & 0x3FFFF) * 8 + p];
        uint4 q3 = xb[(long)(r3.x & 0x3FFFF) * 8 + p];
        float v0 = __uint_as_float(r0.y);
        float v1 = __uint_as_float(r1.y);
        float v2 = __uint_as_float(r2.y);
        float v3 = __uint_as_float(r3.y);
        ACC8(q0, v0)
        ACC8(q1, v1)
        ACC8(q2, v2)
        ACC8(q3, v3)
    }
    for (; j < e; j++) {
        uint2 r = rec[j];
        uint4 q = xb[(long)(r.x & 0x3FFFF) * 8 + p];
        float v = __uint_as_float(r.y);
        ACC8(q, v)
    }

    *(uint4*)(out + (long)row * 64 + p * 8) =
        make_uint4(pk2(a[0], a[1]), pk2(a[2], a[3]),
                   pk2(a[4], a[5]), pk2(a[6], a[7]));
}

// single-segment spmm (adjacency layer loop)
__global__ __launch_bounds__(256) void k_spmm_bf(const int* __restrict__ rstart,
                                                 const int* __restrict__ rend,
                                                 const uint2* __restrict__ rec,
                                                 const bf16* __restrict__ x,
                                                 bf16* __restrict__ out,
                                                 int n_rows) {
    int row = blockIdx.x * 32 + (threadIdx.x >> 3);
    int p = threadIdx.x & 7;
    if (row >= n_rows) return;
    spmm_row(row, p, rstart, rend, rec, x, out);
}

// two-segment spmm (user+item MLP stages merged into one launch)
__global__ __launch_bounds__(256) void k_spmm2(
        const int* __restrict__ rs0, const int* __restrict__ re0, const uint2* __restrict__ rc0,
        const bf16* __restrict__ x0, bf16* __restrict__ o0, int n0, int nb0,
        const int* __restrict__ rs1, const int* __restrict__ re1, const uint2* __restrict__ rc1,
        const bf16* __restrict__ x1, bf16* __restrict__ o1, int n1) {
    int b = blockIdx.x;
    int p = threadIdx.x & 7;
    int rl = threadIdx.x >> 3;
    if (b < nb0) {
        int row = b * 32 + rl;
        if (row < n0) spmm_row(row, p, rs0, re0, rc0, x0, o0);
    } else {
        int row = (b - nb0) * 32 + rl;
        if (row < n1) spmm_row(row, p, rs1, re1, rc1, x1, o1);
    }
}

// ---------------- two-segment Y = act(X16 @ W + b) -> bf16 (MFMA) --------------
template <int ACT>
__global__ __launch_bounds__(256) void k_gemm2(
        const bf16* __restrict__ X0, const void* __restrict__ W0, const void* __restrict__ b0,
        bf16* __restrict__ Y0, int M0, int nb0,
        const bf16* __restrict__ X1, const void* __restrict__ W1, const void* __restrict__ b1,
        bf16* __restrict__ Y1, int M1,
        const int* __restrict__ flag) {
    __shared__ bf16 WtH[64][72];
    __shared__ bf16 WtL[64][72];
    __shared__ float bl[64];
    int f = *flag;
    int tid = threadIdx.x;
    int bId = blockIdx.x;
    const bf16* X; const void* W; const void* bb; bf16* Y; int M, sb, nbseg;
    if (bId < nb0) { X = X0; W = W0; bb = b0; Y = Y0; M = M0; sb = bId; nbseg = nb0; }
    else { X = X1; W = W1; bb = b1; Y = Y1; M = M1; sb = bId - nb0; nbseg = gridDim.x - nb0; }

    for (int idx = tid; idx < 4096; idx += 256) {
        int n = idx >> 6, kk = idx & 63;
        float v = ldf(W, (long)kk * 64 + n, f);
        bf16 h = __float2bfloat16(v);
        WtH[n][kk] = h;
        WtL[n][kk] = __float2bfloat16(v - __bfloat162float(h));
    }
    if (tid < 64) bl[tid] = ldf(bb, tid, f);
    __syncthreads();

    int l  = tid & 63;
    int lr = l & 15;      // A row / D col within tile
    int lk = l >> 4;      // k sub-block / D row group

    bf16x8 bh[2][4], bbf[2][4];
#pragma unroll
    for (int kt = 0; kt < 2; kt++)
#pragma unroll
        for (int ct = 0; ct < 4; ct++) {
            int n  = ct * 16 + lr;
            int ko = kt * 32 + lk * 8;
            bh[kt][ct]  = *(const bf16x8*)&WtH[n][ko];
            bbf[kt][ct] = *(const bf16x8*)&WtL[n][ko];
        }

    int nt  = M >> 4;                       // M is a multiple of 16
    int wid = sb * 4 + (tid >> 6);
    int nw  = nbseg * 4;

    for (int t = wid; t < nt; t += nw) {
        const bf16* Ap = X + (long)(t * 16 + lr) * 64 + lk * 8;
        bf16x8 a[2];
#pragma unroll
        for (int kt = 0; kt < 2; kt++) a[kt] = *(const bf16x8*)(Ap + kt * 32);

        f32x4 acc[4];
#pragma unroll
        for (int ct = 0; ct < 4; ct++) {
            float bv = bl[ct * 16 + lr];
            acc[ct] = (f32x4){bv, bv, bv, bv};
        }
#pragma unroll
        for (int kt = 0; kt < 2; kt++)
#pragma unroll
            for (int ct = 0; ct < 4; ct++) {
                acc[ct] = __builtin_amdgcn_mfma_f32_16x16x32_bf16(a[kt], bh[kt][ct], acc[ct], 0, 0, 0);
                acc[ct] = __builtin_amdgcn_mfma_f32_16x16x32_bf16(a[kt], bbf[kt][ct], acc[ct], 0, 0, 0);
            }

#pragma unroll
        for (int r = 0; r < 4; r++) {
            float v0 = acc[0][r], v1 = acc[1][r], v2 = acc[2][r], v3 = acc[3][r];
            if (ACT == 2) {
                v0 = fmaxf(v0, 0.0f); v1 = fmaxf(v1, 0.0f);
                v2 = fmaxf(v2, 0.0f); v3 = fmaxf(v3, 0.0f);
            } else {
                v0 = (v0 > 0.0f) ? v0 : (expf(v0) - 1.0f);
                v1 = (v1 > 0.0f) ? v1 : (expf(v1) - 1.0f);
                v2 = (v2 > 0.0f) ? v2 : (expf(v2) - 1.0f);
                v3 = (v3 > 0.0f) ? v3 : (expf(v3) - 1.0f);
            }
            long ob = (long)(t * 16 + lk * 4 + r) * 64 + lr;
            Y[ob]      = __float2bfloat16(v0);
            Y[ob + 16] = __float2bfloat16(v1);
            Y[ob + 32] = __float2bfloat16(v2);
            Y[ob + 48] = __float2bfloat16(v3);
        }
    }
}

// ---------------- NGCF layer: E_out = leakyrelu(S@W1 + (E.*S)@W2 + b) --------
// P = E.*S formed IN-REGISTER (row-local). Only the per-row l2 scale (f32) is
// stored; k_gather applies E_k * scale. W1/W2 in LDS (B^T layout, +8 pad),
// bf16 hi+lo split.
__global__ __launch_bounds__(256) void k_layer(const bf16* __restrict__ S,
                                               const bf16* __restrict__ Ein,
                                               bf16* __restrict__ Eout,
                                               const void* __restrict__ Wgc,
                                               const void* __restrict__ bgc,
                                               const void* __restrict__ Wbi,
                                               const void* __restrict__ bbi,
                                               long woff, long boff,
                                               float* __restrict__ scale, int M,
                                               const int* __restrict__ flag) {
    __shared__ bf16 W1H[64][72];
    __shared__ bf16 W1L[64][72];
    __shared__ bf16 W2H[64][72];
    __shared__ bf16 W2L[64][72];
    __shared__ float bl[64];
    int f = *flag;
    int tid = threadIdx.x;
    for (int idx = tid; idx < 4096; idx += 256) {
        int n = idx >> 6, kk = idx & 63;
        float v1 = ldf(Wgc, woff + (long)kk * 64 + n, f);
        float v2 = ldf(Wbi, woff + (long)kk * 64 + n, f);
        bf16 h1 = __float2bfloat16(v1);
        bf16 h2 = __float2bfloat16(v2);
        W1H[n][kk] = h1;
        W1L[n][kk] = __float2bfloat16(v1 - __bfloat162float(h1));
        W2H[n][kk] = h2;
        W2L[n][kk] = __float2bfloat16(v2 - __bfloat162float(h2));
    }
    if (tid < 64) bl[tid] = ldf(bgc, boff + tid, f) + ldf(bbi, boff + tid, f);
    __syncthreads();

    int l  = tid & 63;
    int lr = l & 15;
    int lk = l >> 4;

    bf16x8 w1h[2][4], w1l[2][4], w2h[2][4], w2l[2][4];
#pragma unroll
    for (int kt = 0; kt < 2; kt++)
#pragma unroll
        for (int ct = 0; ct < 4; ct++) {
            int n  = ct * 16 + lr;
            int ko = kt * 32 + lk * 8;
            w1h[kt][ct] = *(const bf16x8*)&W1H[n][ko];
            w1l[kt][ct] = *(const bf16x8*)&W1L[n][ko];
            w2h[kt][ct] = *(const bf16x8*)&W2H[n][ko];
            w2l[kt][ct] = *(const bf16x8*)&W2L[n][ko];
        }

    int nt  = M >> 4;                 // 11250 for NTOT
    int wid = blockIdx.x * 4 + (tid >> 6);
    int nw  = gridDim.x * 4;

    for (int t = wid; t < nt; t += nw) {
        long rb = (long)(t * 16 + lr) * 64 + lk * 8;
        bf16x8 sv[2], pv[2];
        sv[0] = *(const bf16x8*)(S + rb);
        sv[1] = *(const bf16x8*)(S + rb + 32);
        {
            bf16x8 e0 = *(const bf16x8*)(Ein + rb);
            bf16x8 e1 = *(const bf16x8*)(Ein + rb + 32);
            pv[0] = mul_bf8(e0, sv[0]);
            pv[1] = mul_bf8(e1, sv[1]);
        }

        f32x4 acc[4];
#pragma unroll
        for (int ct = 0; ct < 4; ct++) {
            float bv = bl[ct * 16 + lr];
            acc[ct] = (f32x4){bv, bv, bv, bv};
        }
#pragma unroll
        for (int kt = 0; kt < 2; kt++)
#pragma unroll
            for (int ct = 0; ct < 4; ct++) {
                acc[ct] = __builtin_amdgcn_mfma_f32_16x16x32_bf16(sv[kt], w1h[kt][ct], acc[ct], 0, 0, 0);
                acc[ct] = __builtin_amdgcn_mfma_f32_16x16x32_bf16(sv[kt], w1l[kt][ct], acc[ct], 0, 0, 0);
                acc[ct] = __builtin_amdgcn_mfma_f32_16x16x32_bf16(pv[kt], w2h[kt][ct], acc[ct], 0, 0, 0);
                acc[ct] = __builtin_amdgcn_mfma_f32_16x16x32_bf16(pv[kt], w2l[kt][ct], acc[ct], 0, 0, 0);
            }

#pragma unroll
        for (int r = 0; r < 4; r++) {
            float v0 = acc[0][r], v1 = acc[1][r], v2 = acc[2][r], v3 = acc[3][r];
            v0 = (v0 > 0.0f) ? v0 : 0.2f * v0;
            v1 = (v1 > 0.0f) ? v1 : 0.2f * v1;
            v2 = (v2 > 0.0f) ? v2 : 0.2f * v2;
            v3 = (v3 > 0.0f) ? v3 : 0.2f * v3;
            float ss = v0 * v0 + v1 * v1 + v2 * v2 + v3 * v3;
            ss += __shfl_xor(ss, 1, 64);    // reduce over the 16-lane column group
            ss += __shfl_xor(ss, 2, 64);
            ss += __shfl_xor(ss, 4, 64);
            ss += __shfl_xor(ss, 8, 64);
            float sc2 = 1.0f / fmaxf(sqrtf(ss), 1e-12f);
            int grow = t * 16 + lk * 4 + r;
            long ob = (long)grow * 64 + lr;
            Eout[ob]      = __float2bfloat16(v0);
            Eout[ob + 16] = __float2bfloat16(v1);
            Eout[ob + 32] = __float2bfloat16(v2);
            Eout[ob + 48] = __float2bfloat16(v3);
            if (lr == 0) scale[grow] = sc2;
        }
    }
}

// ---------------- final gather into output ----------------
// nm_k[row] reconstructed as E_k[row] * scale_k[row] (norms not materialized).
__global__ __launch_bounds__(64) void k_gather(const int* __restrict__ users,
                                               const int* __restrict__ pos,
                                               const int* __restrict__ neg,
                                               const void* __restrict__ ue,
                                               const void* __restrict__ ie,
                                               const bf16* __restrict__ E1,
                                               const bf16* __restrict__ E2,
                                               const bf16* __restrict__ E3,
                                               const float* __restrict__ s1,
                                               const float* __restrict__ s2,
                                               const float* __restrict__ s3,
                                               const bf16* __restrict__ uh,
                                               const bf16* __restrict__ ih,
                                               void* __restrict__ out,
                                               const int* __restrict__ flag) {
    int f = *flag;
    int b = blockIdx.x;           // 0..12287: [users | pos | neg] x 4096
    int which = b >> 12;
    int s = b & 4095;
    int lane = threadIdx.x;       // 64
    long ebase, nrow;
    const void* e0;
    const bf16* hh;
    if (which == 0) {
        int r = users[s];
        e0 = ue; ebase = (long)r * 64;
        hh = uh + (long)r * 64;
        nrow = (long)r;
    } else {
        int r = (which == 1) ? pos[s] : neg[s];
        e0 = ie; ebase = (long)r * 64;
        hh = ih + (long)r * 64;
        nrow = (long)(N_USER + r);
    }
    long nbase = nrow * 64;
    float o0 = ldf(e0, ebase + lane, f);
    float o1 = __bfloat162float(E1[nbase + lane]) * s1[nrow];
    float o2 = __bfloat162float(E2[nbase + lane]) * s2[nrow];
    float o3 = __bfloat162float(E3[nbase + lane]) * s3[nrow];
    float o4 = __bfloat162float(hh[lane]);
    long ob = (long)b * 320;
    if (f) {
        float* o = (float*)out + ob;
        o[lane] = o0; o[64 + lane] = o1; o[128 + lane] = o2;
        o[192 + lane] = o3; o[256 + lane] = o4;
    } else {
        bf16* o = (bf16*)out + ob;
        o[lane]       = __float2bfloat16(o0);
        o[64 + lane]  = __float2bfloat16(o1);
        o[128 + lane] = __float2bfloat16(o2);
        o[192 + lane] = __float2bfloat16(o3);
        o[256 + lane] = __float2bfloat16(o4);
    }
}

extern "C" void kernel_launch(void* const* d_in, const int* in_sizes, int n_in,
                              void* d_out, int out_size, void* d_ws, size_t ws_size,
                              hipStream_t stream) {
    const int* users = (const int*)d_in[0];
    const int* pos   = (const int*)d_in[1];
    const int* neg   = (const int*)d_in[2];
    const int* adj_r = (const int*)d_in[3];
    const int* adj_c = (const int*)d_in[4];
    const void* adj_v = d_in[5];
    const int* ug_r  = (const int*)d_in[6];
    const int* ug_c  = (const int*)d_in[7];
    const void* ug_v = d_in[8];
    const int* ig_r  = (const int*)d_in[9];
    const int* ig_c  = (const int*)d_in[10];
    const void* ig_v = d_in[11];
    const void* ue   = d_in[12];
    const void* ie   = d_in[13];
    const void* Wgc  = d_in[14];
    const void* bgc  = d_in[15];
    const void* Wbi  = d_in[16];
    const void* bbi  = d_in[17];
    const void* Wu0  = d_in[18];
    const void* bu0  = d_in[19];
    const void* Wu1  = d_in[20];
    const void* bu1  = d_in[21];
    const void* Wi0  = d_in[22];
    const void* bi0  = d_in[23];
    const void* Wi1  = d_in[24];
    const void* bi1  = d_in[25];

    char* ws = (char*)d_ws;
    int*   FLAG  = (int*)(ws + 0);                       // 256 B
    bf16*  S16A  = (bf16*)(ws + 256);                    // 23,040,000 (adj S, layer phase)
    // recTmpA aliases [256, 30,277,888): dead before S16A first written (layer phase)
    uint2* recTmpA = (uint2*)(ws + 256);                 // 30,277,632
    bf16*  SU    = (bf16*)(ws + 30277888L);              //  7,680,000 (user S, MLP) - after recTmpA
    bf16*  SI    = (bf16*)(ws + 46080256L);              // 15,360,000 (item S, MLP)
    bf16*  ego16 = (bf16*)(ws + 61440256L);              // E0, 23,040,000
    bf16*  UH    = (bf16*)(ws + 84480256L);              //  7,680,000
    bf16*  IH    = (bf16*)(ws + 92160256L);              // 15,360,000
    bf16*  E1    = (bf16*)(ws + 107520256L);             // 23,040,000
    bf16*  E2    = (bf16*)(ws + 130560256L);             // 23,040,000
    bf16*  E3    = (bf16*)(ws + 153600256L);             // 23,040,000
    // recTmpU aliases E2 head (dead before MLP writes TI); TI aliases E2 head;
    // TU aliases E2 tail. All dead before layer k=1 writes E2.
    uint2* recTmpU = (uint2*)(ws + 130560256L);          //  8,355,840
    bf16*  TI    = (bf16*)(ws + 130560256L);             // 15,360,000
    bf16*  TU    = (bf16*)(ws + 145920256L);             //  7,680,000 (ends 153,600,256)
    // recTmpI aliases E3 head: dead before layer k=2 writes E3
    uint2* recTmpI = (uint2*)(ws + 153600256L);          // 16,433,152
    uint2* rec2A = (uint2*)(ws + 176640256L);            // 30,277,632
    uint2* rec2U = (uint2*)(ws + 206917888L);            //  8,355,840
    uint2* rec2I = (uint2*)(ws + 215273728L);            // 16,433,152
    int* rstartA = (int*)(ws + 231706880L);              //    720,000
    int* rendA   = (int*)(ws + 232426880L);              //    720,000
    int* rstartU = (int*)(ws + 233146880L);              //    240,000
    int* rendU   = (int*)(ws + 233386880L);              //    240,000
    int* rstartI = (int*)(ws + 233626880L);              //    480,000
    int* rendI   = (int*)(ws + 234106880L);              //    480,000
    int* sbposU  = (int*)(ws + 234586880L);              //      1,920 (pad to 2,048)
    int* sbposI  = (int*)(ws + 234588928L);              //      3,776 (pad to 4,096)
    int* sbposA  = (int*)(ws + 234593024L);              //      5,632
    float* SC1   = (float*)(ws + 234600192L);            //    720,000
    float* SC2   = (float*)(ws + 235320192L);            //    720,000
    float* SC3   = (float*)(ws + 236040192L);            //    720,000
                                                         // end 236,760,192 (< 261,120,256 proven)

    k_detect<<<1, 64, 0, stream>>>(adj_v, FLAG);
    k_cast16<<<45000, 256, 0, stream>>>(ue, ie, ego16, FLAG);

    // ---- merged two-level build: 3 launches for all three graphs ----
    k_initpos3<<<1, 256, 0, stream>>>(sbposU, sbposI, sbposA);
    k_part3<<<PB_U + PB_I + PB_A, 256, 0, stream>>>(ug_r, ug_c, ug_v,
                                                    ig_r, ig_c, ig_v,
                                                    adj_r, adj_c, adj_v,
                                                    recTmpU, recTmpI, recTmpA,
                                                    sbposU, sbposI, sbposA, FLAG);
    k_sortsb3<<<NSB_UG + NSB_IG + NSB_ADJ, 1024, 0, stream>>>(
        recTmpU, rec2U, rstartU, rendU, sbposU,
        recTmpI, rec2I, rstartI, rendI, sbposI,
        recTmpA, rec2A, rstartA, rendA, sbposA);

    // ---- user+item MLP branches, stage-merged (2 spmm + 2 gemm launches) ----
    const bf16* ego16I = ego16 + (size_t)N_USER * 64;
    int nbU = (N_USER + 31) / 32;       // 1875
    int nbI = (N_ITEM + 31) / 32;       // 3750
    int gu = (N_USER / 16 + 7) / 8;     // 469 (~2 row-tiles per wave)
    int gi = (N_ITEM / 16 + 7) / 8;     // 938
    k_spmm2<<<nbU + nbI, 256, 0, stream>>>(rstartU, rendU, rec2U, ego16,  SU, N_USER, nbU,
                                           rstartI, rendI, rec2I, ego16I, SI, N_ITEM);
    k_gemm2<1><<<gu + gi, 256, 0, stream>>>(SU, Wu0, bu0, TU, N_USER, gu,
                                            SI, Wi0, bi0, TI, N_ITEM, FLAG);
    k_spmm2<<<nbU + nbI, 256, 0, stream>>>(rstartU, rendU, rec2U, TU, SU, N_USER, nbU,
                                           rstartI, rendI, rec2I, TI, SI, N_ITEM);
    k_gemm2<2><<<gu + gi, 256, 0, stream>>>(SU, Wu1, bu1, UH, N_USER, gu,
                                            SI, Wi1, bi1, IH, N_ITEM, FLAG);

    // ---- 3 NGCF layers: S-only spmm; layer forms P in-register, stores E_k + scale ----
    bf16* Ebuf[4]  = {ego16, E1, E2, E3};
    float* SCs[3]  = {SC1, SC2, SC3};
    for (int k = 0; k < 3; k++) {
        k_spmm_bf<<<(NTOT + 31) / 32, 256, 0, stream>>>(rstartA, rendA, rec2A, Ebuf[k], S16A, NTOT);
        k_layer<<<704, 256, 0, stream>>>(S16A, Ebuf[k], Ebuf[k + 1],
                                         Wgc, bgc, Wbi, bbi,
                                         (long)k * 4096, (long)k * 64,
                                         SCs[k], NTOT, FLAG);
    }

    // ---- output gather ----
    k_gather<<<12288, 64, 0, stream>>>(users, pos, neg, ue, ie, E1, E2, E3,
                                       SC1, SC2, SC3, UH, IH, d_out, FLAG);
}

// Round 12
// 749.964 us; speedup vs baseline: 1.4264x; 1.0212x over previous
//
#include <hip/hip_runtime.h>
#include <hip/hip_bf16.h>

#define N_USER 60000
#define N_ITEM 120000
#define NTOT   180000
#define NNZ_ADJ 3600000
#define NNZ_UG   960000
#define NNZ_IG  1920000

#define RSBF    256         // rows per fine bin (round-11: was 2048; 256-row bins
                            // make the row-sort scatter LDS-stageable)
#define NBF_U   235         // ceil(60000/256)
#define NBF_I   469         // ceil(120000/256)
#define NBF_A   704         // ceil(180000/256)
#define CAPU_F  4736        // mean 4096 + 10 sigma
#define CAPI_F  4736
#define CAPA_F  5888        // mean 5120 + ~10 sigma
#define CHUNK   4096
#define PB_U ((NNZ_UG  + CHUNK - 1) / CHUNK)   // 235
#define PB_I ((NNZ_IG  + CHUNK - 1) / CHUNK)   // 469
#define PB_A ((NNZ_ADJ + CHUNK - 1) / CHUNK)   // 879

typedef __hip_bfloat16 bf16;
typedef __attribute__((ext_vector_type(8))) short bf16x8;   // one MFMA A/B fragment
typedef __attribute__((ext_vector_type(4))) float f32x4;    // one MFMA C/D fragment

// load float element i from input tensor of unknown dtype: flag=1 -> fp32, 0 -> bf16
__device__ __forceinline__ float ldf(const void* p, long i, int f) {
    return f ? ((const float*)p)[i] : __bfloat162float(((const bf16*)p)[i]);
}

// pack two fp32 -> one uint holding 2 bf16
__device__ __forceinline__ unsigned pk2(float a, float b) {
    unsigned short lo = __bfloat16_as_ushort(__float2bfloat16(a));
    unsigned short hi = __bfloat16_as_ushort(__float2bfloat16(b));
    return (unsigned)lo | ((unsigned)hi << 16);
}

// elementwise bf16 product of two bf16x8 fragments (for P = E .* S in-register)
__device__ __forceinline__ bf16x8 mul_bf8(bf16x8 x, bf16x8 y) {
    bf16x8 r;
#pragma unroll
    for (int e = 0; e < 8; e++) {
        float xf = __uint_as_float(((unsigned)(unsigned short)x[e]) << 16);
        float yf = __uint_as_float(((unsigned)(unsigned short)y[e]) << 16);
        r[e] = (short)__bfloat16_as_ushort(__float2bfloat16(xf * yf));
    }
    return r;
}

// ---------------- dtype detector (adj_vals >= 0 -> bf16 words have bit15==0) ----
__global__ void k_detect(const void* __restrict__ vals, int* __restrict__ flag) {
    if (threadIdx.x == 0 && blockIdx.x == 0) {
        const unsigned short* w = (const unsigned short*)vals;
        int cnt = 0;
        for (int i = 0; i < 512; i += 2) cnt += (w[i] >> 15) & 1;
        *flag = (cnt > 16) ? 1 : 0;
    }
}

// ---------------- cast user/item emb -> ego bf16 ----------------
__global__ __launch_bounds__(256) void k_cast16(const void* __restrict__ ue,
                                                const void* __restrict__ ie,
                                                bf16* __restrict__ ego16,
                                                const int* __restrict__ flag) {
    int f = *flag;
    long i = (long)blockIdx.x * 256 + threadIdx.x;   // NTOT*64 = 11,520,000
    const long uN = (long)N_USER * 64;
    if (i < (long)NTOT * 64) {
        float v = (i < uN) ? ldf(ue, i, f) : ldf(ie, i - uN, f);
        ego16[i] = __float2bfloat16(v);
    }
}

// ================= fine-binned build (round-11) =================
__global__ void k_initpos3(int* __restrict__ sbU, int* __restrict__ sbI,
                           int* __restrict__ sbA) {
    for (int i = threadIdx.x; i < NBF_U + NBF_I + NBF_A; i += blockDim.x) {
        if (i < NBF_U) sbU[i * 16] = i * CAPU_F;
        else if (i < NBF_U + NBF_I) { int k = i - NBF_U; sbI[k * 16] = k * CAPI_F; }
        else { int k = i - NBF_U - NBF_I; sbA[k * 16] = k * CAPA_F; }
    }
}

// L1: partition edges into 256-row fine bins, all 3 graphs in one grid.
// Record: {rl(8b)<<18 | col(18b), val_f32}. LDS-staged counting sort +
// coalesced flush (proven round-10 structure, 704 bins instead of 96).
// Finer bins shorten flush runs (~6 rec = 48 B) -- accepted tradeoff so the
// row-sort (k_sortfine3) becomes fully LDS-stageable.
__global__ __launch_bounds__(256) void k_part3(const int* __restrict__ rU, const int* __restrict__ cU, const void* __restrict__ vU,
                                               const int* __restrict__ rI, const int* __restrict__ cI, const void* __restrict__ vI,
                                               const int* __restrict__ rA, const int* __restrict__ cA, const void* __restrict__ vA,
                                               uint2* __restrict__ recU, uint2* __restrict__ recI, uint2* __restrict__ recA,
                                               int* __restrict__ sbU, int* __restrict__ sbI, int* __restrict__ sbA,
                                               const int* __restrict__ flag) {
    __shared__ int lcnt[NBF_A];
    __shared__ int lstart[NBF_A];
    __shared__ int lpos[NBF_A];
    __shared__ int lbase[NBF_A];
    __shared__ int wsum4[4];
    __shared__ uint2 stage[CHUNK];            // 32 KB bin-sorted records
    __shared__ unsigned short sbin[CHUNK];    // bin (0..703) of each stage slot

    int f = *flag;
    int t = threadIdx.x;
    int b = blockIdx.x;
    const int *rows, *cols; const void* vals; uint2* rec; int* sbpos; int nnz, base;
    if (b < PB_U)             { rows = rU; cols = cU; vals = vU; rec = recU; sbpos = sbU; nnz = NNZ_UG;  base = b * CHUNK; }
    else if (b < PB_U + PB_I) { rows = rI; cols = cI; vals = vI; rec = recI; sbpos = sbI; nnz = NNZ_IG;  base = (b - PB_U) * CHUNK; }
    else                      { rows = rA; cols = cA; vals = vA; rec = recA; sbpos = sbA; nnz = NNZ_ADJ; base = (b - PB_U - PB_I) * CHUNK; }

    for (int i = t; i < NBF_A; i += 256) lcnt[i] = 0;

    // ---- load 16 consecutive edges per thread into registers (read once) ----
    int base16 = base + t * 16;
    int rr[16], cc[16];
    float vv[16];
    if (base + CHUNK <= nnz) {           // full block: vectorized, unguarded
#pragma unroll
        for (int k = 0; k < 4; k++) {
            int4 r4 = *(const int4*)(rows + base16 + 4 * k);
            int4 c4 = *(const int4*)(cols + base16 + 4 * k);
            rr[4 * k + 0] = r4.x; rr[4 * k + 1] = r4.y; rr[4 * k + 2] = r4.z; rr[4 * k + 3] = r4.w;
            cc[4 * k + 0] = c4.x; cc[4 * k + 1] = c4.y; cc[4 * k + 2] = c4.z; cc[4 * k + 3] = c4.w;
        }
        if (f) {
#pragma unroll
            for (int k = 0; k < 4; k++) {
                float4 v4 = *(const float4*)((const float*)vals + base16 + 4 * k);
                vv[4 * k + 0] = v4.x; vv[4 * k + 1] = v4.y; vv[4 * k + 2] = v4.z; vv[4 * k + 3] = v4.w;
            }
        } else {
            const unsigned short* vb = (const unsigned short*)vals;
#pragma unroll
            for (int h = 0; h < 2; h++) {
                uint4 q = *(const uint4*)(vb + base16 + 8 * h);
                vv[8 * h + 0] = __uint_as_float(q.x << 16);
                vv[8 * h + 1] = __uint_as_float(q.x & 0xFFFF0000u);
                vv[8 * h + 2] = __uint_as_float(q.y << 16);
                vv[8 * h + 3] = __uint_as_float(q.y & 0xFFFF0000u);
                vv[8 * h + 4] = __uint_as_float(q.z << 16);
                vv[8 * h + 5] = __uint_as_float(q.z & 0xFFFF0000u);
                vv[8 * h + 6] = __uint_as_float(q.w << 16);
                vv[8 * h + 7] = __uint_as_float(q.w & 0xFFFF0000u);
            }
        }
    } else {                             // tail block: guarded scalar
#pragma unroll
        for (int k = 0; k < 16; k++) {
            int e = base16 + k;
            if (e < nnz) { rr[k] = rows[e]; cc[k] = cols[e]; vv[k] = ldf(vals, e, f); }
            else         { rr[k] = -1; cc[k] = 0; vv[k] = 0.0f; }
        }
    }
    __syncthreads();

    // ---- count pass (registers -> LDS counters, bin = row>>8) ----
#pragma unroll
    for (int k = 0; k < 16; k++)
        if (rr[k] >= 0) atomicAdd(&lcnt[rr[k] >> 8], 1);
    __syncthreads();

    // ---- exclusive scan over 704 bin counts (3 contiguous bins per thread) ----
    int b0 = 3 * t;
    int v0 = (b0     < NBF_A) ? lcnt[b0]     : 0;
    int v1 = (b0 + 1 < NBF_A) ? lcnt[b0 + 1] : 0;
    int v2 = (b0 + 2 < NBF_A) ? lcnt[b0 + 2] : 0;
    int ts = v0 + v1 + v2;
    int incl = ts;
    int lane = t & 63;
#pragma unroll
    for (int d = 1; d < 64; d <<= 1) {
        int w = __shfl_up(incl, d, 64);
        if (lane >= d) incl += w;
    }
    int wv = t >> 6;
    if (lane == 63) wsum4[wv] = incl;
    __syncthreads();
    if (t == 0) { int a = 0; for (int k2 = 0; k2 < 4; k2++) { int x = wsum4[k2]; wsum4[k2] = a; a += x; } }
    __syncthreads();
    int ex = wsum4[wv] + (incl - ts);
    if (b0 < NBF_A) {
        lstart[b0] = ex;            lpos[b0] = ex;
        lbase[b0]  = v0 ? atomicAdd(&sbpos[b0 * 16], v0) : 0;
    }
    if (b0 + 1 < NBF_A) {
        lstart[b0 + 1] = ex + v0;   lpos[b0 + 1] = ex + v0;
        lbase[b0 + 1]  = v1 ? atomicAdd(&sbpos[(b0 + 1) * 16], v1) : 0;
    }
    if (b0 + 2 < NBF_A) {
        lstart[b0 + 2] = ex + v0 + v1; lpos[b0 + 2] = ex + v0 + v1;
        lbase[b0 + 2]  = v2 ? atomicAdd(&sbpos[(b0 + 2) * 16], v2) : 0;
    }
    __syncthreads();

    // ---- scatter into LDS stage (bin-sorted within block) ----
#pragma unroll
    for (int k = 0; k < 16; k++) {
        if (rr[k] >= 0) {
            int sb = rr[k] >> 8;
            int o = atomicAdd(&lpos[sb], 1);
            stage[o] = make_uint2(((unsigned)(rr[k] & 255) << 18) | (unsigned)cc[k],
                                  __float_as_uint(vv[k]));
            sbin[o] = (unsigned short)sb;
        }
    }
    __syncthreads();

    // ---- coalesced flush: linear LDS -> per-bin global runs ----
    int total = lstart[NBF_A - 1] + lcnt[NBF_A - 1];
    for (int i = t; i < total; i += 256) {
        int sb = sbin[i];
        rec[lbase[sb] + (i - lstart[sb])] = stage[i];
    }
}

// L2: row-sort each 256-row fine bin fully in LDS, in place.
// (round-10 counters: k_sortsb3 at 188 MB writes for 52 MB payload -- 2048-row
// scatter span overflowed L2. 256-row bins: count from global, 256-entry shfl
// scan, scatter into a 47 KB LDS stage, linear in-place flush. Writes fully
// coalesced; grid 1408 blocks.)
__global__ __launch_bounds__(256) void k_sortfine3(
        uint2* __restrict__ recU, int* __restrict__ rstartU, int* __restrict__ rendU, const int* __restrict__ sbU,
        uint2* __restrict__ recI, int* __restrict__ rstartI, int* __restrict__ rendI, const int* __restrict__ sbI,
        uint2* __restrict__ recA, int* __restrict__ rstartA, int* __restrict__ rendA, const int* __restrict__ sbA) {
    __shared__ int cnt[RSBF];
    __shared__ int lpos[RSBF];
    __shared__ int wsum[4];
    __shared__ uint2 stage[CAPA_F];      // 47.1 KB
    int b = blockIdx.x, t = threadIdx.x;
    uint2* rec; int* rstart; int* rend; const int* sbpos; int cap, n_rows, bin;
    if (b < NBF_U) {
        bin = b; rec = recU; rstart = rstartU; rend = rendU;
        sbpos = sbU; cap = CAPU_F; n_rows = N_USER;
    } else if (b < NBF_U + NBF_I) {
        bin = b - NBF_U; rec = recI; rstart = rstartI; rend = rendI;
        sbpos = sbI; cap = CAPI_F; n_rows = N_ITEM;
    } else {
        bin = b - NBF_U - NBF_I; rec = recA; rstart = rstartA; rend = rendA;
        sbpos = sbA; cap = CAPA_F; n_rows = NTOT;
    }
    int s = bin * cap;
    int e = sbpos[bin * 16];             // fill cursor after k_part3
    cnt[t] = 0;
    __syncthreads();
    // ---- count pass ----
    for (int j = s + t; j < e; j += 256)
        atomicAdd(&cnt[rec[j].x >> 18], 1);
    __syncthreads();
    // ---- 256-entry exclusive scan (4-wave shfl) ----
    int v = cnt[t];
    int incl = v;
    int lane = t & 63;
#pragma unroll
    for (int d = 1; d < 64; d <<= 1) {
        int w = __shfl_up(incl, d, 64);
        if (lane >= d) incl += w;
    }
    int wv = t >> 6;
    if (lane == 63) wsum[wv] = incl;
    __syncthreads();
    if (t == 0) { int a = 0; for (int k = 0; k < 4; k++) { int x = wsum[k]; wsum[k] = a; a += x; } }
    __syncthreads();
    int ex = wsum[wv] + (incl - v);
    lpos[t] = ex;
    int row = bin * RSBF + t;
    if (row < n_rows) { rstart[row] = s + ex; rend[row] = s + ex + v; }
    __syncthreads();
    // ---- scatter pass: global (L2-hit re-read) -> LDS stage in sorted order ----
    for (int j = s + t; j < e; j += 256) {
        uint2 r = rec[j];
        int o = atomicAdd(&lpos[r.x >> 18], 1);
        stage[o] = r;
    }
    __syncthreads();
    // ---- linear in-place flush (all reads completed above) ----
    int total = e - s;
    for (int i = t; i < total; i += 256)
        rec[s + i] = stage[i];
}

#define ACC8(q, v)                                      \
    a[0] += (v) * __uint_as_float((q).x << 16);         \
    a[1] += (v) * __uint_as_float((q).x & 0xFFFF0000u); \
    a[2] += (v) * __uint_as_float((q).y << 16);         \
    a[3] += (v) * __uint_as_float((q).y & 0xFFFF0000u); \
    a[4] += (v) * __uint_as_float((q).z << 16);         \
    a[5] += (v) * __uint_as_float((q).z & 0xFFFF0000u); \
    a[6] += (v) * __uint_as_float((q).w << 16);         \
    a[7] += (v) * __uint_as_float((q).w & 0xFFFF0000u);

// ================= CSR SpMM row body, bf16 x: one row per 8-lane octet =========
// Edge loop unrolled x4 with grouped loads (4 gathers in flight per wave).
__device__ __forceinline__ void spmm_row(int row, int p,
                                         const int* __restrict__ rstart,
                                         const int* __restrict__ rend,
                                         const uint2* __restrict__ rec,
                                         const bf16* __restrict__ x,
                                         bf16* __restrict__ out) {
    int s = rstart[row], e = rend[row];
    const uint4* xb = (const uint4*)x;   // 8 bf16 per uint4
    float a[8];
#pragma unroll
    for (int i = 0; i < 8; i++) a[i] = 0.0f;

    int j = s;
    for (; j + 4 <= e; j += 4) {
        uint2 r0 = rec[j];
        uint2 r1 = rec[j + 1];
        uint2 r2 = rec[j + 2];
        uint2 r3 = rec[j + 3];
        uint4 q0 = xb[(long)(r0.x & 0x3FFFF) * 8 + p];
        uint4 q1 = xb[(long)(r1.x & 0x3FFFF) * 8 + p];
        uint4 q2 = xb[(long)(r2.x & 0x3FFFF) * 8 + p];
        uint4 q3 = xb[(long)(r3.x & 0x3FFFF) * 8 + p];
        float v0 = __uint_as_float(r0.y);
        float v1 = __uint_as_float(r1.y);
        float v2 = __uint_as_float(r2.y);
        float v3 = __uint_as_float(r3.y);
        ACC8(q0, v0)
        ACC8(q1, v1)
        ACC8(q2, v2)
        ACC8(q3, v3)
    }
    for (; j < e; j++) {
        uint2 r = rec[j];
        uint4 q = xb[(long)(r.x & 0x3FFFF) * 8 + p];
        float v = __uint_as_float(r.y);
        ACC8(q, v)
    }

    *(uint4*)(out + (long)row * 64 + p * 8) =
        make_uint4(pk2(a[0], a[1]), pk2(a[2], a[3]),
                   pk2(a[4], a[5]), pk2(a[6], a[7]));
}

// single-segment spmm (adjacency layer loop)
__global__ __launch_bounds__(256) void k_spmm_bf(const int* __restrict__ rstart,
                                                 const int* __restrict__ rend,
                                                 const uint2* __restrict__ rec,
                                                 const bf16* __restrict__ x,
                                                 bf16* __restrict__ out,
                                                 int n_rows) {
    int row = blockIdx.x * 32 + (threadIdx.x >> 3);
    int p = threadIdx.x & 7;
    if (row >= n_rows) return;
    spmm_row(row, p, rstart, rend, rec, x, out);
}

// two-segment spmm (user+item MLP stages merged into one launch)
__global__ __launch_bounds__(256) void k_spmm2(
        const int* __restrict__ rs0, const int* __restrict__ re0, const uint2* __restrict__ rc0,
        const bf16* __restrict__ x0, bf16* __restrict__ o0, int n0, int nb0,
        const int* __restrict__ rs1, const int* __restrict__ re1, const uint2* __restrict__ rc1,
        const bf16* __restrict__ x1, bf16* __restrict__ o1, int n1) {
    int b = blockIdx.x;
    int p = threadIdx.x & 7;
    int rl = threadIdx.x >> 3;
    if (b < nb0) {
        int row = b * 32 + rl;
        if (row < n0) spmm_row(row, p, rs0, re0, rc0, x0, o0);
    } else {
        int row = (b - nb0) * 32 + rl;
        if (row < n1) spmm_row(row, p, rs1, re1, rc1, x1, o1);
    }
}

// ---------------- two-segment Y = act(X16 @ W + b) -> bf16 (MFMA) --------------
template <int ACT>
__global__ __launch_bounds__(256) void k_gemm2(
        const bf16* __restrict__ X0, const void* __restrict__ W0, const void* __restrict__ b0,
        bf16* __restrict__ Y0, int M0, int nb0,
        const bf16* __restrict__ X1, const void* __restrict__ W1, const void* __restrict__ b1,
        bf16* __restrict__ Y1, int M1,
        const int* __restrict__ flag) {
    __shared__ bf16 WtH[64][72];
    __shared__ bf16 WtL[64][72];
    __shared__ float bl[64];
    int f = *flag;
    int tid = threadIdx.x;
    int bId = blockIdx.x;
    const bf16* X; const void* W; const void* bb; bf16* Y; int M, sb, nbseg;
    if (bId < nb0) { X = X0; W = W0; bb = b0; Y = Y0; M = M0; sb = bId; nbseg = nb0; }
    else { X = X1; W = W1; bb = b1; Y = Y1; M = M1; sb = bId - nb0; nbseg = gridDim.x - nb0; }

    for (int idx = tid; idx < 4096; idx += 256) {
        int n = idx >> 6, kk = idx & 63;
        float v = ldf(W, (long)kk * 64 + n, f);
        bf16 h = __float2bfloat16(v);
        WtH[n][kk] = h;
        WtL[n][kk] = __float2bfloat16(v - __bfloat162float(h));
    }
    if (tid < 64) bl[tid] = ldf(bb, tid, f);
    __syncthreads();

    int l  = tid & 63;
    int lr = l & 15;      // A row / D col within tile
    int lk = l >> 4;      // k sub-block / D row group

    bf16x8 bh[2][4], bbf[2][4];
#pragma unroll
    for (int kt = 0; kt < 2; kt++)
#pragma unroll
        for (int ct = 0; ct < 4; ct++) {
            int n  = ct * 16 + lr;
            int ko = kt * 32 + lk * 8;
            bh[kt][ct]  = *(const bf16x8*)&WtH[n][ko];
            bbf[kt][ct] = *(const bf16x8*)&WtL[n][ko];
        }

    int nt  = M >> 4;                       // M is a multiple of 16
    int wid = sb * 4 + (tid >> 6);
    int nw  = nbseg * 4;

    for (int t = wid; t < nt; t += nw) {
        const bf16* Ap = X + (long)(t * 16 + lr) * 64 + lk * 8;
        bf16x8 a[2];
#pragma unroll
        for (int kt = 0; kt < 2; kt++) a[kt] = *(const bf16x8*)(Ap + kt * 32);

        f32x4 acc[4];
#pragma unroll
        for (int ct = 0; ct < 4; ct++) {
            float bv = bl[ct * 16 + lr];
            acc[ct] = (f32x4){bv, bv, bv, bv};
        }
#pragma unroll
        for (int kt = 0; kt < 2; kt++)
#pragma unroll
            for (int ct = 0; ct < 4; ct++) {
                acc[ct] = __builtin_amdgcn_mfma_f32_16x16x32_bf16(a[kt], bh[kt][ct], acc[ct], 0, 0, 0);
                acc[ct] = __builtin_amdgcn_mfma_f32_16x16x32_bf16(a[kt], bbf[kt][ct], acc[ct], 0, 0, 0);
            }

#pragma unroll
        for (int r = 0; r < 4; r++) {
            float v0 = acc[0][r], v1 = acc[1][r], v2 = acc[2][r], v3 = acc[3][r];
            if (ACT == 2) {
                v0 = fmaxf(v0, 0.0f); v1 = fmaxf(v1, 0.0f);
                v2 = fmaxf(v2, 0.0f); v3 = fmaxf(v3, 0.0f);
            } else {
                v0 = (v0 > 0.0f) ? v0 : (expf(v0) - 1.0f);
                v1 = (v1 > 0.0f) ? v1 : (expf(v1) - 1.0f);
                v2 = (v2 > 0.0f) ? v2 : (expf(v2) - 1.0f);
                v3 = (v3 > 0.0f) ? v3 : (expf(v3) - 1.0f);
            }
            long ob = (long)(t * 16 + lk * 4 + r) * 64 + lr;
            Y[ob]      = __float2bfloat16(v0);
            Y[ob + 16] = __float2bfloat16(v1);
            Y[ob + 32] = __float2bfloat16(v2);
            Y[ob + 48] = __float2bfloat16(v3);
        }
    }
}

// ---------------- NGCF layer: E_out = leakyrelu(S@W1 + (E.*S)@W2 + b) --------
// P = E.*S formed IN-REGISTER (row-local). Only the per-row l2 scale (f32) is
// stored; k_gather applies E_k * scale. W1/W2 in LDS (B^T layout, +8 pad),
// bf16 hi+lo split.
__global__ __launch_bounds__(256) void k_layer(const bf16* __restrict__ S,
                                               const bf16* __restrict__ Ein,
                                               bf16* __restrict__ Eout,
                                               const void* __restrict__ Wgc,
                                               const void* __restrict__ bgc,
                                               const void* __restrict__ Wbi,
                                               const void* __restrict__ bbi,
                                               long woff, long boff,
                                               float* __restrict__ scale, int M,
                                               const int* __restrict__ flag) {
    __shared__ bf16 W1H[64][72];
    __shared__ bf16 W1L[64][72];
    __shared__ bf16 W2H[64][72];
    __shared__ bf16 W2L[64][72];
    __shared__ float bl[64];
    int f = *flag;
    int tid = threadIdx.x;
    for (int idx = tid; idx < 4096; idx += 256) {
        int n = idx >> 6, kk = idx & 63;
        float v1 = ldf(Wgc, woff + (long)kk * 64 + n, f);
        float v2 = ldf(Wbi, woff + (long)kk * 64 + n, f);
        bf16 h1 = __float2bfloat16(v1);
        bf16 h2 = __float2bfloat16(v2);
        W1H[n][kk] = h1;
        W1L[n][kk] = __float2bfloat16(v1 - __bfloat162float(h1));
        W2H[n][kk] = h2;
        W2L[n][kk] = __float2bfloat16(v2 - __bfloat162float(h2));
    }
    if (tid < 64) bl[tid] = ldf(bgc, boff + tid, f) + ldf(bbi, boff + tid, f);
    __syncthreads();

    int l  = tid & 63;
    int lr = l & 15;
    int lk = l >> 4;

    bf16x8 w1h[2][4], w1l[2][4], w2h[2][4], w2l[2][4];
#pragma unroll
    for (int kt = 0; kt < 2; kt++)
#pragma unroll
        for (int ct = 0; ct < 4; ct++) {
            int n  = ct * 16 + lr;
            int ko = kt * 32 + lk * 8;
            w1h[kt][ct] = *(const bf16x8*)&W1H[n][ko];
            w1l[kt][ct] = *(const bf16x8*)&W1L[n][ko];
            w2h[kt][ct] = *(const bf16x8*)&W2H[n][ko];
            w2l[kt][ct] = *(const bf16x8*)&W2L[n][ko];
        }

    int nt  = M >> 4;                 // 11250 for NTOT
    int wid = blockIdx.x * 4 + (tid >> 6);
    int nw  = gridDim.x * 4;

    for (int t = wid; t < nt; t += nw) {
        long rb = (long)(t * 16 + lr) * 64 + lk * 8;
        bf16x8 sv[2], pv[2];
        sv[0] = *(const bf16x8*)(S + rb);
        sv[1] = *(const bf16x8*)(S + rb + 32);
        {
            bf16x8 e0 = *(const bf16x8*)(Ein + rb);
            bf16x8 e1 = *(const bf16x8*)(Ein + rb + 32);
            pv[0] = mul_bf8(e0, sv[0]);
            pv[1] = mul_bf8(e1, sv[1]);
        }

        f32x4 acc[4];
#pragma unroll
        for (int ct = 0; ct < 4; ct++) {
            float bv = bl[ct * 16 + lr];
            acc[ct] = (f32x4){bv, bv, bv, bv};
        }
#pragma unroll
        for (int kt = 0; kt < 2; kt++)
#pragma unroll
            for (int ct = 0; ct < 4; ct++) {
                acc[ct] = __builtin_amdgcn_mfma_f32_16x16x32_bf16(sv[kt], w1h[kt][ct], acc[ct], 0, 0, 0);
                acc[ct] = __builtin_amdgcn_mfma_f32_16x16x32_bf16(sv[kt], w1l[kt][ct], acc[ct], 0, 0, 0);
                acc[ct] = __builtin_amdgcn_mfma_f32_16x16x32_bf16(pv[kt], w2h[kt][ct], acc[ct], 0, 0, 0);
                acc[ct] = __builtin_amdgcn_mfma_f32_16x16x32_bf16(pv[kt], w2l[kt][ct], acc[ct], 0, 0, 0);
            }

#pragma unroll
        for (int r = 0; r < 4; r++) {
            float v0 = acc[0][r], v1 = acc[1][r], v2 = acc[2][r], v3 = acc[3][r];
            v0 = (v0 > 0.0f) ? v0 : 0.2f * v0;
            v1 = (v1 > 0.0f) ? v1 : 0.2f * v1;
            v2 = (v2 > 0.0f) ? v2 : 0.2f * v2;
            v3 = (v3 > 0.0f) ? v3 : 0.2f * v3;
            float ss = v0 * v0 + v1 * v1 + v2 * v2 + v3 * v3;
            ss += __shfl_xor(ss, 1, 64);    // reduce over the 16-lane column group
            ss += __shfl_xor(ss, 2, 64);
            ss += __shfl_xor(ss, 4, 64);
            ss += __shfl_xor(ss, 8, 64);
            float sc2 = 1.0f / fmaxf(sqrtf(ss), 1e-12f);
            int grow = t * 16 + lk * 4 + r;
            long ob = (long)grow * 64 + lr;
            Eout[ob]      = __float2bfloat16(v0);
            Eout[ob + 16] = __float2bfloat16(v1);
            Eout[ob + 32] = __float2bfloat16(v2);
            Eout[ob + 48] = __float2bfloat16(v3);
            if (lr == 0) scale[grow] = sc2;
        }
    }
}

// ---------------- final gather into output ----------------
// nm_k[row] reconstructed as E_k[row] * scale_k[row] (norms not materialized).
__global__ __launch_bounds__(64) void k_gather(const int* __restrict__ users,
                                               const int* __restrict__ pos,
                                               const int* __restrict__ neg,
                                               const void* __restrict__ ue,
                                               const void* __restrict__ ie,
                                               const bf16* __restrict__ E1,
                                               const bf16* __restrict__ E2,
                                               const bf16* __restrict__ E3,
                                               const float* __restrict__ s1,
                                               const float* __restrict__ s2,
                                               const float* __restrict__ s3,
                                               const bf16* __restrict__ uh,
                                               const bf16* __restrict__ ih,
                                               void* __restrict__ out,
                                               const int* __restrict__ flag) {
    int f = *flag;
    int b = blockIdx.x;           // 0..12287: [users | pos | neg] x 4096
    int which = b >> 12;
    int s = b & 4095;
    int lane = threadIdx.x;       // 64
    long ebase, nrow;
    const void* e0;
    const bf16* hh;
    if (which == 0) {
        int r = users[s];
        e0 = ue; ebase = (long)r * 64;
        hh = uh + (long)r * 64;
        nrow = (long)r;
    } else {
        int r = (which == 1) ? pos[s] : neg[s];
        e0 = ie; ebase = (long)r * 64;
        hh = ih + (long)r * 64;
        nrow = (long)(N_USER + r);
    }
    long nbase = nrow * 64;
    float o0 = ldf(e0, ebase + lane, f);
    float o1 = __bfloat162float(E1[nbase + lane]) * s1[nrow];
    float o2 = __bfloat162float(E2[nbase + lane]) * s2[nrow];
    float o3 = __bfloat162float(E3[nbase + lane]) * s3[nrow];
    float o4 = __bfloat162float(hh[lane]);
    long ob = (long)b * 320;
    if (f) {
        float* o = (float*)out + ob;
        o[lane] = o0; o[64 + lane] = o1; o[128 + lane] = o2;
        o[192 + lane] = o3; o[256 + lane] = o4;
    } else {
        bf16* o = (bf16*)out + ob;
        o[lane]       = __float2bfloat16(o0);
        o[64 + lane]  = __float2bfloat16(o1);
        o[128 + lane] = __float2bfloat16(o2);
        o[192 + lane] = __float2bfloat16(o3);
        o[256 + lane] = __float2bfloat16(o4);
    }
}

extern "C" void kernel_launch(void* const* d_in, const int* in_sizes, int n_in,
                              void* d_out, int out_size, void* d_ws, size_t ws_size,
                              hipStream_t stream) {
    const int* users = (const int*)d_in[0];
    const int* pos   = (const int*)d_in[1];
    const int* neg   = (const int*)d_in[2];
    const int* adj_r = (const int*)d_in[3];
    const int* adj_c = (const int*)d_in[4];
    const void* adj_v = d_in[5];
    const int* ug_r  = (const int*)d_in[6];
    const int* ug_c  = (const int*)d_in[7];
    const void* ug_v = d_in[8];
    const int* ig_r  = (const int*)d_in[9];
    const int* ig_c  = (const int*)d_in[10];
    const void* ig_v = d_in[11];
    const void* ue   = d_in[12];
    const void* ie   = d_in[13];
    const void* Wgc  = d_in[14];
    const void* bgc  = d_in[15];
    const void* Wbi  = d_in[16];
    const void* bbi  = d_in[17];
    const void* Wu0  = d_in[18];
    const void* bu0  = d_in[19];
    const void* Wu1  = d_in[20];
    const void* bu1  = d_in[21];
    const void* Wi0  = d_in[22];
    const void* bi0  = d_in[23];
    const void* Wi1  = d_in[24];
    const void* bi1  = d_in[25];

    char* ws = (char*)d_ws;
    int*   FLAG  = (int*)(ws + 0);                       // 256 B
    // fine-binned record buffers (sorted IN PLACE by k_sortfine3, live all run)
    uint2* recA  = (uint2*)(ws + 256);                   // 704*5888*8 = 33,161,216
    uint2* recU  = (uint2*)(ws + 33161472L);             // 235*4736*8 =  8,903,680
    uint2* recI  = (uint2*)(ws + 42065152L);             // 469*4736*8 = 17,766,912
    bf16*  S16A  = (bf16*)(ws + 59832064L);              // 23,040,000 (adj S, layer phase)
    bf16*  SU    = (bf16*)(ws + 82872064L);              //  7,680,000
    bf16*  SI    = (bf16*)(ws + 90552064L);              // 15,360,000
    bf16*  ego16 = (bf16*)(ws + 105912064L);             // E0, 23,040,000
    bf16*  UH    = (bf16*)(ws + 128952064L);             //  7,680,000
    bf16*  IH    = (bf16*)(ws + 136632064L);             // 15,360,000
    bf16*  E1    = (bf16*)(ws + 151992064L);             // 23,040,000
    bf16*  E2    = (bf16*)(ws + 175032064L);             // 23,040,000
    bf16*  E3    = (bf16*)(ws + 198072064L);             // 23,040,000
    // TI aliases E2 head; TU aliases E2 tail. Both dead before layer k=1 writes E2.
    bf16*  TI    = (bf16*)(ws + 175032064L);             // 15,360,000
    bf16*  TU    = (bf16*)(ws + 190392064L);             //  7,680,000 (ends 198,072,064)
    int* rstartA = (int*)(ws + 221112064L);              //    720,000
    int* rendA   = (int*)(ws + 221832064L);              //    720,000
    int* rstartU = (int*)(ws + 222552064L);              //    240,000
    int* rendU   = (int*)(ws + 222792064L);              //    240,000
    int* rstartI = (int*)(ws + 223032064L);              //    480,000
    int* rendI   = (int*)(ws + 223512064L);              //    480,000
    int* sbposU  = (int*)(ws + 223992064L);              //  15,040 (pad)
    int* sbposI  = (int*)(ws + 224007168L);              //  30,016 (pad)
    int* sbposA  = (int*)(ws + 224037248L);              //  45,056
    float* SC1   = (float*)(ws + 224082304L);            //    720,000
    float* SC2   = (float*)(ws + 224802304L);            //    720,000
    float* SC3   = (float*)(ws + 225522304L);            //    720,000
                                                         // end 226,242,304 (< 261,120,256 proven)

    k_detect<<<1, 64, 0, stream>>>(adj_v, FLAG);
    k_cast16<<<45000, 256, 0, stream>>>(ue, ie, ego16, FLAG);

    // ---- fine-binned build: part (bin) + sortfine (row-sort in place) ----
    k_initpos3<<<1, 256, 0, stream>>>(sbposU, sbposI, sbposA);
    k_part3<<<PB_U + PB_I + PB_A, 256, 0, stream>>>(ug_r, ug_c, ug_v,
                                                    ig_r, ig_c, ig_v,
                                                    adj_r, adj_c, adj_v,
                                                    recU, recI, recA,
                                                    sbposU, sbposI, sbposA, FLAG);
    k_sortfine3<<<NBF_U + NBF_I + NBF_A, 256, 0, stream>>>(
        recU, rstartU, rendU, sbposU,
        recI, rstartI, rendI, sbposI,
        recA, rstartA, rendA, sbposA);

    // ---- user+item MLP branches, stage-merged (2 spmm + 2 gemm launches) ----
    const bf16* ego16I = ego16 + (size_t)N_USER * 64;
    int nbU = (N_USER + 31) / 32;       // 1875
    int nbI = (N_ITEM + 31) / 32;       // 3750
    int gu = (N_USER / 16 + 7) / 8;     // 469 (~2 row-tiles per wave)
    int gi = (N_ITEM / 16 + 7) / 8;     // 938
    k_spmm2<<<nbU + nbI, 256, 0, stream>>>(rstartU, rendU, recU, ego16,  SU, N_USER, nbU,
                                           rstartI, rendI, recI, ego16I, SI, N_ITEM);
    k_gemm2<1><<<gu + gi, 256, 0, stream>>>(SU, Wu0, bu0, TU, N_USER, gu,
                                            SI, Wi0, bi0, TI, N_ITEM, FLAG);
    k_spmm2<<<nbU + nbI, 256, 0, stream>>>(rstartU, rendU, recU, TU, SU, N_USER, nbU,
                                           rstartI, rendI, recI, TI, SI, N_ITEM);
    k_gemm2<2><<<gu + gi, 256, 0, stream>>>(SU, Wu1, bu1, UH, N_USER, gu,
                                            SI, Wi1, bi1, IH, N_ITEM, FLAG);

    // ---- 3 NGCF layers: S-only spmm; layer forms P in-register, stores E_k + scale ----
    bf16* Ebuf[4]  = {ego16, E1, E2, E3};
    float* SCs[3]  = {SC1, SC2, SC3};
    for (int k = 0; k < 3; k++) {
        k_spmm_bf<<<(NTOT + 31) / 32, 256, 0, stream>>>(rstartA, rendA, recA, Ebuf[k], S16A, NTOT);
        k_layer<<<704, 256, 0, stream>>>(S16A, Ebuf[k], Ebuf[k + 1],
                                         Wgc, bgc, Wbi, bbi,
                                         (long)k * 4096, (long)k * 64,
                                         SCs[k], NTOT, FLAG);
    }

    // ---- output gather ----
    k_gather<<<12288, 64, 0, stream>>>(users, pos, neg, ue, ie, E1, E2, E3,
                                       SC1, SC2, SC3, UH, IH, d_out, FLAG);
}